// Round 7
// baseline (401.570 us; speedup 1.0000x reference)
//
#include <hip/hip_runtime.h>

#define NN 100000
#define NE 1600000
#define NG 256

#define NB 196    // node buckets of 512 nodes
#define BSH 9     // bucket shift (512)
#define NPB 392   // partition blocks
#define EPB 4096  // edges per partition block

#define TT 64     // nodes per tail block

// ---------------------------------------------------------------------------
// Workspace layout (4-byte words). 16B alignment holds for agg/buf.
//   norm_out  : [0, NN)                      float
//   norm_in   : [NN, 2NN)                    float
//   inv_cnt   : [2NN, 2NN+256)               float
//   row_ptr   : [2NN+512, 3NN+516)           int (NN+1 used, padded)
//   csr_src   : [3NN+516, +NE)               int
//   agg       : [A, A+32NN)                  float (alias: pairs uint2[NE])
//   buf       : [B, B+32NN)                  float (alias: srcbuf int[NE])
//   cnt_dst   : [C, C+NB*NPB)                int
//   cnt_src   : [.., +NB*NPB)                int
//   bb_dst    : [.., +200)                   int (NB+1 used)
//   bb_src    : [.., +200)                   int
// ---------------------------------------------------------------------------
#define OFF_NORM_OUT 0
#define OFF_NORM_IN  (NN)
#define OFF_INVC     (2 * NN)
#define OFF_ROWPTR   (2 * NN + 512)
#define OFF_CSR      (3 * NN + 516)
#define OFF_AGG      (3 * NN + 516 + NE)
#define OFF_BUF      (OFF_AGG + 32 * NN)
#define OFF_CNTD     (OFF_BUF + 32 * NN)
#define OFF_CNTS     (OFF_CNTD + NB * NPB)
#define OFF_BBD      (OFF_CNTS + NB * NPB)
#define OFF_BBS      (OFF_BBD + 200)

// phase 1: per-(block,bucket) histograms of dst and src buckets (LDS only)
__global__ void __launch_bounds__(256) k_part_count(const int* __restrict__ src,
                                                    const int* __restrict__ dst,
                                                    int* __restrict__ cnt_dst,
                                                    int* __restrict__ cnt_src) {
  __shared__ int hd[NB], hs[NB];
  int t = threadIdx.x;
  int blk = blockIdx.x;
  for (int i = t; i < NB; i += 256) { hd[i] = 0; hs[i] = 0; }
  __syncthreads();
  int e0 = blk * EPB, e1 = min(e0 + EPB, NE);
  for (int e = e0 + t; e < e1; e += 256) {
    atomicAdd(&hd[dst[e] >> BSH], 1);
    atomicAdd(&hs[src[e] >> BSH], 1);
  }
  __syncthreads();
  for (int i = t; i < NB; i += 256) {
    cnt_dst[i * NPB + blk] = hd[i];
    cnt_src[i * NPB + blk] = hs[i];
  }
}

// phase 2: turn count matrices into exact chunk bases + bucket bases
__global__ void __launch_bounds__(256) k_chunk_scan(int* __restrict__ cnt_dst,
                                                    int* __restrict__ bb_dst,
                                                    int* __restrict__ cnt_src,
                                                    int* __restrict__ bb_src) {
  __shared__ int tot[256];
  int t = threadIdx.x;
  for (int p = 0; p < 2; ++p) {
    int* cnt = p ? cnt_src : cnt_dst;
    int* bb = p ? bb_src : bb_dst;
    int s = 0;
    if (t < NB)
      for (int k = 0; k < NPB; ++k) s += cnt[t * NPB + k];
    tot[t] = s;
    __syncthreads();
    int incl = s;
    for (int off = 1; off < 256; off <<= 1) {
      int o = (t >= off) ? tot[t - off] : 0;
      __syncthreads();
      incl += o;
      tot[t] = incl;
      __syncthreads();
    }
    int base = incl - s;  // exclusive bucket base
    if (t < NB) {
      bb[t] = base;
      int run = base;
      for (int k = 0; k < NPB; ++k) {
        int c = cnt[t * NPB + k];
        cnt[t * NPB + k] = run;
        run += c;
      }
      if (t == NB - 1) bb[NB] = run;
    }
    __syncthreads();
  }
}

// phase 3: scatter edges into bucket regions (block-private sequential cursors)
__global__ void __launch_bounds__(256) k_part_scatter(const int* __restrict__ src,
                                                      const int* __restrict__ dst,
                                                      const int* __restrict__ cnt_dst,
                                                      const int* __restrict__ cnt_src,
                                                      uint2* __restrict__ pairs,
                                                      int* __restrict__ srcbuf) {
  __shared__ int cd[NB], cs[NB];
  int t = threadIdx.x;
  int blk = blockIdx.x;
  for (int i = t; i < NB; i += 256) {
    cd[i] = cnt_dst[i * NPB + blk];
    cs[i] = cnt_src[i * NPB + blk];
  }
  __syncthreads();
  int e0 = blk * EPB, e1 = min(e0 + EPB, NE);
  for (int e = e0 + t; e < e1; e += 256) {
    int s = src[e], d = dst[e];
    int pd = atomicAdd(&cd[d >> BSH], 1);
    pairs[pd] = make_uint2((unsigned)s, (unsigned)d);
    int ps = atomicAdd(&cs[s >> BSH], 1);
    srcbuf[ps] = s;
  }
}

// phase 4: per-bucket CSR finalize: row_ptr, norm_in, csr (all bucket-local)
__global__ void __launch_bounds__(256) k_bucket_csr(const uint2* __restrict__ pairs,
                                                    const int* __restrict__ bb,
                                                    int* __restrict__ row_ptr,
                                                    float* __restrict__ norm_in,
                                                    int* __restrict__ csr) {
  __shared__ int hist[512], curs[512], pscan[256];
  int t = threadIdx.x;
  int b = blockIdx.x;
  int n0 = b << BSH;
  int ebase = bb[b], eend = bb[b + 1];
  hist[t] = 0;
  hist[t + 256] = 0;
  __syncthreads();
  for (int e = ebase + t; e < eend; e += 256)
    atomicAdd(&hist[pairs[e].y & 511], 1);
  __syncthreads();
  int s0 = hist[2 * t], s1 = hist[2 * t + 1];
  int ps = s0 + s1;
  pscan[t] = ps;
  __syncthreads();
  int incl = ps;
  for (int off = 1; off < 256; off <<= 1) {
    int o = (t >= off) ? pscan[t - off] : 0;
    __syncthreads();
    incl += o;
    pscan[t] = incl;
    __syncthreads();
  }
  int ex = incl - ps;
  curs[2 * t] = ex;
  curs[2 * t + 1] = ex + s0;
  int n = n0 + 2 * t;
  if (n < NN) {
    row_ptr[n] = ebase + ex;
    norm_in[n] = s0 > 0 ? 1.0f / sqrtf((float)s0) : 0.0f;
  }
  if (n + 1 < NN) {
    row_ptr[n + 1] = ebase + ex + s0;
    norm_in[n + 1] = s1 > 0 ? 1.0f / sqrtf((float)s1) : 0.0f;
  }
  __syncthreads();
  for (int e = ebase + t; e < eend; e += 256) {
    uint2 pr = pairs[e];
    int pos = atomicAdd(&curs[pr.y & 511], 1);
    csr[ebase + pos] = (int)pr.x;
  }
  if (b == 0 && t == 0) row_ptr[NN] = NE;
}

// phase 5: per-bucket out-degree -> norm_out
__global__ void __launch_bounds__(256) k_bucket_deg(const int* __restrict__ srcbuf,
                                                    const int* __restrict__ bb,
                                                    float* __restrict__ norm_out) {
  __shared__ int hist[512];
  int t = threadIdx.x;
  int b = blockIdx.x;
  hist[t] = 0;
  hist[t + 256] = 0;
  __syncthreads();
  int e0 = bb[b], e1 = bb[b + 1];
  for (int e = e0 + t; e < e1; e += 256)
    atomicAdd(&hist[srcbuf[e] & 511], 1);
  __syncthreads();
  int n = (b << BSH) + t;
  if (n < NN) {
    int d = hist[t];
    norm_out[n] = d > 0 ? 1.0f / sqrtf((float)d) : 0.0f;
  }
  n += 256;
  if (n < NN) {
    int d = hist[t + 256];
    norm_out[n] = d > 0 ? 1.0f / sqrtf((float)d) : 0.0f;
  }
}

// xs0 = n_feat * norm_out (pure streaming)
__global__ void k_norm_scale(const float* __restrict__ n_feat,
                             const float* __restrict__ norm_out,
                             float* __restrict__ xs) {
  int i = blockIdx.x * blockDim.x + threadIdx.x;
  if (i >= NN) return;
  float no = norm_out[i];
  float4 a = *reinterpret_cast<const float4*>(n_feat + (size_t)i * 8);
  float4 b = *reinterpret_cast<const float4*>(n_feat + (size_t)i * 8 + 4);
  a.x *= no; a.y *= no; a.z *= no; a.w *= no;
  b.x *= no; b.y *= no; b.z *= no; b.w *= no;
  *reinterpret_cast<float4*>(xs + (size_t)i * 8) = a;
  *reinterpret_cast<float4*>(xs + (size_t)i * 8 + 4) = b;
}

// graph sizes via binary search on the SORTED gid array: no atomics at all.
__global__ void __launch_bounds__(NG) k_graphinfo(const int* __restrict__ gid,
                                                  float* __restrict__ inv) {
  int g = threadIdx.x;
  int lo0 = 0, hi0 = NN;
  while (lo0 < hi0) { int m = (lo0 + hi0) >> 1; if (gid[m] < g) lo0 = m + 1; else hi0 = m; }
  int lo1 = lo0, hi1 = NN;
  while (lo1 < hi1) { int m = (lo1 + hi1) >> 1; if (gid[m] < g + 1) lo1 = m + 1; else hi1 = m; }
  int c = lo1 - lo0;
  inv[g] = 1.0f / fmaxf((float)c, 1.0f);
}

// CSR gather-aggregate: agg[i] = (sum_{e in in(i)} xs[src(e)]) * norm_in[i]
template <int D>
__global__ void k_agg(const float* __restrict__ xs, const int* __restrict__ csr,
                      const int* __restrict__ row_ptr, const float* __restrict__ norm_in,
                      float* __restrict__ agg) {
  constexpr int C = D / 4;
  int t = blockIdx.x * blockDim.x + threadIdx.x;
  if (t >= NN * C) return;
  int i = t / C;
  int c = t % C;
  int e0 = row_ptr[i], e1 = row_ptr[i + 1];
  float4 acc = {0.f, 0.f, 0.f, 0.f};
  for (int e = e0; e < e1; ++e) {
    int s = csr[e];
    float4 v = *reinterpret_cast<const float4*>(xs + (size_t)s * D + c * 4);
    acc.x += v.x; acc.y += v.y; acc.z += v.z; acc.w += v.w;
  }
  float ni = norm_in[i];
  acc.x *= ni; acc.y *= ni; acc.z *= ni; acc.w *= ni;
  *reinterpret_cast<float4*>(agg + (size_t)t * 4) = acc;
}

// node update: xs_out = relu(agg @ W + b) * norm_out   (agg already * norm_in)
template <int DIN, int DOUT>
__global__ void k_layer(const float* __restrict__ agg, const float* __restrict__ norm_out,
                        const float* __restrict__ W, const float* __restrict__ b,
                        float* __restrict__ xs_out) {
  int i = blockIdx.x * blockDim.x + threadIdx.x;
  if (i >= NN) return;
  float x[DIN];
#pragma unroll
  for (int k = 0; k < DIN; ++k) x[k] = agg[(size_t)i * DIN + k];
  float no = norm_out[i];
#pragma unroll
  for (int j = 0; j < DOUT; ++j) {
    float acc = b[j];
#pragma unroll
    for (int k = 0; k < DIN; ++k) acc = fmaf(x[k], W[k * DOUT + j], acc);
    acc = fmaxf(acc, 0.f);
    xs_out[(size_t)i * DOUT + j] = acc * no;
  }
}

// ---------------------------------------------------------------------------
// Tail v2: 64 nodes/block, 4 waves, lane==node. Activations transposed in LDS
// ([feat][node]: conflict-free). Output-column stripe is wave-uniform ->
// weights/biases come in via scalar s_loads (no LDS staging, no wbuf).
// ---------------------------------------------------------------------------

// MODE: 0 = plain, 1 = relu, 2 = maxpool(2)
template <int DIN, int DOUT, int MODE>
__device__ __forceinline__ void phaseT(const float* __restrict__ Ain,
                                       float* __restrict__ Bout,
                                       const float* __restrict__ W,
                                       const float* __restrict__ bias,
                                       int j0, int lane) {
  constexpr int STRIPE = DOUT / 4;
  constexpr int KB = (DIN < 32) ? DIN : 32;
  float acc[STRIPE];
#pragma unroll
  for (int j = 0; j < STRIPE; ++j) acc[j] = bias[j0 + j];
#pragma unroll
  for (int kb = 0; kb < DIN; kb += KB) {
    float xc[KB];
#pragma unroll
    for (int k = 0; k < KB; ++k) xc[k] = Ain[(kb + k) * TT + lane];
#pragma unroll
    for (int k = 0; k < KB; ++k) {
#pragma unroll
      for (int j = 0; j < STRIPE; ++j)
        acc[j] = fmaf(xc[k], W[(kb + k) * DOUT + j0 + j], acc[j]);
    }
  }
  if constexpr (MODE == 2) {
#pragma unroll
    for (int m = 0; m < STRIPE / 2; ++m)
      Bout[(j0 / 2 + m) * TT + lane] = fmaxf(acc[2 * m], acc[2 * m + 1]);
  } else {
#pragma unroll
    for (int j = 0; j < STRIPE; ++j) {
      float v = acc[j];
      if constexpr (MODE == 1) v = fmaxf(v, 0.f);
      Bout[(j0 + j) * TT + lane] = v;
    }
  }
}

__global__ void __launch_bounds__(256) k_tail2(
    const float* __restrict__ agg, const int* __restrict__ gid,
    const float* __restrict__ W3, const float* __restrict__ b3,
    const float* __restrict__ fW1, const float* __restrict__ fb1,
    const float* __restrict__ fW2, const float* __restrict__ fb2,
    const float* __restrict__ fW3, const float* __restrict__ fb3,
    const float* __restrict__ fW4, const float* __restrict__ fb4,
    const float* __restrict__ inv_counts, float* __restrict__ out) {
  __shared__ __align__(16) float A[128 * TT];   // 32 KB: x / q / s
  __shared__ __align__(16) float Bb[64 * TT];   // 16 KB: p / r / t
  __shared__ int sgid[TT];
  int t = threadIdx.x;
  int lane = t & 63;
  int wid = __builtin_amdgcn_readfirstlane(t >> 6);
  int nb = blockIdx.x * TT;
  int rem = min(TT, NN - nb);

  // stage x transposed: wave w loads 8-float chunk w of each node's row
  {
    const float* srcp = agg + (size_t)(nb + lane) * 32 + wid * 8;
    float4 v0 = *reinterpret_cast<const float4*>(srcp);
    float4 v1 = *reinterpret_cast<const float4*>(srcp + 4);
    int k0 = wid * 8;
    A[(k0 + 0) * TT + lane] = v0.x;
    A[(k0 + 1) * TT + lane] = v0.y;
    A[(k0 + 2) * TT + lane] = v0.z;
    A[(k0 + 3) * TT + lane] = v0.w;
    A[(k0 + 4) * TT + lane] = v1.x;
    A[(k0 + 5) * TT + lane] = v1.y;
    A[(k0 + 6) * TT + lane] = v1.z;
    A[(k0 + 7) * TT + lane] = v1.w;
  }
  if (t < TT) sgid[t] = (nb + t < NN) ? gid[nb + t] : 0x7fffffff;
  __syncthreads();

  phaseT<32, 128, 2>(A, Bb, W3, b3, wid * 32, lane);    // W3 + pool -> p[64][TT]
  __syncthreads();
  phaseT<64, 128, 1>(Bb, A, fW1, fb1, wid * 32, lane);  // fc1 -> q[128][TT]
  __syncthreads();
  phaseT<128, 64, 1>(A, Bb, fW2, fb2, wid * 16, lane);  // fc2 -> r[64][TT]
  __syncthreads();
  phaseT<64, 32, 1>(Bb, A, fW3, fb3, wid * 8, lane);    // fc3 -> s[32][TT]
  __syncthreads();

  // fc4: 32 -> 10, output t stored node-major [TT][12]
  {
    int jn = (wid < 2) ? 4 : (wid == 2 ? 2 : 0);
    int j0 = wid * 4;
    if (jn) {
      float xc[32];
#pragma unroll
      for (int k = 0; k < 32; ++k) xc[k] = A[k * TT + lane];
      for (int jj = 0; jj < jn; ++jj) {
        float acc = fb4[j0 + jj];
#pragma unroll
        for (int k = 0; k < 32; ++k) acc = fmaf(xc[k], fW4[k * 10 + j0 + jj], acc);
        Bb[lane * 12 + j0 + jj] = acc;
      }
    }
  }
  __syncthreads();

  // segmented graph-mean (gids sorted): few atomics per block
  if (t < 10) {
    int g = sgid[0];
    float run = 0.f;
    for (int n = 0; n < rem; ++n) {
      run += Bb[n * 12 + t];
      bool last = (n == rem - 1) || (sgid[n + 1] != g);
      if (last) {
        atomicAdd(&out[g * 10 + t], run * inv_counts[g]);
        run = 0.f;
        if (n < rem - 1) g = sgid[n + 1];
      }
    }
  }
}

extern "C" void kernel_launch(void* const* d_in, const int* in_sizes, int n_in,
                              void* d_out, int out_size, void* d_ws, size_t ws_size,
                              hipStream_t stream) {
  const int* src = (const int*)d_in[0];
  const int* dst = (const int*)d_in[1];
  const int* gid = (const int*)d_in[2];
  const float* n_feat = (const float*)d_in[3];
  const float* W1 = (const float*)d_in[4];
  const float* b1 = (const float*)d_in[5];
  const float* W2 = (const float*)d_in[6];
  const float* b2 = (const float*)d_in[7];
  const float* W3 = (const float*)d_in[8];
  const float* b3 = (const float*)d_in[9];
  const float* fW1 = (const float*)d_in[10];
  const float* fb1 = (const float*)d_in[11];
  const float* fW2 = (const float*)d_in[12];
  const float* fb2 = (const float*)d_in[13];
  const float* fW3 = (const float*)d_in[14];
  const float* fb3 = (const float*)d_in[15];
  const float* fW4 = (const float*)d_in[16];
  const float* fb4 = (const float*)d_in[17];
  float* out = (float*)d_out;

  float* ws = (float*)d_ws;
  float* norm_out = ws + OFF_NORM_OUT;
  float* norm_in = ws + OFF_NORM_IN;
  float* inv_cnt = ws + OFF_INVC;
  int* row_ptr = (int*)(ws + OFF_ROWPTR);
  int* csr = (int*)(ws + OFF_CSR);
  float* agg = ws + OFF_AGG;
  float* buf = ws + OFF_BUF;
  int* cnt_dst = (int*)(ws + OFF_CNTD);
  int* cnt_src = (int*)(ws + OFF_CNTS);
  int* bb_dst = (int*)(ws + OFF_BBD);
  int* bb_src = (int*)(ws + OFF_BBS);
  uint2* pairs = (uint2*)agg;   // alias (2*NE words == 32*NN words)
  int* srcbuf = (int*)buf;      // alias (NE words < 32*NN words)

  hipMemsetAsync(out, 0, (size_t)out_size * sizeof(float), stream);

  k_part_count<<<NPB, 256, 0, stream>>>(src, dst, cnt_dst, cnt_src);
  k_graphinfo<<<1, NG, 0, stream>>>(gid, inv_cnt);
  k_chunk_scan<<<1, 256, 0, stream>>>(cnt_dst, bb_dst, cnt_src, bb_src);
  k_part_scatter<<<NPB, 256, 0, stream>>>(src, dst, cnt_dst, cnt_src, pairs, srcbuf);
  k_bucket_csr<<<NB, 256, 0, stream>>>(pairs, bb_dst, row_ptr, norm_in, csr);
  k_bucket_deg<<<NB, 256, 0, stream>>>(srcbuf, bb_src, norm_out);
  k_norm_scale<<<(NN + 255) / 256, 256, 0, stream>>>(n_feat, norm_out, buf);

  // layer 1: gather-agg d=8, then 8->16 relu
  k_agg<8><<<(NN * 2 + 255) / 256, 256, 0, stream>>>(buf, csr, row_ptr, norm_in, agg);
  k_layer<8, 16><<<(NN + 255) / 256, 256, 0, stream>>>(agg, norm_out, W1, b1, buf);

  // layer 2: gather-agg d=16, then 16->32 relu
  k_agg<16><<<(NN * 4 + 255) / 256, 256, 0, stream>>>(buf, csr, row_ptr, norm_in, agg);
  k_layer<16, 32><<<(NN + 255) / 256, 256, 0, stream>>>(agg, norm_out, W2, b2, buf);

  // layer 3: gather-agg d=32, then tail v2 (W3+maxpool+MLP+graph-mean)
  k_agg<32><<<(NN * 8 + 255) / 256, 256, 0, stream>>>(buf, csr, row_ptr, norm_in, agg);
  k_tail2<<<(NN + TT - 1) / TT, 256, 0, stream>>>(agg, gid, W3, b3, fW1, fb1, fW2, fb2,
                                                  fW3, fb3, fW4, fb4, inv_cnt, out);
}

// Round 8
// 390.494 us; speedup vs baseline: 1.0284x; 1.0284x over previous
//
#include <hip/hip_runtime.h>
#include <stdint.h>

#define NN 100000
#define NE 1600000
#define NG 256

#define NB 196    // node buckets of 512 nodes
#define BSH 9     // bucket shift (512)
#define NPB 392   // partition blocks
#define EPB 4096  // edges per partition block

#define TT 64     // nodes per tail block

// ---------------------------------------------------------------------------
// Workspace layout (4-byte words).
//   norm_out  : [0, NN)                      float
//   norm_in   : [NN, 2NN)                    float
//   inv_cnt   : [2NN, 2NN+256)               float
//   row_ptr   : [2NN+512, 3NN+516)           int (NN+1 used, padded)
//   csr_src   : [3NN+516, +NE)               int
//   agg       : [A, A+32NN)                  float (aliases: pairs u32[NE] at A,
//                                            srcbuf u16[NE] at A+NE words)
//   buf       : [B, B+32NN)                  float (xs0 -> xs1 -> xs2)
//   cnt_dst   : [C, C+NB*NPB)                int
//   cnt_src   : [.., +NB*NPB)                int
//   bb_dst    : [.., +200)                   int (NB+1 used)
//   bb_src    : [.., +200)                   int
// ---------------------------------------------------------------------------
#define OFF_NORM_OUT 0
#define OFF_NORM_IN  (NN)
#define OFF_INVC     (2 * NN)
#define OFF_ROWPTR   (2 * NN + 512)
#define OFF_CSR      (3 * NN + 516)
#define OFF_AGG      (3 * NN + 516 + NE)
#define OFF_BUF      (OFF_AGG + 32 * NN)
#define OFF_CNTD     (OFF_BUF + 32 * NN)
#define OFF_CNTS     (OFF_CNTD + NB * NPB)
#define OFF_BBD      (OFF_CNTS + NB * NPB)
#define OFF_BBS      (OFF_BBD + 200)

// phase 1: per-(block,bucket) histograms of dst and src buckets (LDS only)
__global__ void __launch_bounds__(256) k_part_count(const int* __restrict__ src,
                                                    const int* __restrict__ dst,
                                                    int* __restrict__ cnt_dst,
                                                    int* __restrict__ cnt_src) {
  __shared__ int hd[NB], hs[NB];
  int t = threadIdx.x;
  int blk = blockIdx.x;
  for (int i = t; i < NB; i += 256) { hd[i] = 0; hs[i] = 0; }
  __syncthreads();
  int e0 = blk * EPB, e1 = min(e0 + EPB, NE);
  for (int e = e0 + t; e < e1; e += 256) {
    atomicAdd(&hd[dst[e] >> BSH], 1);
    atomicAdd(&hs[src[e] >> BSH], 1);
  }
  __syncthreads();
  for (int i = t; i < NB; i += 256) {
    cnt_dst[i * NPB + blk] = hd[i];
    cnt_src[i * NPB + blk] = hs[i];
  }
}

// phase 2: turn count matrices into exact chunk bases + bucket bases
__global__ void __launch_bounds__(256) k_chunk_scan(int* __restrict__ cnt_dst,
                                                    int* __restrict__ bb_dst,
                                                    int* __restrict__ cnt_src,
                                                    int* __restrict__ bb_src) {
  __shared__ int tot[256];
  int t = threadIdx.x;
  for (int p = 0; p < 2; ++p) {
    int* cnt = p ? cnt_src : cnt_dst;
    int* bb = p ? bb_src : bb_dst;
    int s = 0;
    if (t < NB)
      for (int k = 0; k < NPB; ++k) s += cnt[t * NPB + k];
    tot[t] = s;
    __syncthreads();
    int incl = s;
    for (int off = 1; off < 256; off <<= 1) {
      int o = (t >= off) ? tot[t - off] : 0;
      __syncthreads();
      incl += o;
      tot[t] = incl;
      __syncthreads();
    }
    int base = incl - s;  // exclusive bucket base
    if (t < NB) {
      bb[t] = base;
      int run = base;
      for (int k = 0; k < NPB; ++k) {
        int c = cnt[t * NPB + k];
        cnt[t * NPB + k] = run;
        run += c;
      }
      if (t == NB - 1) bb[NB] = run;
    }
    __syncthreads();
  }
}

// phase 3: scatter edges into bucket regions (block-private sequential cursors)
// pairs packed: (src<<9) | (dst & 511); srcbuf packed: local src id (u16)
__global__ void __launch_bounds__(256) k_part_scatter(const int* __restrict__ src,
                                                      const int* __restrict__ dst,
                                                      const int* __restrict__ cnt_dst,
                                                      const int* __restrict__ cnt_src,
                                                      uint32_t* __restrict__ pairs,
                                                      uint16_t* __restrict__ srcbuf) {
  __shared__ int cd[NB], cs[NB];
  int t = threadIdx.x;
  int blk = blockIdx.x;
  for (int i = t; i < NB; i += 256) {
    cd[i] = cnt_dst[i * NPB + blk];
    cs[i] = cnt_src[i * NPB + blk];
  }
  __syncthreads();
  int e0 = blk * EPB, e1 = min(e0 + EPB, NE);
  for (int e = e0 + t; e < e1; e += 256) {
    int s = src[e], d = dst[e];
    int pd = atomicAdd(&cd[d >> BSH], 1);
    pairs[pd] = ((uint32_t)s << 9) | (uint32_t)(d & 511);
    int ps = atomicAdd(&cs[s >> BSH], 1);
    srcbuf[ps] = (uint16_t)(s & 511);
  }
}

// phase 4: per-bucket CSR finalize: row_ptr, norm_in, csr (all bucket-local)
__global__ void __launch_bounds__(256) k_bucket_csr(const uint32_t* __restrict__ pairs,
                                                    const int* __restrict__ bb,
                                                    int* __restrict__ row_ptr,
                                                    float* __restrict__ norm_in,
                                                    int* __restrict__ csr) {
  __shared__ int hist[512], curs[512], pscan[256];
  int t = threadIdx.x;
  int b = blockIdx.x;
  int n0 = b << BSH;
  int ebase = bb[b], eend = bb[b + 1];
  hist[t] = 0;
  hist[t + 256] = 0;
  __syncthreads();
  for (int e = ebase + t; e < eend; e += 256)
    atomicAdd(&hist[pairs[e] & 511], 1);
  __syncthreads();
  int s0 = hist[2 * t], s1 = hist[2 * t + 1];
  int ps = s0 + s1;
  pscan[t] = ps;
  __syncthreads();
  int incl = ps;
  for (int off = 1; off < 256; off <<= 1) {
    int o = (t >= off) ? pscan[t - off] : 0;
    __syncthreads();
    incl += o;
    pscan[t] = incl;
    __syncthreads();
  }
  int ex = incl - ps;
  curs[2 * t] = ex;
  curs[2 * t + 1] = ex + s0;
  int n = n0 + 2 * t;
  if (n < NN) {
    row_ptr[n] = ebase + ex;
    norm_in[n] = s0 > 0 ? 1.0f / sqrtf((float)s0) : 0.0f;
  }
  if (n + 1 < NN) {
    row_ptr[n + 1] = ebase + ex + s0;
    norm_in[n + 1] = s1 > 0 ? 1.0f / sqrtf((float)s1) : 0.0f;
  }
  __syncthreads();
  for (int e = ebase + t; e < eend; e += 256) {
    uint32_t pr = pairs[e];
    int pos = atomicAdd(&curs[pr & 511], 1);
    csr[ebase + pos] = (int)(pr >> 9);
  }
  if (b == 0 && t == 0) row_ptr[NN] = NE;
}

// phase 5: per-bucket out-degree -> norm_out, fused xs0 = n_feat * norm_out
__global__ void __launch_bounds__(256) k_bucket_deg(const uint16_t* __restrict__ srcbuf,
                                                    const int* __restrict__ bb,
                                                    const float* __restrict__ n_feat,
                                                    float* __restrict__ norm_out,
                                                    float* __restrict__ xs) {
  __shared__ int hist[512];
  int t = threadIdx.x;
  int b = blockIdx.x;
  hist[t] = 0;
  hist[t + 256] = 0;
  __syncthreads();
  int e0 = bb[b], e1 = bb[b + 1];
  for (int e = e0 + t; e < e1; e += 256)
    atomicAdd(&hist[srcbuf[e]], 1);
  __syncthreads();
#pragma unroll
  for (int h = 0; h < 2; ++h) {
    int n = (b << BSH) + t + h * 256;
    if (n < NN) {
      int d = hist[t + h * 256];
      float no = d > 0 ? 1.0f / sqrtf((float)d) : 0.0f;
      norm_out[n] = no;
      float4 a = *reinterpret_cast<const float4*>(n_feat + (size_t)n * 8);
      float4 bb4 = *reinterpret_cast<const float4*>(n_feat + (size_t)n * 8 + 4);
      a.x *= no; a.y *= no; a.z *= no; a.w *= no;
      bb4.x *= no; bb4.y *= no; bb4.z *= no; bb4.w *= no;
      *reinterpret_cast<float4*>(xs + (size_t)n * 8) = a;
      *reinterpret_cast<float4*>(xs + (size_t)n * 8 + 4) = bb4;
    }
  }
}

// graph sizes via binary search on the SORTED gid array: no atomics at all.
__global__ void __launch_bounds__(NG) k_graphinfo(const int* __restrict__ gid,
                                                  float* __restrict__ inv) {
  int g = threadIdx.x;
  int lo0 = 0, hi0 = NN;
  while (lo0 < hi0) { int m = (lo0 + hi0) >> 1; if (gid[m] < g) lo0 = m + 1; else hi0 = m; }
  int lo1 = lo0, hi1 = NN;
  while (lo1 < hi1) { int m = (lo1 + hi1) >> 1; if (gid[m] < g + 1) lo1 = m + 1; else hi1 = m; }
  int c = lo1 - lo0;
  inv[g] = 1.0f / fmaxf((float)c, 1.0f);
}

// CSR gather-aggregate: agg[i] = (sum_{e in in(i)} xs[src(e)]) * norm_in[i]
template <int D>
__global__ void k_agg(const float* __restrict__ xs, const int* __restrict__ csr,
                      const int* __restrict__ row_ptr, const float* __restrict__ norm_in,
                      float* __restrict__ agg) {
  constexpr int C = D / 4;
  int t = blockIdx.x * blockDim.x + threadIdx.x;
  if (t >= NN * C) return;
  int i = t / C;
  int c = t % C;
  int e0 = row_ptr[i], e1 = row_ptr[i + 1];
  float4 acc = {0.f, 0.f, 0.f, 0.f};
  for (int e = e0; e < e1; ++e) {
    int s = csr[e];
    float4 v = *reinterpret_cast<const float4*>(xs + (size_t)s * D + c * 4);
    acc.x += v.x; acc.y += v.y; acc.z += v.z; acc.w += v.w;
  }
  float ni = norm_in[i];
  acc.x *= ni; acc.y *= ni; acc.z *= ni; acc.w *= ni;
  *reinterpret_cast<float4*>(agg + (size_t)t * 4) = acc;
}

// node update: xs_out = relu(agg @ W + b) * norm_out   (agg already * norm_in)
template <int DIN, int DOUT>
__global__ void k_layer(const float* __restrict__ agg, const float* __restrict__ norm_out,
                        const float* __restrict__ W, const float* __restrict__ b,
                        float* __restrict__ xs_out) {
  int i = blockIdx.x * blockDim.x + threadIdx.x;
  if (i >= NN) return;
  float x[DIN];
#pragma unroll
  for (int k = 0; k < DIN; ++k) x[k] = agg[(size_t)i * DIN + k];
  float no = norm_out[i];
#pragma unroll
  for (int j = 0; j < DOUT; ++j) {
    float acc = b[j];
#pragma unroll
    for (int k = 0; k < DIN; ++k) acc = fmaf(x[k], W[k * DOUT + j], acc);
    acc = fmaxf(acc, 0.f);
    xs_out[(size_t)i * DOUT + j] = acc * no;
  }
}

// ---------------------------------------------------------------------------
// Tail v4: 64 nodes/block, 4 waves, lane==node. Activations transposed in LDS
// ([feat][node], conflict-free). Weights read via wave-uniform (scalar) loads.
// fc1/fc2 computed in 2 column/k passes so A stays 64x64 -> 33KB LDS total
// -> 4 blocks/CU (the v2 version was 48.5KB -> 2 blocks/CU, s_load latency
// exposed at 2 waves/SIMD).
// ---------------------------------------------------------------------------

// MODE: 0 plain, 1 relu, 2 maxpool(2) (pool writes STRIPE/2 rows at o0)
template <int DIN, int STRIPE, int WSTRIDE, int MODE, bool INIT, bool WRITE>
__device__ __forceinline__ void phaseW(const float* __restrict__ Ain,
                                       float* __restrict__ Bout,
                                       const float* __restrict__ Wg,
                                       const float* __restrict__ bias,
                                       int c0, int o0,
                                       float* __restrict__ acc, int lane) {
  if constexpr (INIT) {
#pragma unroll
    for (int j = 0; j < STRIPE; ++j) acc[j] = bias[c0 + j];
  }
#pragma unroll
  for (int kb = 0; kb < DIN; kb += 32) {
    float xc[32];
#pragma unroll
    for (int k = 0; k < 32; ++k) xc[k] = Ain[(kb + k) * TT + lane];
#pragma unroll
    for (int k = 0; k < 32; ++k) {
      const float* wr = Wg + (kb + k) * WSTRIDE + c0;
#pragma unroll
      for (int j = 0; j < STRIPE; ++j)
        acc[j] = fmaf(xc[k], wr[j], acc[j]);
    }
  }
  if constexpr (WRITE) {
    if constexpr (MODE == 2) {
#pragma unroll
      for (int h = 0; h < STRIPE / 2; ++h)
        Bout[(o0 + h) * TT + lane] = fmaxf(acc[2 * h], acc[2 * h + 1]);
    } else {
#pragma unroll
      for (int j = 0; j < STRIPE; ++j) {
        float v = acc[j];
        if constexpr (MODE == 1) v = fmaxf(v, 0.f);
        Bout[(o0 + j) * TT + lane] = v;
      }
    }
  }
}

__global__ void __launch_bounds__(256, 4) k_tail4(
    const float* __restrict__ agg, const int* __restrict__ gid,
    const float* __restrict__ W3, const float* __restrict__ b3,
    const float* __restrict__ fW1, const float* __restrict__ fb1,
    const float* __restrict__ fW2, const float* __restrict__ fb2,
    const float* __restrict__ fW3, const float* __restrict__ fb3,
    const float* __restrict__ fW4, const float* __restrict__ fb4,
    const float* __restrict__ inv_counts, float* __restrict__ out) {
  __shared__ __align__(16) float A[64 * TT];   // 16 KB: x(rows 0..31) / q-half / s
  __shared__ __align__(16) float B[64 * TT];   // 16 KB: p / r / t(rows 0..9)
  __shared__ int sgid[TT];
  int t = threadIdx.x;
  int lane = t & 63;
  int wid = __builtin_amdgcn_readfirstlane(t >> 6);
  int nb = blockIdx.x * TT;
  int rem = min(TT, NN - nb);

  // stage x transposed: wave w writes 8-feature chunk w of each node's row
  {
    const float* srcp = agg + (size_t)(nb + lane) * 32 + wid * 8;
    float4 v0 = *reinterpret_cast<const float4*>(srcp);
    float4 v1 = *reinterpret_cast<const float4*>(srcp + 4);
    int k0 = wid * 8;
    A[(k0 + 0) * TT + lane] = v0.x;
    A[(k0 + 1) * TT + lane] = v0.y;
    A[(k0 + 2) * TT + lane] = v0.z;
    A[(k0 + 3) * TT + lane] = v0.w;
    A[(k0 + 4) * TT + lane] = v1.x;
    A[(k0 + 5) * TT + lane] = v1.y;
    A[(k0 + 6) * TT + lane] = v1.z;
    A[(k0 + 7) * TT + lane] = v1.w;
  }
  if (t < TT) sgid[t] = (nb + t < NN) ? gid[nb + t] : 0x7fffffff;
  __syncthreads();

  float accW[32];
  phaseW<32, 32, 128, 2, true, true>(A, B, W3, b3, wid * 32, wid * 16, accW, lane);
  __syncthreads();                                        // p in B
  float acc1[16], acc2[16];
  phaseW<64, 16, 128, 1, true, true>(B, A, fW1, fb1, wid * 16, wid * 16, acc1, lane);
  __syncthreads();                                        // q1 in A
  phaseW<64, 16, 64, 0, true, false>(A, A, fW2, fb2, wid * 16, 0, acc2, lane);
  __syncthreads();                                        // fc2 partial (k 0:64)
  phaseW<64, 16, 128, 1, true, true>(B, A, fW1, fb1, 64 + wid * 16, wid * 16, acc1, lane);
  __syncthreads();                                        // q2 in A (p last read here)
  phaseW<64, 16, 64, 1, false, true>(A, B, fW2 + 64 * 64, fb2, wid * 16, wid * 16, acc2, lane);
  __syncthreads();                                        // r in B
  float acc3[8];
  phaseW<64, 8, 32, 1, true, true>(B, A, fW3, fb3, wid * 8, wid * 8, acc3, lane);
  __syncthreads();                                        // s in A (rows 0..31)

  // fc4: 32 -> 10, output stored [j][64] (conflict-free)
  {
    int jn = (wid < 2) ? 4 : (wid == 2 ? 2 : 0);
    int j0 = wid * 4;
    if (jn) {
      float xc[32];
#pragma unroll
      for (int k = 0; k < 32; ++k) xc[k] = A[k * TT + lane];
      for (int jj = 0; jj < jn; ++jj) {
        float a = fb4[j0 + jj];
#pragma unroll
        for (int k = 0; k < 32; ++k) a = fmaf(xc[k], fW4[k * 10 + j0 + jj], a);
        B[(j0 + jj) * TT + lane] = a;
      }
    }
  }
  __syncthreads();

  // segmented graph-mean (gids sorted): few atomics per block
  if (t < 10) {
    int g = sgid[0];
    float run = 0.f;
    for (int n = 0; n < rem; ++n) {
      run += B[t * TT + n];
      bool last = (n == rem - 1) || (sgid[n + 1] != g);
      if (last) {
        atomicAdd(&out[g * 10 + t], run * inv_counts[g]);
        run = 0.f;
        if (n < rem - 1) g = sgid[n + 1];
      }
    }
  }
}

extern "C" void kernel_launch(void* const* d_in, const int* in_sizes, int n_in,
                              void* d_out, int out_size, void* d_ws, size_t ws_size,
                              hipStream_t stream) {
  const int* src = (const int*)d_in[0];
  const int* dst = (const int*)d_in[1];
  const int* gid = (const int*)d_in[2];
  const float* n_feat = (const float*)d_in[3];
  const float* W1 = (const float*)d_in[4];
  const float* b1 = (const float*)d_in[5];
  const float* W2 = (const float*)d_in[6];
  const float* b2 = (const float*)d_in[7];
  const float* W3 = (const float*)d_in[8];
  const float* b3 = (const float*)d_in[9];
  const float* fW1 = (const float*)d_in[10];
  const float* fb1 = (const float*)d_in[11];
  const float* fW2 = (const float*)d_in[12];
  const float* fb2 = (const float*)d_in[13];
  const float* fW3 = (const float*)d_in[14];
  const float* fb3 = (const float*)d_in[15];
  const float* fW4 = (const float*)d_in[16];
  const float* fb4 = (const float*)d_in[17];
  float* out = (float*)d_out;

  float* ws = (float*)d_ws;
  float* norm_out = ws + OFF_NORM_OUT;
  float* norm_in = ws + OFF_NORM_IN;
  float* inv_cnt = ws + OFF_INVC;
  int* row_ptr = (int*)(ws + OFF_ROWPTR);
  int* csr = (int*)(ws + OFF_CSR);
  float* agg = ws + OFF_AGG;
  float* buf = ws + OFF_BUF;
  int* cnt_dst = (int*)(ws + OFF_CNTD);
  int* cnt_src = (int*)(ws + OFF_CNTS);
  int* bb_dst = (int*)(ws + OFF_BBD);
  int* bb_src = (int*)(ws + OFF_BBS);
  uint32_t* pairs = (uint32_t*)agg;                 // NE u32 inside agg region
  uint16_t* srcbuf = (uint16_t*)((int*)agg + NE);   // NE u16, after pairs

  hipMemsetAsync(out, 0, (size_t)out_size * sizeof(float), stream);

  k_part_count<<<NPB, 256, 0, stream>>>(src, dst, cnt_dst, cnt_src);
  k_graphinfo<<<1, NG, 0, stream>>>(gid, inv_cnt);
  k_chunk_scan<<<1, 256, 0, stream>>>(cnt_dst, bb_dst, cnt_src, bb_src);
  k_part_scatter<<<NPB, 256, 0, stream>>>(src, dst, cnt_dst, cnt_src, pairs, srcbuf);
  k_bucket_csr<<<NB, 256, 0, stream>>>(pairs, bb_dst, row_ptr, norm_in, csr);
  k_bucket_deg<<<NB, 256, 0, stream>>>(srcbuf, bb_src, n_feat, norm_out, buf);

  // layer 1: gather-agg d=8, then 8->16 relu
  k_agg<8><<<(NN * 2 + 255) / 256, 256, 0, stream>>>(buf, csr, row_ptr, norm_in, agg);
  k_layer<8, 16><<<(NN + 255) / 256, 256, 0, stream>>>(agg, norm_out, W1, b1, buf);

  // layer 2: gather-agg d=16, then 16->32 relu
  k_agg<16><<<(NN * 4 + 255) / 256, 256, 0, stream>>>(buf, csr, row_ptr, norm_in, agg);
  k_layer<16, 32><<<(NN + 255) / 256, 256, 0, stream>>>(agg, norm_out, W2, b2, buf);

  // layer 3: gather-agg d=32, then tail v4 (W3+maxpool+MLP+graph-mean)
  k_agg<32><<<(NN * 8 + 255) / 256, 256, 0, stream>>>(buf, csr, row_ptr, norm_in, agg);
  k_tail4<<<(NN + TT - 1) / TT, 256, 0, stream>>>(agg, gid, W3, b3, fW1, fb1, fW2, fb2,
                                                  fW3, fb3, fW4, fb4, inv_cnt, out);
}

// Round 9
// 390.361 us; speedup vs baseline: 1.0287x; 1.0003x over previous
//
#include <hip/hip_runtime.h>
#include <stdint.h>

#define NN 100000
#define NE 1600000
#define NG 256

#define NB 196    // node buckets of 512 nodes
#define BSH 9     // bucket shift (512)
#define NPB 392   // partition blocks
#define EPB 4096  // edges per partition block

#define TT 128    // nodes per tail block (2 per lane)

// ---------------------------------------------------------------------------
// Workspace layout (4-byte words).
//   norm_out  : [0, NN)                      float
//   norm_in   : [NN, 2NN)                    float
//   inv_cnt   : [2NN, 2NN+256)               float
//   row_ptr   : [2NN+512, 3NN+516)           int (NN+1 used, padded)
//   csr_src   : [3NN+516, +NE)               int
//   agg       : [A, A+32NN)                  float (aliases: pairs u32[NE],
//                                            srcbuf u16[NE] after; xs1 later)
//   buf       : [B, B+32NN)                  float (xs0 -> xs2)
//   cnt_dst   : [C, C+NB*NPB)                int
//   cnt_src   : [.., +NB*NPB)                int
//   bb_dst    : [.., +200)                   int (NB+1 used)
//   bb_src    : [.., +200)                   int
//   tot       : [.., +2*NB)                  int
// ---------------------------------------------------------------------------
#define OFF_NORM_OUT 0
#define OFF_NORM_IN  (NN)
#define OFF_INVC     (2 * NN)
#define OFF_ROWPTR   (2 * NN + 512)
#define OFF_CSR      (3 * NN + 516)
#define OFF_AGG      (3 * NN + 516 + NE)
#define OFF_BUF      (OFF_AGG + 32 * NN)
#define OFF_CNTD     (OFF_BUF + 32 * NN)
#define OFF_CNTS     (OFF_CNTD + NB * NPB)
#define OFF_BBD      (OFF_CNTS + NB * NPB)
#define OFF_BBS      (OFF_BBD + 200)
#define OFF_TOT      (OFF_BBS + 200)

// phase 1: per-(block,bucket) histograms of dst and src buckets (LDS only)
__global__ void __launch_bounds__(256) k_part_count(const int* __restrict__ src,
                                                    const int* __restrict__ dst,
                                                    int* __restrict__ cnt_dst,
                                                    int* __restrict__ cnt_src) {
  __shared__ int hd[NB], hs[NB];
  int t = threadIdx.x;
  int blk = blockIdx.x;
  for (int i = t; i < NB; i += 256) { hd[i] = 0; hs[i] = 0; }
  __syncthreads();
  int e0 = blk * EPB, e1 = min(e0 + EPB, NE);
  for (int e = e0 + t; e < e1; e += 256) {
    atomicAdd(&hd[dst[e] >> BSH], 1);
    atomicAdd(&hs[src[e] >> BSH], 1);
  }
  __syncthreads();
  for (int i = t; i < NB; i += 256) {
    cnt_dst[i * NPB + blk] = hd[i];
    cnt_src[i * NPB + blk] = hs[i];
  }
}

// phase 2a: per-bucket totals (grid 2*NB: dst rows then src rows)
__global__ void __launch_bounds__(256) k_btot(const int* __restrict__ cnt_dst,
                                              const int* __restrict__ cnt_src,
                                              int* __restrict__ tot) {
  __shared__ int red[256];
  int m = blockIdx.x;
  const int* cnt = (m < NB) ? cnt_dst : cnt_src;
  int row = (m < NB) ? m : m - NB;
  int t = threadIdx.x;
  int s = 0;
  for (int k = t; k < NPB; k += 256) s += cnt[row * NPB + k];
  red[t] = s;
  __syncthreads();
  for (int off = 128; off; off >>= 1) {
    if (t < off) red[t] += red[t + off];
    __syncthreads();
  }
  if (t == 0) tot[m] = red[0];
}

// phase 2b: scan bucket totals -> bucket bases
__global__ void __launch_bounds__(256) k_bscan(const int* __restrict__ tot,
                                               int* __restrict__ bb_dst,
                                               int* __restrict__ bb_src) {
  __shared__ int tmp[256];
  int t = threadIdx.x;
  for (int p = 0; p < 2; ++p) {
    int* bb = p ? bb_src : bb_dst;
    int v = (t < NB) ? tot[p * NB + t] : 0;
    tmp[t] = v;
    __syncthreads();
    int incl = v;
    for (int off = 1; off < 256; off <<= 1) {
      int o = (t >= off) ? tmp[t - off] : 0;
      __syncthreads();
      incl += o;
      tmp[t] = incl;
      __syncthreads();
    }
    if (t < NB) bb[t] = incl - v;
    if (t == NB - 1) bb[NB] = incl;
    __syncthreads();
  }
}

// phase 2c: per-bucket chunk prefix (cnt row -> exclusive bases + bucket base)
__global__ void __launch_bounds__(256) k_crow(int* __restrict__ cnt_dst,
                                              int* __restrict__ cnt_src,
                                              const int* __restrict__ bb_dst,
                                              const int* __restrict__ bb_src) {
  __shared__ int tmp[256];
  int m = blockIdx.x;
  bool is_src = m >= NB;
  int row = is_src ? m - NB : m;
  int* cnt = is_src ? cnt_src : cnt_dst;
  const int* bb = is_src ? bb_src : bb_dst;
  int t = threadIdx.x;
  int i0 = 2 * t, i1 = 2 * t + 1;
  int v0 = (i0 < NPB) ? cnt[row * NPB + i0] : 0;
  int v1 = (i1 < NPB) ? cnt[row * NPB + i1] : 0;
  int ps = v0 + v1;
  tmp[t] = ps;
  __syncthreads();
  int incl = ps;
  for (int off = 1; off < 256; off <<= 1) {
    int o = (t >= off) ? tmp[t - off] : 0;
    __syncthreads();
    incl += o;
    tmp[t] = incl;
    __syncthreads();
  }
  int ex = incl - ps + bb[row];
  if (i0 < NPB) cnt[row * NPB + i0] = ex;
  if (i1 < NPB) cnt[row * NPB + i1] = ex + v0;
}

// phase 3: scatter edges into bucket regions (block-private sequential cursors)
__global__ void __launch_bounds__(256) k_part_scatter(const int* __restrict__ src,
                                                      const int* __restrict__ dst,
                                                      const int* __restrict__ cnt_dst,
                                                      const int* __restrict__ cnt_src,
                                                      uint32_t* __restrict__ pairs,
                                                      uint16_t* __restrict__ srcbuf) {
  __shared__ int cd[NB], cs[NB];
  int t = threadIdx.x;
  int blk = blockIdx.x;
  for (int i = t; i < NB; i += 256) {
    cd[i] = cnt_dst[i * NPB + blk];
    cs[i] = cnt_src[i * NPB + blk];
  }
  __syncthreads();
  int e0 = blk * EPB, e1 = min(e0 + EPB, NE);
  for (int e = e0 + t; e < e1; e += 256) {
    int s = src[e], d = dst[e];
    int pd = atomicAdd(&cd[d >> BSH], 1);
    pairs[pd] = ((uint32_t)s << 9) | (uint32_t)(d & 511);
    int ps = atomicAdd(&cs[s >> BSH], 1);
    srcbuf[ps] = (uint16_t)(s & 511);
  }
}

// phase 4: per-bucket CSR finalize: row_ptr, norm_in, csr (all bucket-local)
__global__ void __launch_bounds__(256) k_bucket_csr(const uint32_t* __restrict__ pairs,
                                                    const int* __restrict__ bb,
                                                    int* __restrict__ row_ptr,
                                                    float* __restrict__ norm_in,
                                                    int* __restrict__ csr) {
  __shared__ int hist[512], curs[512], pscan[256];
  int t = threadIdx.x;
  int b = blockIdx.x;
  int n0 = b << BSH;
  int ebase = bb[b], eend = bb[b + 1];
  hist[t] = 0;
  hist[t + 256] = 0;
  __syncthreads();
  for (int e = ebase + t; e < eend; e += 256)
    atomicAdd(&hist[pairs[e] & 511], 1);
  __syncthreads();
  int s0 = hist[2 * t], s1 = hist[2 * t + 1];
  int ps = s0 + s1;
  pscan[t] = ps;
  __syncthreads();
  int incl = ps;
  for (int off = 1; off < 256; off <<= 1) {
    int o = (t >= off) ? pscan[t - off] : 0;
    __syncthreads();
    incl += o;
    pscan[t] = incl;
    __syncthreads();
  }
  int ex = incl - ps;
  curs[2 * t] = ex;
  curs[2 * t + 1] = ex + s0;
  int n = n0 + 2 * t;
  if (n < NN) {
    row_ptr[n] = ebase + ex;
    norm_in[n] = s0 > 0 ? 1.0f / sqrtf((float)s0) : 0.0f;
  }
  if (n + 1 < NN) {
    row_ptr[n + 1] = ebase + ex + s0;
    norm_in[n + 1] = s1 > 0 ? 1.0f / sqrtf((float)s1) : 0.0f;
  }
  __syncthreads();
  for (int e = ebase + t; e < eend; e += 256) {
    uint32_t pr = pairs[e];
    int pos = atomicAdd(&curs[pr & 511], 1);
    csr[ebase + pos] = (int)(pr >> 9);
  }
  if (b == 0 && t == 0) row_ptr[NN] = NE;
}

// phase 5: per-bucket out-degree -> norm_out, fused xs0 = n_feat * norm_out
__global__ void __launch_bounds__(256) k_bucket_deg(const uint16_t* __restrict__ srcbuf,
                                                    const int* __restrict__ bb,
                                                    const float* __restrict__ n_feat,
                                                    float* __restrict__ norm_out,
                                                    float* __restrict__ xs) {
  __shared__ int hist[512];
  int t = threadIdx.x;
  int b = blockIdx.x;
  hist[t] = 0;
  hist[t + 256] = 0;
  __syncthreads();
  int e0 = bb[b], e1 = bb[b + 1];
  for (int e = e0 + t; e < e1; e += 256)
    atomicAdd(&hist[srcbuf[e]], 1);
  __syncthreads();
#pragma unroll
  for (int h = 0; h < 2; ++h) {
    int n = (b << BSH) + t + h * 256;
    if (n < NN) {
      int d = hist[t + h * 256];
      float no = d > 0 ? 1.0f / sqrtf((float)d) : 0.0f;
      norm_out[n] = no;
      float4 a = *reinterpret_cast<const float4*>(n_feat + (size_t)n * 8);
      float4 bb4 = *reinterpret_cast<const float4*>(n_feat + (size_t)n * 8 + 4);
      a.x *= no; a.y *= no; a.z *= no; a.w *= no;
      bb4.x *= no; bb4.y *= no; bb4.z *= no; bb4.w *= no;
      *reinterpret_cast<float4*>(xs + (size_t)n * 8) = a;
      *reinterpret_cast<float4*>(xs + (size_t)n * 8 + 4) = bb4;
    }
  }
}

// graph sizes via binary search on the SORTED gid array
__global__ void __launch_bounds__(NG) k_graphinfo(const int* __restrict__ gid,
                                                  float* __restrict__ inv) {
  int g = threadIdx.x;
  int lo0 = 0, hi0 = NN;
  while (lo0 < hi0) { int m = (lo0 + hi0) >> 1; if (gid[m] < g) lo0 = m + 1; else hi0 = m; }
  int lo1 = lo0, hi1 = NN;
  while (lo1 < hi1) { int m = (lo1 + hi1) >> 1; if (gid[m] < g + 1) lo1 = m + 1; else hi1 = m; }
  int c = lo1 - lo0;
  inv[g] = 1.0f / fmaxf((float)c, 1.0f);
}

// fused gather-aggregate + linear + relu + *norm_out (layers 1,2), thread/node
template <int DIN, int DOUT>
__global__ void __launch_bounds__(256) k_agglayer(
    const float* __restrict__ xs, const int* __restrict__ csr,
    const int* __restrict__ row_ptr, const float* __restrict__ norm_in,
    const float* __restrict__ norm_out, const float* __restrict__ W,
    const float* __restrict__ bvec, float* __restrict__ ys) {
  int i = blockIdx.x * 256 + threadIdx.x;
  if (i >= NN) return;
  float acc[DIN];
#pragma unroll
  for (int k = 0; k < DIN; ++k) acc[k] = 0.f;
  int e0 = row_ptr[i], e1 = row_ptr[i + 1];
  for (int e = e0; e < e1; ++e) {
    int s = csr[e];
#pragma unroll
    for (int c = 0; c < DIN / 4; ++c) {
      float4 v = *reinterpret_cast<const float4*>(xs + (size_t)s * DIN + 4 * c);
      acc[4 * c + 0] += v.x;
      acc[4 * c + 1] += v.y;
      acc[4 * c + 2] += v.z;
      acc[4 * c + 3] += v.w;
    }
  }
  float ni = norm_in[i];
#pragma unroll
  for (int k = 0; k < DIN; ++k) acc[k] *= ni;
  float no = norm_out[i];
#pragma unroll
  for (int j4 = 0; j4 < DOUT / 4; ++j4) {
    float4 y;
    float* yp = reinterpret_cast<float*>(&y);
#pragma unroll
    for (int jj = 0; jj < 4; ++jj) {
      int j = 4 * j4 + jj;
      float s = bvec[j];
#pragma unroll
      for (int k = 0; k < DIN; ++k) s = fmaf(acc[k], W[k * DOUT + j], s);
      yp[jj] = fmaxf(s, 0.f) * no;
    }
    *reinterpret_cast<float4*>(ys + (size_t)i * DOUT + 4 * j4) = y;
  }
}

// CSR gather-aggregate (layer 3 input): thread per (node, float4 chunk)
template <int D>
__global__ void k_agg(const float* __restrict__ xs, const int* __restrict__ csr,
                      const int* __restrict__ row_ptr, const float* __restrict__ norm_in,
                      float* __restrict__ agg) {
  constexpr int C = D / 4;
  int t = blockIdx.x * blockDim.x + threadIdx.x;
  if (t >= NN * C) return;
  int i = t / C;
  int c = t % C;
  int e0 = row_ptr[i], e1 = row_ptr[i + 1];
  float4 acc = {0.f, 0.f, 0.f, 0.f};
  for (int e = e0; e < e1; ++e) {
    int s = csr[e];
    float4 v = *reinterpret_cast<const float4*>(xs + (size_t)s * D + c * 4);
    acc.x += v.x; acc.y += v.y; acc.z += v.z; acc.w += v.w;
  }
  float ni = norm_in[i];
  acc.x *= ni; acc.y *= ni; acc.z *= ni; acc.w *= ni;
  *reinterpret_cast<float4*>(agg + (size_t)t * 4) = acc;
}

// ---------------------------------------------------------------------------
// Tail v5: 128 nodes/block, 4 waves, 2 nodes per lane (float2 LDS reads).
// Activations transposed [feat][128] in LDS; weights via per-lane vector
// loads (same addr across lanes -> one line, L1-resident, deep vmcnt queue).
// ---------------------------------------------------------------------------

// MODE: 0 plain, 1 relu, 2 maxpool(2)
template <int DIN, int STRIPE, int WSTRIDE, int MODE, bool INIT, bool WRITE>
__device__ __forceinline__ void phaseV(const float* __restrict__ A,
                                       float* __restrict__ B,
                                       const float* __restrict__ Wg,
                                       const float* __restrict__ bias,
                                       int c0, int o0,
                                       float* __restrict__ a0,
                                       float* __restrict__ a1, int lane) {
  if constexpr (INIT) {
#pragma unroll
    for (int j = 0; j < STRIPE; ++j) {
      float bv = bias[c0 + j];
      a0[j] = bv;
      a1[j] = bv;
    }
  }
#pragma unroll
  for (int kb = 0; kb < DIN; kb += 32) {
    float2 xc[32];
#pragma unroll
    for (int k = 0; k < 32; ++k)
      xc[k] = *reinterpret_cast<const float2*>(&A[(kb + k) * TT + (lane << 1)]);
#pragma unroll
    for (int k = 0; k < 32; ++k) {
      const float* wr = Wg + (size_t)(kb + k) * WSTRIDE + c0;
      if constexpr (STRIPE % 4 == 0 && WSTRIDE % 4 == 0) {
#pragma unroll
        for (int j4 = 0; j4 < STRIPE / 4; ++j4) {
          float4 wv = *reinterpret_cast<const float4*>(wr + 4 * j4);
          a0[4 * j4 + 0] = fmaf(xc[k].x, wv.x, a0[4 * j4 + 0]);
          a0[4 * j4 + 1] = fmaf(xc[k].x, wv.y, a0[4 * j4 + 1]);
          a0[4 * j4 + 2] = fmaf(xc[k].x, wv.z, a0[4 * j4 + 2]);
          a0[4 * j4 + 3] = fmaf(xc[k].x, wv.w, a0[4 * j4 + 3]);
          a1[4 * j4 + 0] = fmaf(xc[k].y, wv.x, a1[4 * j4 + 0]);
          a1[4 * j4 + 1] = fmaf(xc[k].y, wv.y, a1[4 * j4 + 1]);
          a1[4 * j4 + 2] = fmaf(xc[k].y, wv.z, a1[4 * j4 + 2]);
          a1[4 * j4 + 3] = fmaf(xc[k].y, wv.w, a1[4 * j4 + 3]);
        }
      } else {
#pragma unroll
        for (int j = 0; j < STRIPE; ++j) {
          float wv = wr[j];
          a0[j] = fmaf(xc[k].x, wv, a0[j]);
          a1[j] = fmaf(xc[k].y, wv, a1[j]);
        }
      }
    }
  }
  if constexpr (WRITE) {
    if constexpr (MODE == 2) {
#pragma unroll
      for (int h = 0; h < STRIPE / 2; ++h) {
        float2 r;
        r.x = fmaxf(a0[2 * h], a0[2 * h + 1]);
        r.y = fmaxf(a1[2 * h], a1[2 * h + 1]);
        *reinterpret_cast<float2*>(&B[(o0 + h) * TT + (lane << 1)]) = r;
      }
    } else {
#pragma unroll
      for (int j = 0; j < STRIPE; ++j) {
        float2 r;
        r.x = (MODE == 1) ? fmaxf(a0[j], 0.f) : a0[j];
        r.y = (MODE == 1) ? fmaxf(a1[j], 0.f) : a1[j];
        *reinterpret_cast<float2*>(&B[(o0 + j) * TT + (lane << 1)]) = r;
      }
    }
  }
}

__global__ void __launch_bounds__(256, 2) k_tail5(
    const float* __restrict__ agg, const int* __restrict__ gid,
    const float* __restrict__ W3, const float* __restrict__ b3,
    const float* __restrict__ fW1, const float* __restrict__ fb1,
    const float* __restrict__ fW2, const float* __restrict__ fb2,
    const float* __restrict__ fW3, const float* __restrict__ fb3,
    const float* __restrict__ fW4, const float* __restrict__ fb4,
    const float* __restrict__ inv_counts, float* __restrict__ out) {
  __shared__ __align__(16) float A[64 * TT];   // 32 KB
  __shared__ __align__(16) float B[64 * TT];   // 32 KB
  __shared__ int sgid[TT];
  int t = threadIdx.x;
  int lane = t & 63;
  int wid = t >> 6;  // NOT readfirstlane: keep weight loads on the vector path
  int nb = blockIdx.x * TT;
  int rem = min(TT, NN - nb);

  // stage x transposed: thread t handles node (t&127), feature half (t>>7)
  {
    int node = t & 127;
    int half = t >> 7;  // 0 or 1 -> features 0..15 / 16..31
    float4 v[4];
    if (nb + node < NN) {
      const float* srcp = agg + (size_t)(nb + node) * 32 + half * 16;
#pragma unroll
      for (int c = 0; c < 4; ++c) v[c] = *reinterpret_cast<const float4*>(srcp + 4 * c);
    } else {
#pragma unroll
      for (int c = 0; c < 4; ++c) v[c] = make_float4(0.f, 0.f, 0.f, 0.f);
    }
#pragma unroll
    for (int c = 0; c < 4; ++c) {
      int k0 = half * 16 + 4 * c;
      A[(k0 + 0) * TT + node] = v[c].x;
      A[(k0 + 1) * TT + node] = v[c].y;
      A[(k0 + 2) * TT + node] = v[c].z;
      A[(k0 + 3) * TT + node] = v[c].w;
    }
  }
  if (t < TT) sgid[t] = (nb + t < NN) ? gid[nb + t] : 0x7fffffff;
  __syncthreads();

  float a0[16], a1[16], c20[16], c21[16];
  // W3 (32->128) + maxpool -> p rows 0..63 in B
  phaseV<32, 16, 128, 2, true, true>(A, B, W3, b3, wid * 32, wid * 16, a0, a1, lane);
  phaseV<32, 16, 128, 2, true, true>(A, B, W3, b3, wid * 32 + 16, wid * 16 + 8, a0, a1, lane);
  __syncthreads();
  // fc1 cols 0..63 -> A rows 0..63
  phaseV<64, 16, 128, 1, true, true>(B, A, fW1, fb1, wid * 16, wid * 16, a0, a1, lane);
  __syncthreads();
  // fc2 partial (k 0..63), accumulate in c2*
  phaseV<64, 16, 64, 0, true, false>(A, A, fW2, fb2, wid * 16, 0, c20, c21, lane);
  __syncthreads();
  // fc1 cols 64..127 -> A rows 0..63 (overwrite)
  phaseV<64, 16, 128, 1, true, true>(B, A, fW1, fb1, 64 + wid * 16, wid * 16, a0, a1, lane);
  __syncthreads();
  // fc2 finish (k 64..127) + relu -> r rows 0..63 in B
  phaseV<64, 16, 64, 1, false, true>(A, B, fW2 + 64 * 64, fb2, wid * 16, wid * 16, c20, c21, lane);
  __syncthreads();
  // fc3 (64->32) + relu -> s rows 0..31 in A
  phaseV<64, 8, 32, 1, true, true>(B, A, fW3, fb3, wid * 8, wid * 8, a0, a1, lane);
  __syncthreads();
  // fc4 (32->10) -> t rows 0..9 in B (stride 10: scalar weight path)
  if (wid < 2)
    phaseV<32, 4, 10, 0, true, true>(A, B, fW4, fb4, wid * 4, wid * 4, a0, a1, lane);
  else if (wid == 2)
    phaseV<32, 2, 10, 0, true, true>(A, B, fW4, fb4, 8, 8, a0, a1, lane);
  __syncthreads();

  // segmented graph-mean (gids sorted): few atomics per block
  if (t < 10) {
    int g = sgid[0];
    float run = 0.f;
    for (int n = 0; n < rem; ++n) {
      run += B[t * TT + n];
      bool last = (n == rem - 1) || (sgid[n + 1] != g);
      if (last) {
        atomicAdd(&out[g * 10 + t], run * inv_counts[g]);
        run = 0.f;
        if (n < rem - 1) g = sgid[n + 1];
      }
    }
  }
}

extern "C" void kernel_launch(void* const* d_in, const int* in_sizes, int n_in,
                              void* d_out, int out_size, void* d_ws, size_t ws_size,
                              hipStream_t stream) {
  const int* src = (const int*)d_in[0];
  const int* dst = (const int*)d_in[1];
  const int* gid = (const int*)d_in[2];
  const float* n_feat = (const float*)d_in[3];
  const float* W1 = (const float*)d_in[4];
  const float* b1 = (const float*)d_in[5];
  const float* W2 = (const float*)d_in[6];
  const float* b2 = (const float*)d_in[7];
  const float* W3 = (const float*)d_in[8];
  const float* b3 = (const float*)d_in[9];
  const float* fW1 = (const float*)d_in[10];
  const float* fb1 = (const float*)d_in[11];
  const float* fW2 = (const float*)d_in[12];
  const float* fb2 = (const float*)d_in[13];
  const float* fW3 = (const float*)d_in[14];
  const float* fb3 = (const float*)d_in[15];
  const float* fW4 = (const float*)d_in[16];
  const float* fb4 = (const float*)d_in[17];
  float* out = (float*)d_out;

  float* ws = (float*)d_ws;
  float* norm_out = ws + OFF_NORM_OUT;
  float* norm_in = ws + OFF_NORM_IN;
  float* inv_cnt = ws + OFF_INVC;
  int* row_ptr = (int*)(ws + OFF_ROWPTR);
  int* csr = (int*)(ws + OFF_CSR);
  float* agg = ws + OFF_AGG;
  float* buf = ws + OFF_BUF;
  int* cnt_dst = (int*)(ws + OFF_CNTD);
  int* cnt_src = (int*)(ws + OFF_CNTS);
  int* bb_dst = (int*)(ws + OFF_BBD);
  int* bb_src = (int*)(ws + OFF_BBS);
  int* tot = (int*)(ws + OFF_TOT);
  uint32_t* pairs = (uint32_t*)agg;                 // NE u32 inside agg region
  uint16_t* srcbuf = (uint16_t*)((int*)agg + NE);   // NE u16, after pairs

  hipMemsetAsync(out, 0, (size_t)out_size * sizeof(float), stream);

  k_part_count<<<NPB, 256, 0, stream>>>(src, dst, cnt_dst, cnt_src);
  k_graphinfo<<<1, NG, 0, stream>>>(gid, inv_cnt);
  k_btot<<<2 * NB, 256, 0, stream>>>(cnt_dst, cnt_src, tot);
  k_bscan<<<1, 256, 0, stream>>>(tot, bb_dst, bb_src);
  k_crow<<<2 * NB, 256, 0, stream>>>(cnt_dst, cnt_src, bb_dst, bb_src);
  k_part_scatter<<<NPB, 256, 0, stream>>>(src, dst, cnt_dst, cnt_src, pairs, srcbuf);
  k_bucket_csr<<<NB, 256, 0, stream>>>(pairs, bb_dst, row_ptr, norm_in, csr);
  k_bucket_deg<<<NB, 256, 0, stream>>>(srcbuf, bb_src, n_feat, norm_out, buf);

  // layer 1 fused: gather(d=8) + 8->16 + relu ; xs1 into agg region
  k_agglayer<8, 16><<<(NN + 255) / 256, 256, 0, stream>>>(buf, csr, row_ptr, norm_in,
                                                          norm_out, W1, b1, agg);
  // layer 2 fused: gather(d=16) + 16->32 + relu ; xs2 into buf
  k_agglayer<16, 32><<<(NN + 255) / 256, 256, 0, stream>>>(agg, csr, row_ptr, norm_in,
                                                           norm_out, W2, b2, buf);
  // layer 3 aggregate (d=32) -> agg, then tail v5
  k_agg<32><<<(NN * 8 + 255) / 256, 256, 0, stream>>>(buf, csr, row_ptr, norm_in, agg);
  k_tail5<<<(NN + TT - 1) / TT, 256, 0, stream>>>(agg, gid, W3, b3, fW1, fb1, fW2, fb2,
                                                  fW3, fb3, fW4, fb4, inv_cnt, out);
}

// Round 10
// 312.704 us; speedup vs baseline: 1.2842x; 1.2483x over previous
//
#include <hip/hip_runtime.h>
#include <stdint.h>

#define NN 100000
#define NE 1600000
#define NG 256

#define NB 196    // node buckets of 512 nodes
#define BSH 9     // bucket shift (512)
#define NPB 392   // partition blocks
#define EPB 4096  // edges per partition block

// ---------------------------------------------------------------------------
// Workspace layout (4-byte words).
//   norm_out  : [0, NN)                      float
//   norm_in   : [NN, 2NN)                    float
//   inv_cnt   : [2NN, 2NN+256)               float
//   row_ptr   : [2NN+512, 3NN+516)           int (NN+1 used, padded)
//   csr_src   : [3NN+516, +NE)               int
//   agg       : [A, A+32NN)                  float (aliases: pairs u32[NE],
//                                            srcbuf u16[NE] after; xs1 later)
//   buf       : [B, B+32NN)                  float (xs0 -> xs2)
//   cnt_dst   : [C, C+NB*NPB)                int
//   cnt_src   : [.., +NB*NPB)                int
//   bb_dst    : [.., +200)                   int (NB+1 used)
//   bb_src    : [.., +200)                   int
//   tot       : [.., +2*NB)                  int
// ---------------------------------------------------------------------------
#define OFF_NORM_OUT 0
#define OFF_NORM_IN  (NN)
#define OFF_INVC     (2 * NN)
#define OFF_ROWPTR   (2 * NN + 512)
#define OFF_CSR      (3 * NN + 516)
#define OFF_AGG      (3 * NN + 516 + NE)
#define OFF_BUF      (OFF_AGG + 32 * NN)
#define OFF_CNTD     (OFF_BUF + 32 * NN)
#define OFF_CNTS     (OFF_CNTD + NB * NPB)
#define OFF_BBD      (OFF_CNTS + NB * NPB)
#define OFF_BBS      (OFF_BBD + 200)
#define OFF_TOT      (OFF_BBS + 200)

// phase 1: per-(block,bucket) histograms of dst and src buckets (LDS only)
__global__ void __launch_bounds__(256) k_part_count(const int* __restrict__ src,
                                                    const int* __restrict__ dst,
                                                    int* __restrict__ cnt_dst,
                                                    int* __restrict__ cnt_src) {
  __shared__ int hd[NB], hs[NB];
  int t = threadIdx.x;
  int blk = blockIdx.x;
  for (int i = t; i < NB; i += 256) { hd[i] = 0; hs[i] = 0; }
  __syncthreads();
  int e0 = blk * EPB, e1 = min(e0 + EPB, NE);
  for (int e = e0 + t; e < e1; e += 256) {
    atomicAdd(&hd[dst[e] >> BSH], 1);
    atomicAdd(&hs[src[e] >> BSH], 1);
  }
  __syncthreads();
  for (int i = t; i < NB; i += 256) {
    cnt_dst[i * NPB + blk] = hd[i];
    cnt_src[i * NPB + blk] = hs[i];
  }
}

// phase 2a: per-bucket totals (grid 2*NB: dst rows then src rows)
__global__ void __launch_bounds__(256) k_btot(const int* __restrict__ cnt_dst,
                                              const int* __restrict__ cnt_src,
                                              int* __restrict__ tot) {
  __shared__ int red[256];
  int m = blockIdx.x;
  const int* cnt = (m < NB) ? cnt_dst : cnt_src;
  int row = (m < NB) ? m : m - NB;
  int t = threadIdx.x;
  int s = 0;
  for (int k = t; k < NPB; k += 256) s += cnt[row * NPB + k];
  red[t] = s;
  __syncthreads();
  for (int off = 128; off; off >>= 1) {
    if (t < off) red[t] += red[t + off];
    __syncthreads();
  }
  if (t == 0) tot[m] = red[0];
}

// phase 2b: scan bucket totals -> bucket bases
__global__ void __launch_bounds__(256) k_bscan(const int* __restrict__ tot,
                                               int* __restrict__ bb_dst,
                                               int* __restrict__ bb_src) {
  __shared__ int tmp[256];
  int t = threadIdx.x;
  for (int p = 0; p < 2; ++p) {
    int* bb = p ? bb_src : bb_dst;
    int v = (t < NB) ? tot[p * NB + t] : 0;
    tmp[t] = v;
    __syncthreads();
    int incl = v;
    for (int off = 1; off < 256; off <<= 1) {
      int o = (t >= off) ? tmp[t - off] : 0;
      __syncthreads();
      incl += o;
      tmp[t] = incl;
      __syncthreads();
    }
    if (t < NB) bb[t] = incl - v;
    if (t == NB - 1) bb[NB] = incl;
    __syncthreads();
  }
}

// phase 2c: per-bucket chunk prefix (cnt row -> exclusive bases + bucket base)
__global__ void __launch_bounds__(256) k_crow(int* __restrict__ cnt_dst,
                                              int* __restrict__ cnt_src,
                                              const int* __restrict__ bb_dst,
                                              const int* __restrict__ bb_src) {
  __shared__ int tmp[256];
  int m = blockIdx.x;
  bool is_src = m >= NB;
  int row = is_src ? m - NB : m;
  int* cnt = is_src ? cnt_src : cnt_dst;
  const int* bb = is_src ? bb_src : bb_dst;
  int t = threadIdx.x;
  int i0 = 2 * t, i1 = 2 * t + 1;
  int v0 = (i0 < NPB) ? cnt[row * NPB + i0] : 0;
  int v1 = (i1 < NPB) ? cnt[row * NPB + i1] : 0;
  int ps = v0 + v1;
  tmp[t] = ps;
  __syncthreads();
  int incl = ps;
  for (int off = 1; off < 256; off <<= 1) {
    int o = (t >= off) ? tmp[t - off] : 0;
    __syncthreads();
    incl += o;
    tmp[t] = incl;
    __syncthreads();
  }
  int ex = incl - ps + bb[row];
  if (i0 < NPB) cnt[row * NPB + i0] = ex;
  if (i1 < NPB) cnt[row * NPB + i1] = ex + v0;
}

// phase 3: scatter edges into bucket regions (block-private sequential cursors)
__global__ void __launch_bounds__(256) k_part_scatter(const int* __restrict__ src,
                                                      const int* __restrict__ dst,
                                                      const int* __restrict__ cnt_dst,
                                                      const int* __restrict__ cnt_src,
                                                      uint32_t* __restrict__ pairs,
                                                      uint16_t* __restrict__ srcbuf) {
  __shared__ int cd[NB], cs[NB];
  int t = threadIdx.x;
  int blk = blockIdx.x;
  for (int i = t; i < NB; i += 256) {
    cd[i] = cnt_dst[i * NPB + blk];
    cs[i] = cnt_src[i * NPB + blk];
  }
  __syncthreads();
  int e0 = blk * EPB, e1 = min(e0 + EPB, NE);
  for (int e = e0 + t; e < e1; e += 256) {
    int s = src[e], d = dst[e];
    int pd = atomicAdd(&cd[d >> BSH], 1);
    pairs[pd] = ((uint32_t)s << 9) | (uint32_t)(d & 511);
    int ps = atomicAdd(&cs[s >> BSH], 1);
    srcbuf[ps] = (uint16_t)(s & 511);
  }
}

// phase 4: per-bucket CSR finalize: row_ptr, norm_in, csr (all bucket-local)
__global__ void __launch_bounds__(256) k_bucket_csr(const uint32_t* __restrict__ pairs,
                                                    const int* __restrict__ bb,
                                                    int* __restrict__ row_ptr,
                                                    float* __restrict__ norm_in,
                                                    int* __restrict__ csr) {
  __shared__ int hist[512], curs[512], pscan[256];
  int t = threadIdx.x;
  int b = blockIdx.x;
  int n0 = b << BSH;
  int ebase = bb[b], eend = bb[b + 1];
  hist[t] = 0;
  hist[t + 256] = 0;
  __syncthreads();
  for (int e = ebase + t; e < eend; e += 256)
    atomicAdd(&hist[pairs[e] & 511], 1);
  __syncthreads();
  int s0 = hist[2 * t], s1 = hist[2 * t + 1];
  int ps = s0 + s1;
  pscan[t] = ps;
  __syncthreads();
  int incl = ps;
  for (int off = 1; off < 256; off <<= 1) {
    int o = (t >= off) ? pscan[t - off] : 0;
    __syncthreads();
    incl += o;
    pscan[t] = incl;
    __syncthreads();
  }
  int ex = incl - ps;
  curs[2 * t] = ex;
  curs[2 * t + 1] = ex + s0;
  int n = n0 + 2 * t;
  if (n < NN) {
    row_ptr[n] = ebase + ex;
    norm_in[n] = s0 > 0 ? 1.0f / sqrtf((float)s0) : 0.0f;
  }
  if (n + 1 < NN) {
    row_ptr[n + 1] = ebase + ex + s0;
    norm_in[n + 1] = s1 > 0 ? 1.0f / sqrtf((float)s1) : 0.0f;
  }
  __syncthreads();
  for (int e = ebase + t; e < eend; e += 256) {
    uint32_t pr = pairs[e];
    int pos = atomicAdd(&curs[pr & 511], 1);
    csr[ebase + pos] = (int)(pr >> 9);
  }
  if (b == 0 && t == 0) row_ptr[NN] = NE;
}

// phase 5: per-bucket out-degree -> norm_out, fused xs0 = n_feat * norm_out
__global__ void __launch_bounds__(256) k_bucket_deg(const uint16_t* __restrict__ srcbuf,
                                                    const int* __restrict__ bb,
                                                    const float* __restrict__ n_feat,
                                                    float* __restrict__ norm_out,
                                                    float* __restrict__ xs) {
  __shared__ int hist[512];
  int t = threadIdx.x;
  int b = blockIdx.x;
  hist[t] = 0;
  hist[t + 256] = 0;
  __syncthreads();
  int e0 = bb[b], e1 = bb[b + 1];
  for (int e = e0 + t; e < e1; e += 256)
    atomicAdd(&hist[srcbuf[e]], 1);
  __syncthreads();
#pragma unroll
  for (int h = 0; h < 2; ++h) {
    int n = (b << BSH) + t + h * 256;
    if (n < NN) {
      int d = hist[t + h * 256];
      float no = d > 0 ? 1.0f / sqrtf((float)d) : 0.0f;
      norm_out[n] = no;
      float4 a = *reinterpret_cast<const float4*>(n_feat + (size_t)n * 8);
      float4 bb4 = *reinterpret_cast<const float4*>(n_feat + (size_t)n * 8 + 4);
      a.x *= no; a.y *= no; a.z *= no; a.w *= no;
      bb4.x *= no; bb4.y *= no; bb4.z *= no; bb4.w *= no;
      *reinterpret_cast<float4*>(xs + (size_t)n * 8) = a;
      *reinterpret_cast<float4*>(xs + (size_t)n * 8 + 4) = bb4;
    }
  }
}

// graph sizes via binary search on the SORTED gid array
__global__ void __launch_bounds__(NG) k_graphinfo(const int* __restrict__ gid,
                                                  float* __restrict__ inv) {
  int g = threadIdx.x;
  int lo0 = 0, hi0 = NN;
  while (lo0 < hi0) { int m = (lo0 + hi0) >> 1; if (gid[m] < g) lo0 = m + 1; else hi0 = m; }
  int lo1 = lo0, hi1 = NN;
  while (lo1 < hi1) { int m = (lo1 + hi1) >> 1; if (gid[m] < g + 1) lo1 = m + 1; else hi1 = m; }
  int c = lo1 - lo0;
  inv[g] = 1.0f / fmaxf((float)c, 1.0f);
}

// fused gather-aggregate + linear + relu + *norm_out (layers 1,2), thread/node
template <int DIN, int DOUT>
__global__ void __launch_bounds__(256) k_agglayer(
    const float* __restrict__ xs, const int* __restrict__ csr,
    const int* __restrict__ row_ptr, const float* __restrict__ norm_in,
    const float* __restrict__ norm_out, const float* __restrict__ W,
    const float* __restrict__ bvec, float* __restrict__ ys) {
  int i = blockIdx.x * 256 + threadIdx.x;
  if (i >= NN) return;
  float acc[DIN];
#pragma unroll
  for (int k = 0; k < DIN; ++k) acc[k] = 0.f;
  int e0 = row_ptr[i], e1 = row_ptr[i + 1];
  for (int e = e0; e < e1; ++e) {
    int s = csr[e];
#pragma unroll
    for (int c = 0; c < DIN / 4; ++c) {
      float4 v = *reinterpret_cast<const float4*>(xs + (size_t)s * DIN + 4 * c);
      acc[4 * c + 0] += v.x;
      acc[4 * c + 1] += v.y;
      acc[4 * c + 2] += v.z;
      acc[4 * c + 3] += v.w;
    }
  }
  float ni = norm_in[i];
#pragma unroll
  for (int k = 0; k < DIN; ++k) acc[k] *= ni;
  float no = norm_out[i];
#pragma unroll
  for (int j4 = 0; j4 < DOUT / 4; ++j4) {
    float4 y;
    float* yp = reinterpret_cast<float*>(&y);
#pragma unroll
    for (int jj = 0; jj < 4; ++jj) {
      int j = 4 * j4 + jj;
      float s = bvec[j];
#pragma unroll
      for (int k = 0; k < DIN; ++k) s = fmaf(acc[k], W[k * DOUT + j], s);
      yp[jj] = fmaxf(s, 0.f) * no;
    }
    *reinterpret_cast<float4*>(ys + (size_t)i * DOUT + 4 * j4) = y;
  }
}

// CSR gather-aggregate (layer 3 input): thread per (node, float4 chunk)
template <int D>
__global__ void k_agg(const float* __restrict__ xs, const int* __restrict__ csr,
                      const int* __restrict__ row_ptr, const float* __restrict__ norm_in,
                      float* __restrict__ agg) {
  constexpr int C = D / 4;
  int t = blockIdx.x * blockDim.x + threadIdx.x;
  if (t >= NN * C) return;
  int i = t / C;
  int c = t % C;
  int e0 = row_ptr[i], e1 = row_ptr[i + 1];
  float4 acc = {0.f, 0.f, 0.f, 0.f};
  for (int e = e0; e < e1; ++e) {
    int s = csr[e];
    float4 v = *reinterpret_cast<const float4*>(xs + (size_t)s * D + c * 4);
    acc.x += v.x; acc.y += v.y; acc.z += v.z; acc.w += v.w;
  }
  float ni = norm_in[i];
  acc.x *= ni; acc.y *= ni; acc.z *= ni; acc.w *= ni;
  *reinterpret_cast<float4*>(agg + (size_t)t * 4) = acc;
}

// ---------------------------------------------------------------------------
// Tail v6: round-6 structure (32 nodes/block, weights in LDS, acts in LDS)
// + software-pipelined weight staging: double-buffered 2x16KB wbuf, global
// loads for chunk i+1 issued BEFORE computing chunk i, LDS writes after.
// ---------------------------------------------------------------------------

// chunked GEMM phase: C[32 x DOUT] (+)= A[32 x DINC] @ Wl[DINC x DOUT]
template <int DINC, int DOUT, int MT, int NT, bool INIT, bool WRITE, int MODE>
__device__ __forceinline__ void phase_c(const float* __restrict__ A, int SA,
                                        float* __restrict__ B, int SB,
                                        const float* __restrict__ wl,
                                        const float* __restrict__ bias,
                                        float* __restrict__ acc, int t) {
  constexpr int OG = DOUT / NT;
  static_assert((32 / MT) * OG == 256, "tile mapping must cover 256 threads");
  int og = t % OG;
  int ng = t / OG;
  int n0 = ng * MT;
  int j0 = og * NT;
  if constexpr (INIT) {
#pragma unroll
    for (int m = 0; m < MT; ++m)
#pragma unroll
      for (int jj = 0; jj < NT; ++jj) acc[m * NT + jj] = bias[j0 + jj];
  }
#pragma unroll 4
  for (int k = 0; k < DINC; k += 2) {
    float w0[NT], w1[NT];
    if constexpr (NT == 4) {
      float4 a4 = *reinterpret_cast<const float4*>(wl + k * DOUT + j0);
      float4 b4 = *reinterpret_cast<const float4*>(wl + (k + 1) * DOUT + j0);
      w0[0] = a4.x; w0[1] = a4.y; w0[2] = a4.z; w0[3] = a4.w;
      w1[0] = b4.x; w1[1] = b4.y; w1[2] = b4.z; w1[3] = b4.w;
    } else {
      float2 a2 = *reinterpret_cast<const float2*>(wl + k * DOUT + j0);
      float2 b2 = *reinterpret_cast<const float2*>(wl + (k + 1) * DOUT + j0);
      w0[0] = a2.x; w0[1] = a2.y;
      w1[0] = b2.x; w1[1] = b2.y;
    }
#pragma unroll
    for (int m = 0; m < MT; ++m) {
      float2 a = *reinterpret_cast<const float2*>(A + (n0 + m) * SA + k);
#pragma unroll
      for (int jj = 0; jj < NT; ++jj) {
        acc[m * NT + jj] = fmaf(a.x, w0[jj], acc[m * NT + jj]);
        acc[m * NT + jj] = fmaf(a.y, w1[jj], acc[m * NT + jj]);
      }
    }
  }
  if constexpr (WRITE) {
    if constexpr (MODE == 2) {
#pragma unroll
      for (int m = 0; m < MT; ++m)
#pragma unroll
        for (int h = 0; h < NT / 2; ++h)
          B[(n0 + m) * SB + og * (NT / 2) + h] =
              fmaxf(acc[m * NT + 2 * h], acc[m * NT + 2 * h + 1]);
    } else {
#pragma unroll
      for (int m = 0; m < MT; ++m)
#pragma unroll
        for (int jj = 0; jj < NT; ++jj) {
          float v = acc[m * NT + jj];
          if constexpr (MODE == 1) v = fmaxf(v, 0.f);
          B[(n0 + m) * SB + j0 + jj] = v;
        }
    }
  }
}

// issue global loads for a weight chunk (nq quarters of 1024 floats)
template <int NQ>
__device__ __forceinline__ void loadc(const float* __restrict__ g, int t, float4* v) {
#pragma unroll
  for (int j = 0; j < NQ; ++j)
    v[j] = *reinterpret_cast<const float4*>(g + j * 1024 + t * 4);
}
// commit staged registers to LDS
template <int NQ>
__device__ __forceinline__ void writec(float* __restrict__ lds, int t, const float4* v) {
#pragma unroll
  for (int j = 0; j < NQ; ++j)
    *reinterpret_cast<float4*>(lds + j * 1024 + t * 4) = v[j];
}

__global__ void __launch_bounds__(256) k_tail6(
    const float* __restrict__ agg, const int* __restrict__ gid,
    const float* __restrict__ W3, const float* __restrict__ b3,
    const float* __restrict__ fW1, const float* __restrict__ fb1,
    const float* __restrict__ fW2, const float* __restrict__ fb2,
    const float* __restrict__ fW3, const float* __restrict__ fb3,
    const float* __restrict__ fW4, const float* __restrict__ fb4,
    const float* __restrict__ inv_counts, float* __restrict__ out) {
  __shared__ __align__(16) float Abuf[32 * 130];  // x(34) / q(130) / s(34)
  __shared__ __align__(16) float Bbuf[32 * 66];   // p(66) / r(66) / t(12)
  __shared__ __align__(16) float wbuf[2][4096];   // 2 x 16KB weight chunks
  __shared__ int sgid[32];
  int t = threadIdx.x;
  int nb = blockIdx.x * 32;

  // stage x = agg[32 nodes x 32] into Abuf (stride 34)
  {
    float4 v = *reinterpret_cast<const float4*>(agg + (size_t)nb * 32 + t * 4);
    int n = t / 8, k = (t % 8) * 4;
    Abuf[n * 34 + k + 0] = v.x;
    Abuf[n * 34 + k + 1] = v.y;
    Abuf[n * 34 + k + 2] = v.z;
    Abuf[n * 34 + k + 3] = v.w;
  }
  if (t < 32) sgid[t] = gid[nb + t];
  // prologue: W3 chunk -> wbuf[0] (not overlapped)
  float4 st[4];
  loadc<4>(W3, t, st);
  writec<4>(wbuf[0], t, st);
  __syncthreads();

  float acc[16];
  // S0: W3 (32->128) + maxpool -> p in Bbuf       | stage fc1a -> wbuf[1]
  loadc<4>(fW1, t, st);
  phase_c<32, 128, 4, 4, true, true, 2>(Abuf, 34, Bbuf, 66, wbuf[0], b3, acc, t);
  writec<4>(wbuf[1], t, st);
  __syncthreads();
  // S1: fc1 k 0..31 (accumulate)                  | stage fc1b -> wbuf[0]
  loadc<4>(fW1 + 32 * 128, t, st);
  phase_c<32, 128, 4, 4, true, false, 0>(Bbuf, 66, nullptr, 0, wbuf[1], fb1, acc, t);
  writec<4>(wbuf[0], t, st);
  __syncthreads();
  // S2: fc1 k 32..63, finish + relu -> q in Abuf  | stage fc2a -> wbuf[1]
  loadc<4>(fW2, t, st);
  phase_c<32, 128, 4, 4, false, true, 1>(Bbuf + 32, 66, Abuf, 130, wbuf[0], fb1, acc, t);
  writec<4>(wbuf[1], t, st);
  __syncthreads();
  // S3: fc2 k 0..63 (accumulate)                  | stage fc2b -> wbuf[0]
  loadc<4>(fW2 + 64 * 64, t, st);
  phase_c<64, 64, 2, 4, true, false, 0>(Abuf, 130, nullptr, 0, wbuf[1], fb2, acc, t);
  writec<4>(wbuf[0], t, st);
  __syncthreads();
  // S4: fc2 k 64..127, finish + relu -> r in Bbuf | stage fc3 -> wbuf[1]
  loadc<2>(fW3, t, st);
  phase_c<64, 64, 2, 4, false, true, 1>(Abuf + 64, 130, Bbuf, 66, wbuf[0], fb2, acc, t);
  writec<2>(wbuf[1], t, st);
  __syncthreads();
  // S5: fc3 (64->32) + relu -> s in Abuf (stride 34)
  phase_c<64, 32, 2, 2, true, true, 1>(Bbuf, 66, Abuf, 34, wbuf[1], fb3, acc, t);
  __syncthreads();
  // S6: fc4 (32->10) from global weights (tiny, L1-hot) -> Bbuf [n*12+j]
  for (int idx = t; idx < 320; idx += 256) {
    int n = idx / 10, j = idx % 10;
    float a = fb4[j];
#pragma unroll
    for (int k = 0; k < 32; ++k) a = fmaf(Abuf[n * 34 + k], fW4[k * 10 + j], a);
    Bbuf[n * 12 + j] = a;
  }
  __syncthreads();
  // segmented graph-mean reduce (gids sorted): one atomic per (segment, j)
  if (t < 10) {
    int g = sgid[0];
    float run = 0.f;
    for (int n = 0; n < 32; ++n) {
      run += Bbuf[n * 12 + t];
      bool last = (n == 31) || (sgid[n + 1] != g);
      if (last) {
        atomicAdd(&out[g * 10 + t], run * inv_counts[g]);
        run = 0.f;
        if (n < 31) g = sgid[n + 1];
      }
    }
  }
}

extern "C" void kernel_launch(void* const* d_in, const int* in_sizes, int n_in,
                              void* d_out, int out_size, void* d_ws, size_t ws_size,
                              hipStream_t stream) {
  const int* src = (const int*)d_in[0];
  const int* dst = (const int*)d_in[1];
  const int* gid = (const int*)d_in[2];
  const float* n_feat = (const float*)d_in[3];
  const float* W1 = (const float*)d_in[4];
  const float* b1 = (const float*)d_in[5];
  const float* W2 = (const float*)d_in[6];
  const float* b2 = (const float*)d_in[7];
  const float* W3 = (const float*)d_in[8];
  const float* b3 = (const float*)d_in[9];
  const float* fW1 = (const float*)d_in[10];
  const float* fb1 = (const float*)d_in[11];
  const float* fW2 = (const float*)d_in[12];
  const float* fb2 = (const float*)d_in[13];
  const float* fW3 = (const float*)d_in[14];
  const float* fb3 = (const float*)d_in[15];
  const float* fW4 = (const float*)d_in[16];
  const float* fb4 = (const float*)d_in[17];
  float* out = (float*)d_out;

  float* ws = (float*)d_ws;
  float* norm_out = ws + OFF_NORM_OUT;
  float* norm_in = ws + OFF_NORM_IN;
  float* inv_cnt = ws + OFF_INVC;
  int* row_ptr = (int*)(ws + OFF_ROWPTR);
  int* csr = (int*)(ws + OFF_CSR);
  float* agg = ws + OFF_AGG;
  float* buf = ws + OFF_BUF;
  int* cnt_dst = (int*)(ws + OFF_CNTD);
  int* cnt_src = (int*)(ws + OFF_CNTS);
  int* bb_dst = (int*)(ws + OFF_BBD);
  int* bb_src = (int*)(ws + OFF_BBS);
  int* tot = (int*)(ws + OFF_TOT);
  uint32_t* pairs = (uint32_t*)agg;                 // NE u32 inside agg region
  uint16_t* srcbuf = (uint16_t*)((int*)agg + NE);   // NE u16, after pairs

  hipMemsetAsync(out, 0, (size_t)out_size * sizeof(float), stream);

  k_part_count<<<NPB, 256, 0, stream>>>(src, dst, cnt_dst, cnt_src);
  k_graphinfo<<<1, NG, 0, stream>>>(gid, inv_cnt);
  k_btot<<<2 * NB, 256, 0, stream>>>(cnt_dst, cnt_src, tot);
  k_bscan<<<1, 256, 0, stream>>>(tot, bb_dst, bb_src);
  k_crow<<<2 * NB, 256, 0, stream>>>(cnt_dst, cnt_src, bb_dst, bb_src);
  k_part_scatter<<<NPB, 256, 0, stream>>>(src, dst, cnt_dst, cnt_src, pairs, srcbuf);
  k_bucket_csr<<<NB, 256, 0, stream>>>(pairs, bb_dst, row_ptr, norm_in, csr);
  k_bucket_deg<<<NB, 256, 0, stream>>>(srcbuf, bb_src, n_feat, norm_out, buf);

  // layer 1 fused: gather(d=8) + 8->16 + relu ; xs1 into agg region
  k_agglayer<8, 16><<<(NN + 255) / 256, 256, 0, stream>>>(buf, csr, row_ptr, norm_in,
                                                          norm_out, W1, b1, agg);
  // layer 2 fused: gather(d=16) + 16->32 + relu ; xs2 into buf
  k_agglayer<16, 32><<<(NN + 255) / 256, 256, 0, stream>>>(agg, csr, row_ptr, norm_in,
                                                           norm_out, W2, b2, buf);
  // layer 3 aggregate (d=32) -> agg, then tail v6
  k_agg<32><<<(NN * 8 + 255) / 256, 256, 0, stream>>>(buf, csr, row_ptr, norm_in, agg);
  k_tail6<<<NN / 32, 256, 0, stream>>>(agg, gid, W3, b3, fW1, fb1, fW2, fb2,
                                       fW3, fb3, fW4, fb4, inv_cnt, out);
}

// Round 11
// 280.861 us; speedup vs baseline: 1.4298x; 1.1134x over previous
//
#include <hip/hip_runtime.h>
#include <stdint.h>

#define NN 100000
#define NE 1600000
#define NG 256

#define NB 196    // node buckets of 512 nodes
#define BSH 9     // bucket shift (512)
#define NPB 392   // partition blocks
#define EPB 4096  // edges per partition block

typedef float f32x4 __attribute__((ext_vector_type(4)));
typedef short s16x8 __attribute__((ext_vector_type(8)));

// bf16 weight buffer layout (elems), [N][K] transposed, XOR-swizzled
#define WT_W3 0        // [128][32]  4096  swz (n&3)<<3
#define WT_F1 4096     // [128][64]  8192  swz (n&7)<<3
#define WT_F2 12288    // [64][128]  8192  swz (n&7)<<3
#define WT_F3 20480    // [32][64]   2048  swz (n&7)<<3
#define WT_F4 22528    // [16][32]   512   swz (n&3)<<3, rows 10..15 zero
#define WT_TOT 23040

// ---------------------------------------------------------------------------
// Workspace layout (4-byte words).
// ---------------------------------------------------------------------------
#define OFF_NORM_OUT 0
#define OFF_NORM_IN  (NN)
#define OFF_INVC     (2 * NN)
#define OFF_ROWPTR   (2 * NN + 512)
#define OFF_CSR      (3 * NN + 516)
#define OFF_AGG      (3 * NN + 516 + NE)
#define OFF_BUF      (OFF_AGG + 32 * NN)
#define OFF_CNTD     (OFF_BUF + 32 * NN)
#define OFF_CNTS     (OFF_CNTD + NB * NPB)
#define OFF_BBD      (OFF_CNTS + NB * NPB)
#define OFF_BBS      (OFF_BBD + 200)
#define OFF_TOT      (OFF_BBS + 200)
#define OFF_WT       (OFF_TOT + 400)   // 23040 ushorts = 11520 words

__device__ __forceinline__ unsigned short f2bf(float f) {
  uint32_t u = __float_as_uint(f);
  u += 0x7fff + ((u >> 16) & 1);  // round to nearest even
  return (unsigned short)(u >> 16);
}

// ---------------- graph setup (unchanged from round 10) --------------------
__global__ void __launch_bounds__(256) k_part_count(const int* __restrict__ src,
                                                    const int* __restrict__ dst,
                                                    int* __restrict__ cnt_dst,
                                                    int* __restrict__ cnt_src) {
  __shared__ int hd[NB], hs[NB];
  int t = threadIdx.x;
  int blk = blockIdx.x;
  for (int i = t; i < NB; i += 256) { hd[i] = 0; hs[i] = 0; }
  __syncthreads();
  int e0 = blk * EPB, e1 = min(e0 + EPB, NE);
  for (int e = e0 + t; e < e1; e += 256) {
    atomicAdd(&hd[dst[e] >> BSH], 1);
    atomicAdd(&hs[src[e] >> BSH], 1);
  }
  __syncthreads();
  for (int i = t; i < NB; i += 256) {
    cnt_dst[i * NPB + blk] = hd[i];
    cnt_src[i * NPB + blk] = hs[i];
  }
}

__global__ void __launch_bounds__(256) k_btot(const int* __restrict__ cnt_dst,
                                              const int* __restrict__ cnt_src,
                                              int* __restrict__ tot) {
  __shared__ int red[256];
  int m = blockIdx.x;
  const int* cnt = (m < NB) ? cnt_dst : cnt_src;
  int row = (m < NB) ? m : m - NB;
  int t = threadIdx.x;
  int s = 0;
  for (int k = t; k < NPB; k += 256) s += cnt[row * NPB + k];
  red[t] = s;
  __syncthreads();
  for (int off = 128; off; off >>= 1) {
    if (t < off) red[t] += red[t + off];
    __syncthreads();
  }
  if (t == 0) tot[m] = red[0];
}

__global__ void __launch_bounds__(256) k_bscan(const int* __restrict__ tot,
                                               int* __restrict__ bb_dst,
                                               int* __restrict__ bb_src) {
  __shared__ int tmp[256];
  int t = threadIdx.x;
  for (int p = 0; p < 2; ++p) {
    int* bb = p ? bb_src : bb_dst;
    int v = (t < NB) ? tot[p * NB + t] : 0;
    tmp[t] = v;
    __syncthreads();
    int incl = v;
    for (int off = 1; off < 256; off <<= 1) {
      int o = (t >= off) ? tmp[t - off] : 0;
      __syncthreads();
      incl += o;
      tmp[t] = incl;
      __syncthreads();
    }
    if (t < NB) bb[t] = incl - v;
    if (t == NB - 1) bb[NB] = incl;
    __syncthreads();
  }
}

__global__ void __launch_bounds__(256) k_crow(int* __restrict__ cnt_dst,
                                              int* __restrict__ cnt_src,
                                              const int* __restrict__ bb_dst,
                                              const int* __restrict__ bb_src) {
  __shared__ int tmp[256];
  int m = blockIdx.x;
  bool is_src = m >= NB;
  int row = is_src ? m - NB : m;
  int* cnt = is_src ? cnt_src : cnt_dst;
  const int* bb = is_src ? bb_src : bb_dst;
  int t = threadIdx.x;
  int i0 = 2 * t, i1 = 2 * t + 1;
  int v0 = (i0 < NPB) ? cnt[row * NPB + i0] : 0;
  int v1 = (i1 < NPB) ? cnt[row * NPB + i1] : 0;
  int ps = v0 + v1;
  tmp[t] = ps;
  __syncthreads();
  int incl = ps;
  for (int off = 1; off < 256; off <<= 1) {
    int o = (t >= off) ? tmp[t - off] : 0;
    __syncthreads();
    incl += o;
    tmp[t] = incl;
    __syncthreads();
  }
  int ex = incl - ps + bb[row];
  if (i0 < NPB) cnt[row * NPB + i0] = ex;
  if (i1 < NPB) cnt[row * NPB + i1] = ex + v0;
}

__global__ void __launch_bounds__(256) k_part_scatter(const int* __restrict__ src,
                                                      const int* __restrict__ dst,
                                                      const int* __restrict__ cnt_dst,
                                                      const int* __restrict__ cnt_src,
                                                      uint32_t* __restrict__ pairs,
                                                      uint16_t* __restrict__ srcbuf) {
  __shared__ int cd[NB], cs[NB];
  int t = threadIdx.x;
  int blk = blockIdx.x;
  for (int i = t; i < NB; i += 256) {
    cd[i] = cnt_dst[i * NPB + blk];
    cs[i] = cnt_src[i * NPB + blk];
  }
  __syncthreads();
  int e0 = blk * EPB, e1 = min(e0 + EPB, NE);
  for (int e = e0 + t; e < e1; e += 256) {
    int s = src[e], d = dst[e];
    int pd = atomicAdd(&cd[d >> BSH], 1);
    pairs[pd] = ((uint32_t)s << 9) | (uint32_t)(d & 511);
    int ps = atomicAdd(&cs[s >> BSH], 1);
    srcbuf[ps] = (uint16_t)(s & 511);
  }
}

__global__ void __launch_bounds__(256) k_bucket_csr(const uint32_t* __restrict__ pairs,
                                                    const int* __restrict__ bb,
                                                    int* __restrict__ row_ptr,
                                                    float* __restrict__ norm_in,
                                                    int* __restrict__ csr) {
  __shared__ int hist[512], curs[512], pscan[256];
  int t = threadIdx.x;
  int b = blockIdx.x;
  int n0 = b << BSH;
  int ebase = bb[b], eend = bb[b + 1];
  hist[t] = 0;
  hist[t + 256] = 0;
  __syncthreads();
  for (int e = ebase + t; e < eend; e += 256)
    atomicAdd(&hist[pairs[e] & 511], 1);
  __syncthreads();
  int s0 = hist[2 * t], s1 = hist[2 * t + 1];
  int ps = s0 + s1;
  pscan[t] = ps;
  __syncthreads();
  int incl = ps;
  for (int off = 1; off < 256; off <<= 1) {
    int o = (t >= off) ? pscan[t - off] : 0;
    __syncthreads();
    incl += o;
    pscan[t] = incl;
    __syncthreads();
  }
  int ex = incl - ps;
  curs[2 * t] = ex;
  curs[2 * t + 1] = ex + s0;
  int n = n0 + 2 * t;
  if (n < NN) {
    row_ptr[n] = ebase + ex;
    norm_in[n] = s0 > 0 ? 1.0f / sqrtf((float)s0) : 0.0f;
  }
  if (n + 1 < NN) {
    row_ptr[n + 1] = ebase + ex + s0;
    norm_in[n + 1] = s1 > 0 ? 1.0f / sqrtf((float)s1) : 0.0f;
  }
  __syncthreads();
  for (int e = ebase + t; e < eend; e += 256) {
    uint32_t pr = pairs[e];
    int pos = atomicAdd(&curs[pr & 511], 1);
    csr[ebase + pos] = (int)(pr >> 9);
  }
  if (b == 0 && t == 0) row_ptr[NN] = NE;
}

__global__ void __launch_bounds__(256) k_bucket_deg(const uint16_t* __restrict__ srcbuf,
                                                    const int* __restrict__ bb,
                                                    const float* __restrict__ n_feat,
                                                    float* __restrict__ norm_out,
                                                    float* __restrict__ xs) {
  __shared__ int hist[512];
  int t = threadIdx.x;
  int b = blockIdx.x;
  hist[t] = 0;
  hist[t + 256] = 0;
  __syncthreads();
  int e0 = bb[b], e1 = bb[b + 1];
  for (int e = e0 + t; e < e1; e += 256)
    atomicAdd(&hist[srcbuf[e]], 1);
  __syncthreads();
#pragma unroll
  for (int h = 0; h < 2; ++h) {
    int n = (b << BSH) + t + h * 256;
    if (n < NN) {
      int d = hist[t + h * 256];
      float no = d > 0 ? 1.0f / sqrtf((float)d) : 0.0f;
      norm_out[n] = no;
      float4 a = *reinterpret_cast<const float4*>(n_feat + (size_t)n * 8);
      float4 bb4 = *reinterpret_cast<const float4*>(n_feat + (size_t)n * 8 + 4);
      a.x *= no; a.y *= no; a.z *= no; a.w *= no;
      bb4.x *= no; bb4.y *= no; bb4.z *= no; bb4.w *= no;
      *reinterpret_cast<float4*>(xs + (size_t)n * 8) = a;
      *reinterpret_cast<float4*>(xs + (size_t)n * 8 + 4) = bb4;
    }
  }
}

__global__ void __launch_bounds__(NG) k_graphinfo(const int* __restrict__ gid,
                                                  float* __restrict__ inv) {
  int g = threadIdx.x;
  int lo0 = 0, hi0 = NN;
  while (lo0 < hi0) { int m = (lo0 + hi0) >> 1; if (gid[m] < g) lo0 = m + 1; else hi0 = m; }
  int lo1 = lo0, hi1 = NN;
  while (lo1 < hi1) { int m = (lo1 + hi1) >> 1; if (gid[m] < g + 1) lo1 = m + 1; else hi1 = m; }
  int c = lo1 - lo0;
  inv[g] = 1.0f / fmaxf((float)c, 1.0f);
}

template <int DIN, int DOUT>
__global__ void __launch_bounds__(256) k_agglayer(
    const float* __restrict__ xs, const int* __restrict__ csr,
    const int* __restrict__ row_ptr, const float* __restrict__ norm_in,
    const float* __restrict__ norm_out, const float* __restrict__ W,
    const float* __restrict__ bvec, float* __restrict__ ys) {
  int i = blockIdx.x * 256 + threadIdx.x;
  if (i >= NN) return;
  float acc[DIN];
#pragma unroll
  for (int k = 0; k < DIN; ++k) acc[k] = 0.f;
  int e0 = row_ptr[i], e1 = row_ptr[i + 1];
  for (int e = e0; e < e1; ++e) {
    int s = csr[e];
#pragma unroll
    for (int c = 0; c < DIN / 4; ++c) {
      float4 v = *reinterpret_cast<const float4*>(xs + (size_t)s * DIN + 4 * c);
      acc[4 * c + 0] += v.x;
      acc[4 * c + 1] += v.y;
      acc[4 * c + 2] += v.z;
      acc[4 * c + 3] += v.w;
    }
  }
  float ni = norm_in[i];
#pragma unroll
  for (int k = 0; k < DIN; ++k) acc[k] *= ni;
  float no = norm_out[i];
#pragma unroll
  for (int j4 = 0; j4 < DOUT / 4; ++j4) {
    float4 y;
    float* yp = reinterpret_cast<float*>(&y);
#pragma unroll
    for (int jj = 0; jj < 4; ++jj) {
      int j = 4 * j4 + jj;
      float s = bvec[j];
#pragma unroll
      for (int k = 0; k < DIN; ++k) s = fmaf(acc[k], W[k * DOUT + j], s);
      yp[jj] = fmaxf(s, 0.f) * no;
    }
    *reinterpret_cast<float4*>(ys + (size_t)i * DOUT + 4 * j4) = y;
  }
}

template <int D>
__global__ void k_agg(const float* __restrict__ xs, const int* __restrict__ csr,
                      const int* __restrict__ row_ptr, const float* __restrict__ norm_in,
                      float* __restrict__ agg) {
  constexpr int C = D / 4;
  int t = blockIdx.x * blockDim.x + threadIdx.x;
  if (t >= NN * C) return;
  int i = t / C;
  int c = t % C;
  int e0 = row_ptr[i], e1 = row_ptr[i + 1];
  float4 acc = {0.f, 0.f, 0.f, 0.f};
  for (int e = e0; e < e1; ++e) {
    int s = csr[e];
    float4 v = *reinterpret_cast<const float4*>(xs + (size_t)s * D + c * 4);
    acc.x += v.x; acc.y += v.y; acc.z += v.z; acc.w += v.w;
  }
  float ni = norm_in[i];
  acc.x *= ni; acc.y *= ni; acc.z *= ni; acc.w *= ni;
  *reinterpret_cast<float4*>(agg + (size_t)t * 4) = acc;
}

// ---------------------------------------------------------------------------
// Weight prep: transpose to [N][K], convert to bf16, pre-apply XOR swizzle.
// ---------------------------------------------------------------------------
__global__ void __launch_bounds__(256) k_prepw(
    const float* __restrict__ W3, const float* __restrict__ fW1,
    const float* __restrict__ fW2, const float* __restrict__ fW3,
    const float* __restrict__ fW4, unsigned short* __restrict__ wT) {
  int t = threadIdx.x;
  for (int i = t; i < 4096; i += 256) {          // W3T [128][32]
    int n = i >> 5, k = i & 31;
    wT[WT_W3 + ((n * 32 + k) ^ ((n & 3) << 3))] = f2bf(W3[k * 128 + n]);
  }
  for (int i = t; i < 8192; i += 256) {          // F1T [128][64]
    int n = i >> 6, k = i & 63;
    wT[WT_F1 + ((n * 64 + k) ^ ((n & 7) << 3))] = f2bf(fW1[k * 128 + n]);
  }
  for (int i = t; i < 8192; i += 256) {          // F2T [64][128]
    int n = i >> 7, k = i & 127;
    wT[WT_F2 + ((n * 128 + k) ^ ((n & 7) << 3))] = f2bf(fW2[k * 64 + n]);
  }
  for (int i = t; i < 2048; i += 256) {          // F3T [32][64]
    int n = i >> 6, k = i & 63;
    wT[WT_F3 + ((n * 64 + k) ^ ((n & 7) << 3))] = f2bf(fW3[k * 32 + n]);
  }
  for (int i = t; i < 512; i += 256) {           // F4T [16][32], pad rows >=10
    int n = i >> 5, k = i & 31;
    float v = (n < 10) ? fW4[k * 10 + n] : 0.f;
    wT[WT_F4 + ((n * 32 + k) ^ ((n & 3) << 3))] = f2bf(v);
  }
}

// ---------------------------------------------------------------------------
// Tail v8 (MFMA): 64 nodes/block, 4 waves; each wave owns 16 nodes and runs
// the whole MLP with mfma_f32_16x16x32_bf16, no inter-layer barriers.
// Acts bf16 in per-wave LDS [16][K] (XOR-swizzled); weights staged once.
// A-frag: row = lane&15, k = (lane>>4)*8+i (contiguous 8).
// B-frag: col = lane&15 -> read wT[n][k] rows. D: col=lane&15, row=(l>>4)*4+r.
// ---------------------------------------------------------------------------
__global__ void __launch_bounds__(256) k_tail8(
    const float* __restrict__ agg, const int* __restrict__ gid,
    const unsigned short* __restrict__ wT,
    const float* __restrict__ b3, const float* __restrict__ fb1,
    const float* __restrict__ fb2, const float* __restrict__ fb3,
    const float* __restrict__ fb4, const float* __restrict__ inv_counts,
    float* __restrict__ out) {
  __shared__ __align__(16) unsigned short wv[WT_TOT];   // 45KB
  __shared__ __align__(16) unsigned short acts[4 * 3072];  // 24KB (per wave: A=2048,B=1024)
  __shared__ float fc4buf[64 * 12];                     // 3KB
  __shared__ int sgid[64];
  int t = threadIdx.x;
  int l = t & 63;
  int w = t >> 6;
  int nb = blockIdx.x * 64;
  int rem = min(64, NN - nb);

  // stage all weights (linear copy; swizzle pre-baked in global layout)
  for (int i = t; i < WT_TOT / 8; i += 256)
    *reinterpret_cast<s16x8*>(&wv[i * 8]) =
        *reinterpret_cast<const s16x8*>(&wT[i * 8]);

  // stage X: node = t>>2, k-octet = t&3; bf16 into wave buffer (stride 64)
  {
    int node = t >> 2, kq = t & 3;
    float4 v0 = {0.f, 0.f, 0.f, 0.f}, v1 = {0.f, 0.f, 0.f, 0.f};
    if (node < rem) {
      v0 = *reinterpret_cast<const float4*>(agg + (size_t)(nb + node) * 32 + kq * 8);
      v1 = *reinterpret_cast<const float4*>(agg + (size_t)(nb + node) * 32 + kq * 8 + 4);
    }
    s16x8 xpk;
    xpk[0] = (short)f2bf(v0.x); xpk[1] = (short)f2bf(v0.y);
    xpk[2] = (short)f2bf(v0.z); xpk[3] = (short)f2bf(v0.w);
    xpk[4] = (short)f2bf(v1.x); xpk[5] = (short)f2bf(v1.y);
    xpk[6] = (short)f2bf(v1.z); xpk[7] = (short)f2bf(v1.w);
    int wave = node >> 4, m = node & 15;
    unsigned short* bx = acts + wave * 3072;
    int e = (m * 64 + kq * 8) ^ ((m & 7) << 3);
    *reinterpret_cast<s16x8*>(&bx[e]) = xpk;
  }
  if (t < 64) sgid[t] = (nb + t < NN) ? gid[nb + t] : 0x7fffffff;
  __syncthreads();

  unsigned short* bufA = acts + w * 3072;         // X (stride64) / Q / S (stride64)
  unsigned short* bufB = acts + w * 3072 + 2048;  // P / R
  int m = l & 15;
  int kg = l >> 4;  // 0..3

  // ---- L3: X[16x32] @ W3 + b3, maxpool(2) -> P[16][64] in bufB
#pragma unroll
  for (int nt = 0; nt < 8; ++nt) {
    int n = nt * 16 + m;
    f32x4 acc = {0.f, 0.f, 0.f, 0.f};
    s16x8 a = *reinterpret_cast<const s16x8*>(
        &bufA[(m * 64 + kg * 8) ^ ((m & 7) << 3)]);
    s16x8 b = *reinterpret_cast<const s16x8*>(
        &wv[WT_W3 + ((n * 32 + kg * 8) ^ ((n & 3) << 3))]);
    acc = __builtin_amdgcn_mfma_f32_16x16x32_bf16(a, b, acc, 0, 0, 0);
    float bias = b3[n];
#pragma unroll
    for (int r = 0; r < 4; ++r) {
      float v = acc[r] + bias;
      float pv = fmaxf(v, __shfl_xor(v, 1));
      if (!(m & 1)) {
        int node = kg * 4 + r;
        int j = n >> 1;
        bufB[(node * 64 + j) ^ ((node & 7) << 3)] = f2bf(pv);
      }
    }
  }
  // ---- fc1: P[16x64] @ fW1 + fb1, relu -> Q[16][128] in bufA
#pragma unroll
  for (int nt = 0; nt < 8; ++nt) {
    int n = nt * 16 + m;
    f32x4 acc = {0.f, 0.f, 0.f, 0.f};
#pragma unroll
    for (int kt = 0; kt < 2; ++kt) {
      s16x8 a = *reinterpret_cast<const s16x8*>(
          &bufB[(m * 64 + kt * 32 + kg * 8) ^ ((m & 7) << 3)]);
      s16x8 b = *reinterpret_cast<const s16x8*>(
          &wv[WT_F1 + ((n * 64 + kt * 32 + kg * 8) ^ ((n & 7) << 3))]);
      acc = __builtin_amdgcn_mfma_f32_16x16x32_bf16(a, b, acc, 0, 0, 0);
    }
    float bias = fb1[n];
#pragma unroll
    for (int r = 0; r < 4; ++r) {
      int node = kg * 4 + r;
      float v = fmaxf(acc[r] + bias, 0.f);
      bufA[(node * 128 + n) ^ ((node & 7) << 3)] = f2bf(v);
    }
  }
  // ---- fc2: Q[16x128] @ fW2 + fb2, relu -> R[16][64] in bufB
#pragma unroll
  for (int nt = 0; nt < 4; ++nt) {
    int n = nt * 16 + m;
    f32x4 acc = {0.f, 0.f, 0.f, 0.f};
#pragma unroll
    for (int kt = 0; kt < 4; ++kt) {
      s16x8 a = *reinterpret_cast<const s16x8*>(
          &bufA[(m * 128 + kt * 32 + kg * 8) ^ ((m & 7) << 3)]);
      s16x8 b = *reinterpret_cast<const s16x8*>(
          &wv[WT_F2 + ((n * 128 + kt * 32 + kg * 8) ^ ((n & 7) << 3))]);
      acc = __builtin_amdgcn_mfma_f32_16x16x32_bf16(a, b, acc, 0, 0, 0);
    }
    float bias = fb2[n];
#pragma unroll
    for (int r = 0; r < 4; ++r) {
      int node = kg * 4 + r;
      float v = fmaxf(acc[r] + bias, 0.f);
      bufB[(node * 64 + n) ^ ((node & 7) << 3)] = f2bf(v);
    }
  }
  // ---- fc3: R[16x64] @ fW3 + fb3, relu -> S[16][32] in bufA (stride 64)
#pragma unroll
  for (int nt = 0; nt < 2; ++nt) {
    int n = nt * 16 + m;
    f32x4 acc = {0.f, 0.f, 0.f, 0.f};
#pragma unroll
    for (int kt = 0; kt < 2; ++kt) {
      s16x8 a = *reinterpret_cast<const s16x8*>(
          &bufB[(m * 64 + kt * 32 + kg * 8) ^ ((m & 7) << 3)]);
      s16x8 b = *reinterpret_cast<const s16x8*>(
          &wv[WT_F3 + ((n * 64 + kt * 32 + kg * 8) ^ ((n & 7) << 3))]);
      acc = __builtin_amdgcn_mfma_f32_16x16x32_bf16(a, b, acc, 0, 0, 0);
    }
    float bias = fb3[n];
#pragma unroll
    for (int r = 0; r < 4; ++r) {
      int node = kg * 4 + r;
      float v = fmaxf(acc[r] + bias, 0.f);
      bufA[(node * 64 + n) ^ ((node & 7) << 3)] = f2bf(v);
    }
  }
  // ---- fc4: S[16x32] @ fW4p[32x16] + fb4 -> fc4buf (f32, node-major)
  {
    f32x4 acc = {0.f, 0.f, 0.f, 0.f};
    s16x8 a = *reinterpret_cast<const s16x8*>(
        &bufA[(m * 64 + kg * 8) ^ ((m & 7) << 3)]);
    s16x8 b = *reinterpret_cast<const s16x8*>(
        &wv[WT_F4 + ((m * 32 + kg * 8) ^ ((m & 3) << 3))]);
    acc = __builtin_amdgcn_mfma_f32_16x16x32_bf16(a, b, acc, 0, 0, 0);
    if (m < 10) {
      float bias = fb4[m];
#pragma unroll
      for (int r = 0; r < 4; ++r) {
        int node = w * 16 + kg * 4 + r;
        fc4buf[node * 12 + m] = acc[r] + bias;
      }
    }
  }
  __syncthreads();

  // segmented graph-mean (gids sorted): few atomics per block
  if (t < 10) {
    int g = sgid[0];
    float run = 0.f;
    for (int n = 0; n < rem; ++n) {
      run += fc4buf[n * 12 + t];
      bool last = (n == rem - 1) || (sgid[n + 1] != g);
      if (last) {
        atomicAdd(&out[g * 10 + t], run * inv_counts[g]);
        run = 0.f;
        if (n < rem - 1) g = sgid[n + 1];
      }
    }
  }
}

extern "C" void kernel_launch(void* const* d_in, const int* in_sizes, int n_in,
                              void* d_out, int out_size, void* d_ws, size_t ws_size,
                              hipStream_t stream) {
  const int* src = (const int*)d_in[0];
  const int* dst = (const int*)d_in[1];
  const int* gid = (const int*)d_in[2];
  const float* n_feat = (const float*)d_in[3];
  const float* W1 = (const float*)d_in[4];
  const float* b1 = (const float*)d_in[5];
  const float* W2 = (const float*)d_in[6];
  const float* b2 = (const float*)d_in[7];
  const float* W3 = (const float*)d_in[8];
  const float* b3 = (const float*)d_in[9];
  const float* fW1 = (const float*)d_in[10];
  const float* fb1 = (const float*)d_in[11];
  const float* fW2 = (const float*)d_in[12];
  const float* fb2 = (const float*)d_in[13];
  const float* fW3 = (const float*)d_in[14];
  const float* fb3 = (const float*)d_in[15];
  const float* fW4 = (const float*)d_in[16];
  const float* fb4 = (const float*)d_in[17];
  float* out = (float*)d_out;

  float* ws = (float*)d_ws;
  float* norm_out = ws + OFF_NORM_OUT;
  float* norm_in = ws + OFF_NORM_IN;
  float* inv_cnt = ws + OFF_INVC;
  int* row_ptr = (int*)(ws + OFF_ROWPTR);
  int* csr = (int*)(ws + OFF_CSR);
  float* agg = ws + OFF_AGG;
  float* buf = ws + OFF_BUF;
  int* cnt_dst = (int*)(ws + OFF_CNTD);
  int* cnt_src = (int*)(ws + OFF_CNTS);
  int* bb_dst = (int*)(ws + OFF_BBD);
  int* bb_src = (int*)(ws + OFF_BBS);
  int* tot = (int*)(ws + OFF_TOT);
  unsigned short* wT = (unsigned short*)(ws + OFF_WT);
  uint32_t* pairs = (uint32_t*)agg;                 // NE u32 inside agg region
  uint16_t* srcbuf = (uint16_t*)((int*)agg + NE);   // NE u16, after pairs

  hipMemsetAsync(out, 0, (size_t)out_size * sizeof(float), stream);

  k_prepw<<<1, 256, 0, stream>>>(W3, fW1, fW2, fW3, fW4, wT);
  k_part_count<<<NPB, 256, 0, stream>>>(src, dst, cnt_dst, cnt_src);
  k_graphinfo<<<1, NG, 0, stream>>>(gid, inv_cnt);
  k_btot<<<2 * NB, 256, 0, stream>>>(cnt_dst, cnt_src, tot);
  k_bscan<<<1, 256, 0, stream>>>(tot, bb_dst, bb_src);
  k_crow<<<2 * NB, 256, 0, stream>>>(cnt_dst, cnt_src, bb_dst, bb_src);
  k_part_scatter<<<NPB, 256, 0, stream>>>(src, dst, cnt_dst, cnt_src, pairs, srcbuf);
  k_bucket_csr<<<NB, 256, 0, stream>>>(pairs, bb_dst, row_ptr, norm_in, csr);
  k_bucket_deg<<<NB, 256, 0, stream>>>(srcbuf, bb_src, n_feat, norm_out, buf);

  // layer 1 fused: gather(d=8) + 8->16 + relu ; xs1 into agg region
  k_agglayer<8, 16><<<(NN + 255) / 256, 256, 0, stream>>>(buf, csr, row_ptr, norm_in,
                                                          norm_out, W1, b1, agg);
  // layer 2 fused: gather(d=16) + 16->32 + relu ; xs2 into buf
  k_agglayer<16, 32><<<(NN + 255) / 256, 256, 0, stream>>>(agg, csr, row_ptr, norm_in,
                                                           norm_out, W2, b2, buf);
  // layer 3 aggregate (d=32) -> agg, then MFMA tail
  k_agg<32><<<(NN * 8 + 255) / 256, 256, 0, stream>>>(buf, csr, row_ptr, norm_in, agg);
  k_tail8<<<(NN + 63) / 64, 256, 0, stream>>>(agg, gid, wT, b3, fb1, fb2, fb3, fb4,
                                              inv_cnt, out);
}

// Round 12
// 258.420 us; speedup vs baseline: 1.5539x; 1.0868x over previous
//
#include <hip/hip_runtime.h>
#include <stdint.h>

#define NN 100000
#define NE 1600000
#define NG 256

#define NB 196    // node buckets of 512 nodes
#define BSH 9     // bucket shift (512)
#define NPB 392   // partition blocks
#define EPB 4096  // edges per partition block

typedef float f32x4 __attribute__((ext_vector_type(4)));
typedef short s16x8 __attribute__((ext_vector_type(8)));

// bf16 weight buffer layout (elems), [N][K] transposed, XOR-swizzled
#define WT_W3 0        // [128][32]  4096  swz (n&3)<<3
#define WT_F1 4096     // [128][64]  8192  swz (n&7)<<3
#define WT_F2 12288    // [64][128]  8192  swz (n&7)<<3
#define WT_F3 20480    // [32][64]   2048  swz (n&7)<<3
#define WT_F4 22528    // [16][32]   512   swz (n&3)<<3, rows 10..15 zero
#define WT_TOT 23040

#define OFF_NORM_OUT 0
#define OFF_NORM_IN  (NN)
#define OFF_INVC     (2 * NN)
#define OFF_ROWPTR   (2 * NN + 512)
#define OFF_CSR      (3 * NN + 516)
#define OFF_AGG      (3 * NN + 516 + NE)
#define OFF_BUF      (OFF_AGG + 32 * NN)
#define OFF_CNTD     (OFF_BUF + 32 * NN)
#define OFF_CNTS     (OFF_CNTD + NB * NPB)
#define OFF_BBD      (OFF_CNTS + NB * NPB)
#define OFF_BBS      (OFF_BBD + 200)
#define OFF_TOT      (OFF_BBS + 200)
#define OFF_WT       (OFF_TOT + 400)   // 23040 ushorts = 11520 words

__device__ __forceinline__ unsigned short f2bf(float f) {
  uint32_t u = __float_as_uint(f);
  u += 0x7fff + ((u >> 16) & 1);  // round to nearest even
  return (unsigned short)(u >> 16);
}

// ---------------- graph setup (unchanged) ----------------------------------
__global__ void __launch_bounds__(256) k_part_count(const int* __restrict__ src,
                                                    const int* __restrict__ dst,
                                                    int* __restrict__ cnt_dst,
                                                    int* __restrict__ cnt_src) {
  __shared__ int hd[NB], hs[NB];
  int t = threadIdx.x;
  int blk = blockIdx.x;
  for (int i = t; i < NB; i += 256) { hd[i] = 0; hs[i] = 0; }
  __syncthreads();
  int e0 = blk * EPB, e1 = min(e0 + EPB, NE);
  for (int e = e0 + t; e < e1; e += 256) {
    atomicAdd(&hd[dst[e] >> BSH], 1);
    atomicAdd(&hs[src[e] >> BSH], 1);
  }
  __syncthreads();
  for (int i = t; i < NB; i += 256) {
    cnt_dst[i * NPB + blk] = hd[i];
    cnt_src[i * NPB + blk] = hs[i];
  }
}

__global__ void __launch_bounds__(256) k_btot(const int* __restrict__ cnt_dst,
                                              const int* __restrict__ cnt_src,
                                              int* __restrict__ tot) {
  __shared__ int red[256];
  int m = blockIdx.x;
  const int* cnt = (m < NB) ? cnt_dst : cnt_src;
  int row = (m < NB) ? m : m - NB;
  int t = threadIdx.x;
  int s = 0;
  for (int k = t; k < NPB; k += 256) s += cnt[row * NPB + k];
  red[t] = s;
  __syncthreads();
  for (int off = 128; off; off >>= 1) {
    if (t < off) red[t] += red[t + off];
    __syncthreads();
  }
  if (t == 0) tot[m] = red[0];
}

__global__ void __launch_bounds__(256) k_bscan(const int* __restrict__ tot,
                                               int* __restrict__ bb_dst,
                                               int* __restrict__ bb_src) {
  __shared__ int tmp[256];
  int t = threadIdx.x;
  for (int p = 0; p < 2; ++p) {
    int* bb = p ? bb_src : bb_dst;
    int v = (t < NB) ? tot[p * NB + t] : 0;
    tmp[t] = v;
    __syncthreads();
    int incl = v;
    for (int off = 1; off < 256; off <<= 1) {
      int o = (t >= off) ? tmp[t - off] : 0;
      __syncthreads();
      incl += o;
      tmp[t] = incl;
      __syncthreads();
    }
    if (t < NB) bb[t] = incl - v;
    if (t == NB - 1) bb[NB] = incl;
    __syncthreads();
  }
}

__global__ void __launch_bounds__(256) k_crow(int* __restrict__ cnt_dst,
                                              int* __restrict__ cnt_src,
                                              const int* __restrict__ bb_dst,
                                              const int* __restrict__ bb_src) {
  __shared__ int tmp[256];
  int m = blockIdx.x;
  bool is_src = m >= NB;
  int row = is_src ? m - NB : m;
  int* cnt = is_src ? cnt_src : cnt_dst;
  const int* bb = is_src ? bb_src : bb_dst;
  int t = threadIdx.x;
  int i0 = 2 * t, i1 = 2 * t + 1;
  int v0 = (i0 < NPB) ? cnt[row * NPB + i0] : 0;
  int v1 = (i1 < NPB) ? cnt[row * NPB + i1] : 0;
  int ps = v0 + v1;
  tmp[t] = ps;
  __syncthreads();
  int incl = ps;
  for (int off = 1; off < 256; off <<= 1) {
    int o = (t >= off) ? tmp[t - off] : 0;
    __syncthreads();
    incl += o;
    tmp[t] = incl;
    __syncthreads();
  }
  int ex = incl - ps + bb[row];
  if (i0 < NPB) cnt[row * NPB + i0] = ex;
  if (i1 < NPB) cnt[row * NPB + i1] = ex + v0;
}

__global__ void __launch_bounds__(256) k_part_scatter(const int* __restrict__ src,
                                                      const int* __restrict__ dst,
                                                      const int* __restrict__ cnt_dst,
                                                      const int* __restrict__ cnt_src,
                                                      uint32_t* __restrict__ pairs,
                                                      uint16_t* __restrict__ srcbuf) {
  __shared__ int cd[NB], cs[NB];
  int t = threadIdx.x;
  int blk = blockIdx.x;
  for (int i = t; i < NB; i += 256) {
    cd[i] = cnt_dst[i * NPB + blk];
    cs[i] = cnt_src[i * NPB + blk];
  }
  __syncthreads();
  int e0 = blk * EPB, e1 = min(e0 + EPB, NE);
  for (int e = e0 + t; e < e1; e += 256) {
    int s = src[e], d = dst[e];
    int pd = atomicAdd(&cd[d >> BSH], 1);
    pairs[pd] = ((uint32_t)s << 9) | (uint32_t)(d & 511);
    int ps = atomicAdd(&cs[s >> BSH], 1);
    srcbuf[ps] = (uint16_t)(s & 511);
  }
}

__global__ void __launch_bounds__(256) k_bucket_csr(const uint32_t* __restrict__ pairs,
                                                    const int* __restrict__ bb,
                                                    int* __restrict__ row_ptr,
                                                    float* __restrict__ norm_in,
                                                    int* __restrict__ csr) {
  __shared__ int hist[512], curs[512], pscan[256];
  int t = threadIdx.x;
  int b = blockIdx.x;
  int n0 = b << BSH;
  int ebase = bb[b], eend = bb[b + 1];
  hist[t] = 0;
  hist[t + 256] = 0;
  __syncthreads();
  for (int e = ebase + t; e < eend; e += 256)
    atomicAdd(&hist[pairs[e] & 511], 1);
  __syncthreads();
  int s0 = hist[2 * t], s1 = hist[2 * t + 1];
  int ps = s0 + s1;
  pscan[t] = ps;
  __syncthreads();
  int incl = ps;
  for (int off = 1; off < 256; off <<= 1) {
    int o = (t >= off) ? pscan[t - off] : 0;
    __syncthreads();
    incl += o;
    pscan[t] = incl;
    __syncthreads();
  }
  int ex = incl - ps;
  curs[2 * t] = ex;
  curs[2 * t + 1] = ex + s0;
  int n = n0 + 2 * t;
  if (n < NN) {
    row_ptr[n] = ebase + ex;
    norm_in[n] = s0 > 0 ? 1.0f / sqrtf((float)s0) : 0.0f;
  }
  if (n + 1 < NN) {
    row_ptr[n + 1] = ebase + ex + s0;
    norm_in[n + 1] = s1 > 0 ? 1.0f / sqrtf((float)s1) : 0.0f;
  }
  __syncthreads();
  for (int e = ebase + t; e < eend; e += 256) {
    uint32_t pr = pairs[e];
    int pos = atomicAdd(&curs[pr & 511], 1);
    csr[ebase + pos] = (int)(pr >> 9);
  }
  if (b == 0 && t == 0) row_ptr[NN] = NE;
}

__global__ void __launch_bounds__(256) k_bucket_deg(const uint16_t* __restrict__ srcbuf,
                                                    const int* __restrict__ bb,
                                                    const float* __restrict__ n_feat,
                                                    float* __restrict__ norm_out,
                                                    float* __restrict__ xs) {
  __shared__ int hist[512];
  int t = threadIdx.x;
  int b = blockIdx.x;
  hist[t] = 0;
  hist[t + 256] = 0;
  __syncthreads();
  int e0 = bb[b], e1 = bb[b + 1];
  for (int e = e0 + t; e < e1; e += 256)
    atomicAdd(&hist[srcbuf[e]], 1);
  __syncthreads();
#pragma unroll
  for (int h = 0; h < 2; ++h) {
    int n = (b << BSH) + t + h * 256;
    if (n < NN) {
      int d = hist[t + h * 256];
      float no = d > 0 ? 1.0f / sqrtf((float)d) : 0.0f;
      norm_out[n] = no;
      float4 a = *reinterpret_cast<const float4*>(n_feat + (size_t)n * 8);
      float4 bb4 = *reinterpret_cast<const float4*>(n_feat + (size_t)n * 8 + 4);
      a.x *= no; a.y *= no; a.z *= no; a.w *= no;
      bb4.x *= no; bb4.y *= no; bb4.z *= no; bb4.w *= no;
      *reinterpret_cast<float4*>(xs + (size_t)n * 8) = a;
      *reinterpret_cast<float4*>(xs + (size_t)n * 8 + 4) = bb4;
    }
  }
}

__global__ void __launch_bounds__(NG) k_graphinfo(const int* __restrict__ gid,
                                                  float* __restrict__ inv) {
  int g = threadIdx.x;
  int lo0 = 0, hi0 = NN;
  while (lo0 < hi0) { int m = (lo0 + hi0) >> 1; if (gid[m] < g) lo0 = m + 1; else hi0 = m; }
  int lo1 = lo0, hi1 = NN;
  while (lo1 < hi1) { int m = (lo1 + hi1) >> 1; if (gid[m] < g + 1) lo1 = m + 1; else hi1 = m; }
  int c = lo1 - lo0;
  inv[g] = 1.0f / fmaxf((float)c, 1.0f);
}

template <int DIN, int DOUT>
__global__ void __launch_bounds__(256) k_agglayer(
    const float* __restrict__ xs, const int* __restrict__ csr,
    const int* __restrict__ row_ptr, const float* __restrict__ norm_in,
    const float* __restrict__ norm_out, const float* __restrict__ W,
    const float* __restrict__ bvec, float* __restrict__ ys) {
  int i = blockIdx.x * 256 + threadIdx.x;
  if (i >= NN) return;
  float acc[DIN];
#pragma unroll
  for (int k = 0; k < DIN; ++k) acc[k] = 0.f;
  int e0 = row_ptr[i], e1 = row_ptr[i + 1];
  for (int e = e0; e < e1; ++e) {
    int s = csr[e];
#pragma unroll
    for (int c = 0; c < DIN / 4; ++c) {
      float4 v = *reinterpret_cast<const float4*>(xs + (size_t)s * DIN + 4 * c);
      acc[4 * c + 0] += v.x;
      acc[4 * c + 1] += v.y;
      acc[4 * c + 2] += v.z;
      acc[4 * c + 3] += v.w;
    }
  }
  float ni = norm_in[i];
#pragma unroll
  for (int k = 0; k < DIN; ++k) acc[k] *= ni;
  float no = norm_out[i];
#pragma unroll
  for (int j4 = 0; j4 < DOUT / 4; ++j4) {
    float4 y;
    float* yp = reinterpret_cast<float*>(&y);
#pragma unroll
    for (int jj = 0; jj < 4; ++jj) {
      int j = 4 * j4 + jj;
      float s = bvec[j];
#pragma unroll
      for (int k = 0; k < DIN; ++k) s = fmaf(acc[k], W[k * DOUT + j], s);
      yp[jj] = fmaxf(s, 0.f) * no;
    }
    *reinterpret_cast<float4*>(ys + (size_t)i * DOUT + 4 * j4) = y;
  }
}

template <int D>
__global__ void k_agg(const float* __restrict__ xs, const int* __restrict__ csr,
                      const int* __restrict__ row_ptr, const float* __restrict__ norm_in,
                      float* __restrict__ agg) {
  constexpr int C = D / 4;
  int t = blockIdx.x * blockDim.x + threadIdx.x;
  if (t >= NN * C) return;
  int i = t / C;
  int c = t % C;
  int e0 = row_ptr[i], e1 = row_ptr[i + 1];
  float4 acc = {0.f, 0.f, 0.f, 0.f};
  for (int e = e0; e < e1; ++e) {
    int s = csr[e];
    float4 v = *reinterpret_cast<const float4*>(xs + (size_t)s * D + c * 4);
    acc.x += v.x; acc.y += v.y; acc.z += v.z; acc.w += v.w;
  }
  float ni = norm_in[i];
  acc.x *= ni; acc.y *= ni; acc.z *= ni; acc.w *= ni;
  *reinterpret_cast<float4*>(agg + (size_t)t * 4) = acc;
}

// ---------------------------------------------------------------------------
// Weight prep: transpose to [N][K], convert to bf16, pre-apply XOR swizzle.
// ---------------------------------------------------------------------------
__global__ void __launch_bounds__(256) k_prepw(
    const float* __restrict__ W3, const float* __restrict__ fW1,
    const float* __restrict__ fW2, const float* __restrict__ fW3,
    const float* __restrict__ fW4, unsigned short* __restrict__ wT) {
  int t = threadIdx.x;
  for (int i = t; i < 4096; i += 256) {          // W3T [128][32]
    int n = i >> 5, k = i & 31;
    wT[WT_W3 + ((n * 32 + k) ^ ((n & 3) << 3))] = f2bf(W3[k * 128 + n]);
  }
  for (int i = t; i < 8192; i += 256) {          // F1T [128][64]
    int n = i >> 6, k = i & 63;
    wT[WT_F1 + ((n * 64 + k) ^ ((n & 7) << 3))] = f2bf(fW1[k * 128 + n]);
  }
  for (int i = t; i < 8192; i += 256) {          // F2T [64][128]
    int n = i >> 7, k = i & 127;
    wT[WT_F2 + ((n * 128 + k) ^ ((n & 7) << 3))] = f2bf(fW2[k * 64 + n]);
  }
  for (int i = t; i < 2048; i += 256) {          // F3T [32][64]
    int n = i >> 6, k = i & 63;
    wT[WT_F3 + ((n * 64 + k) ^ ((n & 7) << 3))] = f2bf(fW3[k * 32 + n]);
  }
  for (int i = t; i < 512; i += 256) {           // F4T [16][32], pad rows >=10
    int n = i >> 5, k = i & 31;
    float v = (n < 10) ? fW4[k * 10 + n] : 0.f;
    wT[WT_F4 + ((n * 32 + k) ^ ((n & 3) << 3))] = f2bf(v);
  }
}

// ---------------------------------------------------------------------------
// Tail v9 (MFMA, 256 nodes/block): 4 waves; each wave runs FOUR sequential
// 16-node groups through the whole MLP (weight staging amortized 4x; grid 391
// -> ~1 block-round). fc4 results carried in regs (statically indexed) and
// flushed into the wave's own dead act buffer at the end.
// ---------------------------------------------------------------------------
__global__ void __launch_bounds__(256) k_tail9(
    const float* __restrict__ agg, const int* __restrict__ gid,
    const unsigned short* __restrict__ wT,
    const float* __restrict__ b3, const float* __restrict__ fb1,
    const float* __restrict__ fb2, const float* __restrict__ fb3,
    const float* __restrict__ fb4, const float* __restrict__ inv_counts,
    float* __restrict__ out) {
  __shared__ __align__(16) unsigned short wv[WT_TOT];      // 45KB
  __shared__ __align__(16) unsigned short acts[4 * 3072];  // 24KB (A=2048,B=1024 per wave)
  __shared__ int sgid[256];                                // 1KB
  int t = threadIdx.x;
  int l = t & 63;
  int w = t >> 6;
  int nb = blockIdx.x * 256;

  // stage all weights (linear copy; swizzle pre-baked in global layout)
  for (int i = t; i < WT_TOT / 8; i += 256)
    *reinterpret_cast<s16x8*>(&wv[i * 8]) =
        *reinterpret_cast<const s16x8*>(&wT[i * 8]);
  if (nb + t < NN) sgid[t] = gid[nb + t]; else sgid[t] = 0x7fffffff;
  __syncthreads();

  unsigned short* bufA = acts + w * 3072;         // X / Q / S
  unsigned short* bufB = acts + w * 3072 + 2048;  // P / R
  int m = l & 15;
  int kg = l >> 4;  // 0..3
  float fc4r[16];

#pragma unroll
  for (int g = 0; g < 4; ++g) {
    int base = nb + w * 64 + g * 16;
    // ---- stage X wave-locally: lane l -> node16 = l>>2, k-octet = l&3
    {
      int n16 = l >> 2, kq = l & 3;
      int node = base + n16;
      float4 v0 = {0.f, 0.f, 0.f, 0.f}, v1 = {0.f, 0.f, 0.f, 0.f};
      if (node < NN) {
        v0 = *reinterpret_cast<const float4*>(agg + (size_t)node * 32 + kq * 8);
        v1 = *reinterpret_cast<const float4*>(agg + (size_t)node * 32 + kq * 8 + 4);
      }
      s16x8 xpk;
      xpk[0] = (short)f2bf(v0.x); xpk[1] = (short)f2bf(v0.y);
      xpk[2] = (short)f2bf(v0.z); xpk[3] = (short)f2bf(v0.w);
      xpk[4] = (short)f2bf(v1.x); xpk[5] = (short)f2bf(v1.y);
      xpk[6] = (short)f2bf(v1.z); xpk[7] = (short)f2bf(v1.w);
      int e = (n16 * 64 + kq * 8) ^ ((n16 & 7) << 3);
      *reinterpret_cast<s16x8*>(&bufA[e]) = xpk;
    }
    // wave-internal cross-lane LDS handoff: drain ds queue before reads
    asm volatile("s_waitcnt lgkmcnt(0)" ::: "memory");

    // ---- L3: X[16x32] @ W3 + b3, maxpool(2) -> P[16][64] in bufB
#pragma unroll
    for (int nt = 0; nt < 8; ++nt) {
      int n = nt * 16 + m;
      f32x4 acc = {0.f, 0.f, 0.f, 0.f};
      s16x8 a = *reinterpret_cast<const s16x8*>(
          &bufA[(m * 64 + kg * 8) ^ ((m & 7) << 3)]);
      s16x8 b = *reinterpret_cast<const s16x8*>(
          &wv[WT_W3 + ((n * 32 + kg * 8) ^ ((n & 3) << 3))]);
      acc = __builtin_amdgcn_mfma_f32_16x16x32_bf16(a, b, acc, 0, 0, 0);
      float bias = b3[n];
#pragma unroll
      for (int r = 0; r < 4; ++r) {
        float v = acc[r] + bias;
        float pv = fmaxf(v, __shfl_xor(v, 1));
        if (!(m & 1)) {
          int node = kg * 4 + r;
          int j = n >> 1;
          bufB[(node * 64 + j) ^ ((node & 7) << 3)] = f2bf(pv);
        }
      }
    }
    asm volatile("s_waitcnt lgkmcnt(0)" ::: "memory");
    // ---- fc1: P[16x64] @ fW1 + fb1, relu -> Q[16][128] in bufA
#pragma unroll
    for (int nt = 0; nt < 8; ++nt) {
      int n = nt * 16 + m;
      f32x4 acc = {0.f, 0.f, 0.f, 0.f};
#pragma unroll
      for (int kt = 0; kt < 2; ++kt) {
        s16x8 a = *reinterpret_cast<const s16x8*>(
            &bufB[(m * 64 + kt * 32 + kg * 8) ^ ((m & 7) << 3)]);
        s16x8 b = *reinterpret_cast<const s16x8*>(
            &wv[WT_F1 + ((n * 64 + kt * 32 + kg * 8) ^ ((n & 7) << 3))]);
        acc = __builtin_amdgcn_mfma_f32_16x16x32_bf16(a, b, acc, 0, 0, 0);
      }
      float bias = fb1[n];
#pragma unroll
      for (int r = 0; r < 4; ++r) {
        int node = kg * 4 + r;
        float v = fmaxf(acc[r] + bias, 0.f);
        bufA[(node * 128 + n) ^ ((node & 7) << 3)] = f2bf(v);
      }
    }
    asm volatile("s_waitcnt lgkmcnt(0)" ::: "memory");
    // ---- fc2: Q[16x128] @ fW2 + fb2, relu -> R[16][64] in bufB
#pragma unroll
    for (int nt = 0; nt < 4; ++nt) {
      int n = nt * 16 + m;
      f32x4 acc = {0.f, 0.f, 0.f, 0.f};
#pragma unroll
      for (int kt = 0; kt < 4; ++kt) {
        s16x8 a = *reinterpret_cast<const s16x8*>(
            &bufA[(m * 128 + kt * 32 + kg * 8) ^ ((m & 7) << 3)]);
        s16x8 b = *reinterpret_cast<const s16x8*>(
            &wv[WT_F2 + ((n * 128 + kt * 32 + kg * 8) ^ ((n & 7) << 3))]);
        acc = __builtin_amdgcn_mfma_f32_16x16x32_bf16(a, b, acc, 0, 0, 0);
      }
      float bias = fb2[n];
#pragma unroll
      for (int r = 0; r < 4; ++r) {
        int node = kg * 4 + r;
        float v = fmaxf(acc[r] + bias, 0.f);
        bufB[(node * 64 + n) ^ ((node & 7) << 3)] = f2bf(v);
      }
    }
    asm volatile("s_waitcnt lgkmcnt(0)" ::: "memory");
    // ---- fc3: R[16x64] @ fW3 + fb3, relu -> S[16][32] in bufA (stride 64)
#pragma unroll
    for (int nt = 0; nt < 2; ++nt) {
      int n = nt * 16 + m;
      f32x4 acc = {0.f, 0.f, 0.f, 0.f};
#pragma unroll
      for (int kt = 0; kt < 2; ++kt) {
        s16x8 a = *reinterpret_cast<const s16x8*>(
            &bufB[(m * 64 + kt * 32 + kg * 8) ^ ((m & 7) << 3)]);
        s16x8 b = *reinterpret_cast<const s16x8*>(
            &wv[WT_F3 + ((n * 64 + kt * 32 + kg * 8) ^ ((n & 7) << 3))]);
        acc = __builtin_amdgcn_mfma_f32_16x16x32_bf16(a, b, acc, 0, 0, 0);
      }
      float bias = fb3[n];
#pragma unroll
      for (int r = 0; r < 4; ++r) {
        int node = kg * 4 + r;
        float v = fmaxf(acc[r] + bias, 0.f);
        bufA[(node * 64 + n) ^ ((node & 7) << 3)] = f2bf(v);
      }
    }
    asm volatile("s_waitcnt lgkmcnt(0)" ::: "memory");
    // ---- fc4: S[16x32] @ fW4p + fb4 -> regs (statically indexed by g)
    {
      f32x4 acc = {0.f, 0.f, 0.f, 0.f};
      s16x8 a = *reinterpret_cast<const s16x8*>(
          &bufA[(m * 64 + kg * 8) ^ ((m & 7) << 3)]);
      s16x8 b = *reinterpret_cast<const s16x8*>(
          &wv[WT_F4 + ((m * 32 + kg * 8) ^ ((m & 3) << 3))]);
      acc = __builtin_amdgcn_mfma_f32_16x16x32_bf16(a, b, acc, 0, 0, 0);
      float bias = (m < 10) ? fb4[m] : 0.f;
#pragma unroll
      for (int r = 0; r < 4; ++r) fc4r[g * 4 + r] = acc[r] + bias;
    }
  }

  // flush fc4 results into this wave's (now dead) act buffer as f32 [64][12]
  asm volatile("s_waitcnt lgkmcnt(0)" ::: "memory");
  {
    float* fbuf = reinterpret_cast<float*>(bufA);
    if (m < 10) {
#pragma unroll
      for (int g = 0; g < 4; ++g)
#pragma unroll
        for (int r = 0; r < 4; ++r) {
          int nl = g * 16 + kg * 4 + r;
          fbuf[nl * 12 + m] = fc4r[g * 4 + r];
        }
    }
  }
  __syncthreads();

  // segmented graph-mean: 4 teams of 10 threads, one per 64-node quarter
  if (t < 40) {
    int q = t / 10, j = t % 10;
    const float* fbuf = reinterpret_cast<const float*>(acts + q * 3072);
    int qbase = q * 64;
    int qrem = min(64, NN - (nb + qbase));
    if (qrem > 0) {
      int g = sgid[qbase];
      float run = 0.f;
      for (int n = 0; n < qrem; ++n) {
        run += fbuf[n * 12 + j];
        bool last = (n == qrem - 1) || (sgid[qbase + n + 1] != g);
        if (last) {
          atomicAdd(&out[g * 10 + j], run * inv_counts[g]);
          run = 0.f;
          if (n < qrem - 1) g = sgid[qbase + n + 1];
        }
      }
    }
  }
}

extern "C" void kernel_launch(void* const* d_in, const int* in_sizes, int n_in,
                              void* d_out, int out_size, void* d_ws, size_t ws_size,
                              hipStream_t stream) {
  const int* src = (const int*)d_in[0];
  const int* dst = (const int*)d_in[1];
  const int* gid = (const int*)d_in[2];
  const float* n_feat = (const float*)d_in[3];
  const float* W1 = (const float*)d_in[4];
  const float* b1 = (const float*)d_in[5];
  const float* W2 = (const float*)d_in[6];
  const float* b2 = (const float*)d_in[7];
  const float* W3 = (const float*)d_in[8];
  const float* b3 = (const float*)d_in[9];
  const float* fW1 = (const float*)d_in[10];
  const float* fb1 = (const float*)d_in[11];
  const float* fW2 = (const float*)d_in[12];
  const float* fb2 = (const float*)d_in[13];
  const float* fW3 = (const float*)d_in[14];
  const float* fb3 = (const float*)d_in[15];
  const float* fW4 = (const float*)d_in[16];
  const float* fb4 = (const float*)d_in[17];
  float* out = (float*)d_out;

  float* ws = (float*)d_ws;
  float* norm_out = ws + OFF_NORM_OUT;
  float* norm_in = ws + OFF_NORM_IN;
  float* inv_cnt = ws + OFF_INVC;
  int* row_ptr = (int*)(ws + OFF_ROWPTR);
  int* csr = (int*)(ws + OFF_CSR);
  float* agg = ws + OFF_AGG;
  float* buf = ws + OFF_BUF;
  int* cnt_dst = (int*)(ws + OFF_CNTD);
  int* cnt_src = (int*)(ws + OFF_CNTS);
  int* bb_dst = (int*)(ws + OFF_BBD);
  int* bb_src = (int*)(ws + OFF_BBS);
  int* tot = (int*)(ws + OFF_TOT);
  unsigned short* wT = (unsigned short*)(ws + OFF_WT);
  uint32_t* pairs = (uint32_t*)agg;                 // NE u32 inside agg region
  uint16_t* srcbuf = (uint16_t*)((int*)agg + NE);   // NE u16, after pairs

  hipMemsetAsync(out, 0, (size_t)out_size * sizeof(float), stream);

  k_prepw<<<1, 256, 0, stream>>>(W3, fW1, fW2, fW3, fW4, wT);
  k_part_count<<<NPB, 256, 0, stream>>>(src, dst, cnt_dst, cnt_src);
  k_graphinfo<<<1, NG, 0, stream>>>(gid, inv_cnt);
  k_btot<<<2 * NB, 256, 0, stream>>>(cnt_dst, cnt_src, tot);
  k_bscan<<<1, 256, 0, stream>>>(tot, bb_dst, bb_src);
  k_crow<<<2 * NB, 256, 0, stream>>>(cnt_dst, cnt_src, bb_dst, bb_src);
  k_part_scatter<<<NPB, 256, 0, stream>>>(src, dst, cnt_dst, cnt_src, pairs, srcbuf);
  k_bucket_csr<<<NB, 256, 0, stream>>>(pairs, bb_dst, row_ptr, norm_in, csr);
  k_bucket_deg<<<NB, 256, 0, stream>>>(srcbuf, bb_src, n_feat, norm_out, buf);

  // layer 1 fused: gather(d=8) + 8->16 + relu ; xs1 into agg region
  k_agglayer<8, 16><<<(NN + 255) / 256, 256, 0, stream>>>(buf, csr, row_ptr, norm_in,
                                                          norm_out, W1, b1, agg);
  // layer 2 fused: gather(d=16) + 16->32 + relu ; xs2 into buf
  k_agglayer<16, 32><<<(NN + 255) / 256, 256, 0, stream>>>(agg, csr, row_ptr, norm_in,
                                                           norm_out, W2, b2, buf);
  // layer 3 aggregate (d=32) -> agg, then MFMA tail (256 nodes/block)
  k_agg<32><<<(NN * 8 + 255) / 256, 256, 0, stream>>>(buf, csr, row_ptr, norm_in, agg);
  k_tail9<<<(NN + 255) / 256, 256, 0, stream>>>(agg, gid, wT, b3, fb1, fb2, fb3, fb4,
                                                inv_cnt, out);
}

// Round 13
// 224.892 us; speedup vs baseline: 1.7856x; 1.1491x over previous
//
#include <hip/hip_runtime.h>
#include <stdint.h>

#define NN 100000
#define NE 1600000
#define NG 256

#define NB 196    // node buckets of 512 nodes
#define BSH 9     // bucket shift (512)
#define NPB 392   // partition blocks
#define EPB 4096  // edges per partition block

typedef float f32x4 __attribute__((ext_vector_type(4)));
typedef short s16x8 __attribute__((ext_vector_type(8)));

// bf16 weight buffer layout (elems), [N][K] transposed, XOR-swizzled
#define WT_W3 0        // [128][32]  4096  swz (n&3)<<3
#define WT_F1 4096     // [128][64]  8192  swz (n&7)<<3
#define WT_F2 12288    // [64][128]  8192  swz (n&7)<<3
#define WT_F3 20480    // [32][64]   2048  swz (n&7)<<3
#define WT_F4 22528    // [16][32]   512   swz (n&3)<<3, rows 10..15 zero
#define WT_TOT 23040

#define OFF_NORM_OUT 0
#define OFF_NORM_IN  (NN)
#define OFF_INVC     (2 * NN)
#define OFF_ROWPTR   (2 * NN + 512)
#define OFF_CSR      (3 * NN + 516)
#define OFF_AGG      (3 * NN + 516 + NE)
#define OFF_BUF      (OFF_AGG + 32 * NN)
#define OFF_CNTD     (OFF_BUF + 32 * NN)
#define OFF_CNTS     (OFF_CNTD + NB * NPB)
#define OFF_BBD      (OFF_CNTS + NB * NPB)
#define OFF_BBS      (OFF_BBD + 200)
#define OFF_TOT      (OFF_BBS + 200)
#define OFF_WT       (OFF_TOT + 400)   // 23040 ushorts = 11520 words

__device__ __forceinline__ unsigned short f2bf(float f) {
  uint32_t u = __float_as_uint(f);
  u += 0x7fff + ((u >> 16) & 1);  // round to nearest even
  return (unsigned short)(u >> 16);
}
__device__ __forceinline__ float bf2f(unsigned short h) {
  return __uint_as_float(((uint32_t)h) << 16);
}

// ---------------- graph setup (unchanged) ----------------------------------
__global__ void __launch_bounds__(256) k_part_count(const int* __restrict__ src,
                                                    const int* __restrict__ dst,
                                                    int* __restrict__ cnt_dst,
                                                    int* __restrict__ cnt_src) {
  __shared__ int hd[NB], hs[NB];
  int t = threadIdx.x;
  int blk = blockIdx.x;
  for (int i = t; i < NB; i += 256) { hd[i] = 0; hs[i] = 0; }
  __syncthreads();
  int e0 = blk * EPB, e1 = min(e0 + EPB, NE);
  for (int e = e0 + t; e < e1; e += 256) {
    atomicAdd(&hd[dst[e] >> BSH], 1);
    atomicAdd(&hs[src[e] >> BSH], 1);
  }
  __syncthreads();
  for (int i = t; i < NB; i += 256) {
    cnt_dst[i * NPB + blk] = hd[i];
    cnt_src[i * NPB + blk] = hs[i];
  }
}

__global__ void __launch_bounds__(256) k_btot(const int* __restrict__ cnt_dst,
                                              const int* __restrict__ cnt_src,
                                              int* __restrict__ tot) {
  __shared__ int red[256];
  int m = blockIdx.x;
  const int* cnt = (m < NB) ? cnt_dst : cnt_src;
  int row = (m < NB) ? m : m - NB;
  int t = threadIdx.x;
  int s = 0;
  for (int k = t; k < NPB; k += 256) s += cnt[row * NPB + k];
  red[t] = s;
  __syncthreads();
  for (int off = 128; off; off >>= 1) {
    if (t < off) red[t] += red[t + off];
    __syncthreads();
  }
  if (t == 0) tot[m] = red[0];
}

__global__ void __launch_bounds__(256) k_bscan(const int* __restrict__ tot,
                                               int* __restrict__ bb_dst,
                                               int* __restrict__ bb_src) {
  __shared__ int tmp[256];
  int t = threadIdx.x;
  for (int p = 0; p < 2; ++p) {
    int* bb = p ? bb_src : bb_dst;
    int v = (t < NB) ? tot[p * NB + t] : 0;
    tmp[t] = v;
    __syncthreads();
    int incl = v;
    for (int off = 1; off < 256; off <<= 1) {
      int o = (t >= off) ? tmp[t - off] : 0;
      __syncthreads();
      incl += o;
      tmp[t] = incl;
      __syncthreads();
    }
    if (t < NB) bb[t] = incl - v;
    if (t == NB - 1) bb[NB] = incl;
    __syncthreads();
  }
}

__global__ void __launch_bounds__(256) k_crow(int* __restrict__ cnt_dst,
                                              int* __restrict__ cnt_src,
                                              const int* __restrict__ bb_dst,
                                              const int* __restrict__ bb_src) {
  __shared__ int tmp[256];
  int m = blockIdx.x;
  bool is_src = m >= NB;
  int row = is_src ? m - NB : m;
  int* cnt = is_src ? cnt_src : cnt_dst;
  const int* bb = is_src ? bb_src : bb_dst;
  int t = threadIdx.x;
  int i0 = 2 * t, i1 = 2 * t + 1;
  int v0 = (i0 < NPB) ? cnt[row * NPB + i0] : 0;
  int v1 = (i1 < NPB) ? cnt[row * NPB + i1] : 0;
  int ps = v0 + v1;
  tmp[t] = ps;
  __syncthreads();
  int incl = ps;
  for (int off = 1; off < 256; off <<= 1) {
    int o = (t >= off) ? tmp[t - off] : 0;
    __syncthreads();
    incl += o;
    tmp[t] = incl;
    __syncthreads();
  }
  int ex = incl - ps + bb[row];
  if (i0 < NPB) cnt[row * NPB + i0] = ex;
  if (i1 < NPB) cnt[row * NPB + i1] = ex + v0;
}

__global__ void __launch_bounds__(256) k_part_scatter(const int* __restrict__ src,
                                                      const int* __restrict__ dst,
                                                      const int* __restrict__ cnt_dst,
                                                      const int* __restrict__ cnt_src,
                                                      uint32_t* __restrict__ pairs,
                                                      uint16_t* __restrict__ srcbuf) {
  __shared__ int cd[NB], cs[NB];
  int t = threadIdx.x;
  int blk = blockIdx.x;
  for (int i = t; i < NB; i += 256) {
    cd[i] = cnt_dst[i * NPB + blk];
    cs[i] = cnt_src[i * NPB + blk];
  }
  __syncthreads();
  int e0 = blk * EPB, e1 = min(e0 + EPB, NE);
  for (int e = e0 + t; e < e1; e += 256) {
    int s = src[e], d = dst[e];
    int pd = atomicAdd(&cd[d >> BSH], 1);
    pairs[pd] = ((uint32_t)s << 9) | (uint32_t)(d & 511);
    int ps = atomicAdd(&cs[s >> BSH], 1);
    srcbuf[ps] = (uint16_t)(s & 511);
  }
}

__global__ void __launch_bounds__(256) k_bucket_csr(const uint32_t* __restrict__ pairs,
                                                    const int* __restrict__ bb,
                                                    int* __restrict__ row_ptr,
                                                    float* __restrict__ norm_in,
                                                    int* __restrict__ csr) {
  __shared__ int hist[512], curs[512], pscan[256];
  int t = threadIdx.x;
  int b = blockIdx.x;
  int n0 = b << BSH;
  int ebase = bb[b], eend = bb[b + 1];
  hist[t] = 0;
  hist[t + 256] = 0;
  __syncthreads();
  for (int e = ebase + t; e < eend; e += 256)
    atomicAdd(&hist[pairs[e] & 511], 1);
  __syncthreads();
  int s0 = hist[2 * t], s1 = hist[2 * t + 1];
  int ps = s0 + s1;
  pscan[t] = ps;
  __syncthreads();
  int incl = ps;
  for (int off = 1; off < 256; off <<= 1) {
    int o = (t >= off) ? pscan[t - off] : 0;
    __syncthreads();
    incl += o;
    pscan[t] = incl;
    __syncthreads();
  }
  int ex = incl - ps;
  curs[2 * t] = ex;
  curs[2 * t + 1] = ex + s0;
  int n = n0 + 2 * t;
  if (n < NN) {
    row_ptr[n] = ebase + ex;
    norm_in[n] = s0 > 0 ? 1.0f / sqrtf((float)s0) : 0.0f;
  }
  if (n + 1 < NN) {
    row_ptr[n + 1] = ebase + ex + s0;
    norm_in[n + 1] = s1 > 0 ? 1.0f / sqrtf((float)s1) : 0.0f;
  }
  __syncthreads();
  for (int e = ebase + t; e < eend; e += 256) {
    uint32_t pr = pairs[e];
    int pos = atomicAdd(&curs[pr & 511], 1);
    csr[ebase + pos] = (int)(pr >> 9);
  }
  if (b == 0 && t == 0) row_ptr[NN] = NE;
}

__global__ void __launch_bounds__(256) k_bucket_deg(const uint16_t* __restrict__ srcbuf,
                                                    const int* __restrict__ bb,
                                                    const float* __restrict__ n_feat,
                                                    float* __restrict__ norm_out,
                                                    float* __restrict__ xs) {
  __shared__ int hist[512];
  int t = threadIdx.x;
  int b = blockIdx.x;
  hist[t] = 0;
  hist[t + 256] = 0;
  __syncthreads();
  int e0 = bb[b], e1 = bb[b + 1];
  for (int e = e0 + t; e < e1; e += 256)
    atomicAdd(&hist[srcbuf[e]], 1);
  __syncthreads();
#pragma unroll
  for (int h = 0; h < 2; ++h) {
    int n = (b << BSH) + t + h * 256;
    if (n < NN) {
      int d = hist[t + h * 256];
      float no = d > 0 ? 1.0f / sqrtf((float)d) : 0.0f;
      norm_out[n] = no;
      float4 a = *reinterpret_cast<const float4*>(n_feat + (size_t)n * 8);
      float4 bb4 = *reinterpret_cast<const float4*>(n_feat + (size_t)n * 8 + 4);
      a.x *= no; a.y *= no; a.z *= no; a.w *= no;
      bb4.x *= no; bb4.y *= no; bb4.z *= no; bb4.w *= no;
      *reinterpret_cast<float4*>(xs + (size_t)n * 8) = a;
      *reinterpret_cast<float4*>(xs + (size_t)n * 8 + 4) = bb4;
    }
  }
}

__global__ void __launch_bounds__(NG) k_graphinfo(const int* __restrict__ gid,
                                                  float* __restrict__ inv) {
  int g = threadIdx.x;
  int lo0 = 0, hi0 = NN;
  while (lo0 < hi0) { int m = (lo0 + hi0) >> 1; if (gid[m] < g) lo0 = m + 1; else hi0 = m; }
  int lo1 = lo0, hi1 = NN;
  while (lo1 < hi1) { int m = (lo1 + hi1) >> 1; if (gid[m] < g + 1) lo1 = m + 1; else hi1 = m; }
  int c = lo1 - lo0;
  inv[g] = 1.0f / fmaxf((float)c, 1.0f);
}

// fused gather + linear + relu + *norm_out; INBF/OUTBF select bf16 I/O
template <int DIN, int DOUT, bool INBF, bool OUTBF>
__global__ void __launch_bounds__(256) k_agglayer(
    const void* __restrict__ xs_, const int* __restrict__ csr,
    const int* __restrict__ row_ptr, const float* __restrict__ norm_in,
    const float* __restrict__ norm_out, const float* __restrict__ W,
    const float* __restrict__ bvec, void* __restrict__ ys_) {
  int i = blockIdx.x * 256 + threadIdx.x;
  if (i >= NN) return;
  float acc[DIN];
#pragma unroll
  for (int k = 0; k < DIN; ++k) acc[k] = 0.f;
  int e0 = row_ptr[i], e1 = row_ptr[i + 1];
  for (int e = e0; e < e1; ++e) {
    int s = csr[e];
    if constexpr (INBF) {
      const unsigned short* xs = (const unsigned short*)xs_;
#pragma unroll
      for (int c = 0; c < DIN / 8; ++c) {
        s16x8 v = *reinterpret_cast<const s16x8*>(&xs[(size_t)s * DIN + c * 8]);
#pragma unroll
        for (int j = 0; j < 8; ++j)
          acc[c * 8 + j] += bf2f((unsigned short)v[j]);
      }
    } else {
      const float* xs = (const float*)xs_;
#pragma unroll
      for (int c = 0; c < DIN / 4; ++c) {
        float4 v = *reinterpret_cast<const float4*>(xs + (size_t)s * DIN + 4 * c);
        acc[4 * c + 0] += v.x;
        acc[4 * c + 1] += v.y;
        acc[4 * c + 2] += v.z;
        acc[4 * c + 3] += v.w;
      }
    }
  }
  float ni = norm_in[i];
#pragma unroll
  for (int k = 0; k < DIN; ++k) acc[k] *= ni;
  float no = norm_out[i];
  float y[DOUT];
#pragma unroll
  for (int j = 0; j < DOUT; ++j) {
    float s = bvec[j];
#pragma unroll
    for (int k = 0; k < DIN; ++k) s = fmaf(acc[k], W[k * DOUT + j], s);
    y[j] = fmaxf(s, 0.f) * no;
  }
  if constexpr (OUTBF) {
    unsigned short* ys = (unsigned short*)ys_;
#pragma unroll
    for (int c = 0; c < DOUT / 8; ++c) {
      s16x8 o;
#pragma unroll
      for (int j = 0; j < 8; ++j) o[j] = (short)f2bf(y[c * 8 + j]);
      *reinterpret_cast<s16x8*>(&ys[(size_t)i * DOUT + c * 8]) = o;
    }
  } else {
    float* ys = (float*)ys_;
#pragma unroll
    for (int c = 0; c < DOUT / 4; ++c) {
      float4 o = make_float4(y[4 * c], y[4 * c + 1], y[4 * c + 2], y[4 * c + 3]);
      *reinterpret_cast<float4*>(ys + (size_t)i * DOUT + 4 * c) = o;
    }
  }
}

// layer-3 gather: bf16 in, bf16 out (rows 64 B = 1 cache line per edge)
__global__ void k_agg32_bf(const unsigned short* __restrict__ xs,
                           const int* __restrict__ csr,
                           const int* __restrict__ row_ptr,
                           const float* __restrict__ norm_in,
                           unsigned short* __restrict__ aggb) {
  int t = blockIdx.x * blockDim.x + threadIdx.x;
  if (t >= NN * 4) return;
  int i = t >> 2;
  int c = t & 3;
  int e0 = row_ptr[i], e1 = row_ptr[i + 1];
  float acc[8];
#pragma unroll
  for (int j = 0; j < 8; ++j) acc[j] = 0.f;
  for (int e = e0; e < e1; ++e) {
    int s = csr[e];
    s16x8 v = *reinterpret_cast<const s16x8*>(&xs[(size_t)s * 32 + c * 8]);
#pragma unroll
    for (int j = 0; j < 8; ++j) acc[j] += bf2f((unsigned short)v[j]);
  }
  float ni = norm_in[i];
  s16x8 o;
#pragma unroll
  for (int j = 0; j < 8; ++j) o[j] = (short)f2bf(acc[j] * ni);
  *reinterpret_cast<s16x8*>(&aggb[(size_t)i * 32 + c * 8]) = o;
}

// ---------------------------------------------------------------------------
// Weight prep: transpose to [N][K], convert to bf16, pre-apply XOR swizzle.
// ---------------------------------------------------------------------------
__global__ void __launch_bounds__(256) k_prepw(
    const float* __restrict__ W3, const float* __restrict__ fW1,
    const float* __restrict__ fW2, const float* __restrict__ fW3,
    const float* __restrict__ fW4, unsigned short* __restrict__ wT) {
  int t = threadIdx.x;
  for (int i = t; i < 4096; i += 256) {          // W3T [128][32]
    int n = i >> 5, k = i & 31;
    wT[WT_W3 + ((n * 32 + k) ^ ((n & 3) << 3))] = f2bf(W3[k * 128 + n]);
  }
  for (int i = t; i < 8192; i += 256) {          // F1T [128][64]
    int n = i >> 6, k = i & 63;
    wT[WT_F1 + ((n * 64 + k) ^ ((n & 7) << 3))] = f2bf(fW1[k * 128 + n]);
  }
  for (int i = t; i < 8192; i += 256) {          // F2T [64][128]
    int n = i >> 7, k = i & 127;
    wT[WT_F2 + ((n * 128 + k) ^ ((n & 7) << 3))] = f2bf(fW2[k * 64 + n]);
  }
  for (int i = t; i < 2048; i += 256) {          // F3T [32][64]
    int n = i >> 6, k = i & 63;
    wT[WT_F3 + ((n * 64 + k) ^ ((n & 7) << 3))] = f2bf(fW3[k * 32 + n]);
  }
  for (int i = t; i < 512; i += 256) {           // F4T [16][32], pad rows >=10
    int n = i >> 5, k = i & 31;
    float v = (n < 10) ? fW4[k * 10 + n] : 0.f;
    wT[WT_F4 + ((n * 32 + k) ^ ((n & 3) << 3))] = f2bf(v);
  }
}

// ---------------------------------------------------------------------------
// Tail v9b (MFMA, 256 nodes/block): as round 12, but X comes in as bf16
// (straight s16x8 copy into swizzled LDS, no conversion).
// ---------------------------------------------------------------------------
__global__ void __launch_bounds__(256) k_tail9(
    const unsigned short* __restrict__ aggb, const int* __restrict__ gid,
    const unsigned short* __restrict__ wT,
    const float* __restrict__ b3, const float* __restrict__ fb1,
    const float* __restrict__ fb2, const float* __restrict__ fb3,
    const float* __restrict__ fb4, const float* __restrict__ inv_counts,
    float* __restrict__ out) {
  __shared__ __align__(16) unsigned short wv[WT_TOT];      // 45KB
  __shared__ __align__(16) unsigned short acts[4 * 3072];  // 24KB
  __shared__ int sgid[256];                                // 1KB
  int t = threadIdx.x;
  int l = t & 63;
  int w = t >> 6;
  int nb = blockIdx.x * 256;

  for (int i = t; i < WT_TOT / 8; i += 256)
    *reinterpret_cast<s16x8*>(&wv[i * 8]) =
        *reinterpret_cast<const s16x8*>(&wT[i * 8]);
  if (nb + t < NN) sgid[t] = gid[nb + t]; else sgid[t] = 0x7fffffff;
  __syncthreads();

  unsigned short* bufA = acts + w * 3072;         // X / Q / S
  unsigned short* bufB = acts + w * 3072 + 2048;  // P / R
  int m = l & 15;
  int kg = l >> 4;  // 0..3
  float fc4r[16];

#pragma unroll
  for (int g = 0; g < 4; ++g) {
    int base = nb + w * 64 + g * 16;
    // ---- stage X wave-locally (bf16 copy): node16 = l>>2, k-octet = l&3
    {
      int n16 = l >> 2, kq = l & 3;
      int node = base + n16;
      s16x8 xpk = {0, 0, 0, 0, 0, 0, 0, 0};
      if (node < NN)
        xpk = *reinterpret_cast<const s16x8*>(&aggb[(size_t)node * 32 + kq * 8]);
      int e = (n16 * 64 + kq * 8) ^ ((n16 & 7) << 3);
      *reinterpret_cast<s16x8*>(&bufA[e]) = xpk;
    }
    asm volatile("s_waitcnt lgkmcnt(0)" ::: "memory");

    // ---- L3: X[16x32] @ W3 + b3, maxpool(2) -> P[16][64] in bufB
#pragma unroll
    for (int nt = 0; nt < 8; ++nt) {
      int n = nt * 16 + m;
      f32x4 acc = {0.f, 0.f, 0.f, 0.f};
      s16x8 a = *reinterpret_cast<const s16x8*>(
          &bufA[(m * 64 + kg * 8) ^ ((m & 7) << 3)]);
      s16x8 b = *reinterpret_cast<const s16x8*>(
          &wv[WT_W3 + ((n * 32 + kg * 8) ^ ((n & 3) << 3))]);
      acc = __builtin_amdgcn_mfma_f32_16x16x32_bf16(a, b, acc, 0, 0, 0);
      float bias = b3[n];
#pragma unroll
      for (int r = 0; r < 4; ++r) {
        float v = acc[r] + bias;
        float pv = fmaxf(v, __shfl_xor(v, 1));
        if (!(m & 1)) {
          int node = kg * 4 + r;
          int j = n >> 1;
          bufB[(node * 64 + j) ^ ((node & 7) << 3)] = f2bf(pv);
        }
      }
    }
    asm volatile("s_waitcnt lgkmcnt(0)" ::: "memory");
    // ---- fc1: P[16x64] @ fW1 + fb1, relu -> Q[16][128] in bufA
#pragma unroll
    for (int nt = 0; nt < 8; ++nt) {
      int n = nt * 16 + m;
      f32x4 acc = {0.f, 0.f, 0.f, 0.f};
#pragma unroll
      for (int kt = 0; kt < 2; ++kt) {
        s16x8 a = *reinterpret_cast<const s16x8*>(
            &bufB[(m * 64 + kt * 32 + kg * 8) ^ ((m & 7) << 3)]);
        s16x8 b = *reinterpret_cast<const s16x8*>(
            &wv[WT_F1 + ((n * 64 + kt * 32 + kg * 8) ^ ((n & 7) << 3))]);
        acc = __builtin_amdgcn_mfma_f32_16x16x32_bf16(a, b, acc, 0, 0, 0);
      }
      float bias = fb1[n];
#pragma unroll
      for (int r = 0; r < 4; ++r) {
        int node = kg * 4 + r;
        float v = fmaxf(acc[r] + bias, 0.f);
        bufA[(node * 128 + n) ^ ((node & 7) << 3)] = f2bf(v);
      }
    }
    asm volatile("s_waitcnt lgkmcnt(0)" ::: "memory");
    // ---- fc2: Q[16x128] @ fW2 + fb2, relu -> R[16][64] in bufB
#pragma unroll
    for (int nt = 0; nt < 4; ++nt) {
      int n = nt * 16 + m;
      f32x4 acc = {0.f, 0.f, 0.f, 0.f};
#pragma unroll
      for (int kt = 0; kt < 4; ++kt) {
        s16x8 a = *reinterpret_cast<const s16x8*>(
            &bufA[(m * 128 + kt * 32 + kg * 8) ^ ((m & 7) << 3)]);
        s16x8 b = *reinterpret_cast<const s16x8*>(
            &wv[WT_F2 + ((n * 128 + kt * 32 + kg * 8) ^ ((n & 7) << 3))]);
        acc = __builtin_amdgcn_mfma_f32_16x16x32_bf16(a, b, acc, 0, 0, 0);
      }
      float bias = fb2[n];
#pragma unroll
      for (int r = 0; r < 4; ++r) {
        int node = kg * 4 + r;
        float v = fmaxf(acc[r] + bias, 0.f);
        bufB[(node * 64 + n) ^ ((node & 7) << 3)] = f2bf(v);
      }
    }
    asm volatile("s_waitcnt lgkmcnt(0)" ::: "memory");
    // ---- fc3: R[16x64] @ fW3 + fb3, relu -> S[16][32] in bufA (stride 64)
#pragma unroll
    for (int nt = 0; nt < 2; ++nt) {
      int n = nt * 16 + m;
      f32x4 acc = {0.f, 0.f, 0.f, 0.f};
#pragma unroll
      for (int kt = 0; kt < 2; ++kt) {
        s16x8 a = *reinterpret_cast<const s16x8*>(
            &bufB[(m * 64 + kt * 32 + kg * 8) ^ ((m & 7) << 3)]);
        s16x8 b = *reinterpret_cast<const s16x8*>(
            &wv[WT_F3 + ((n * 64 + kt * 32 + kg * 8) ^ ((n & 7) << 3))]);
        acc = __builtin_amdgcn_mfma_f32_16x16x32_bf16(a, b, acc, 0, 0, 0);
      }
      float bias = fb3[n];
#pragma unroll
      for (int r = 0; r < 4; ++r) {
        int node = kg * 4 + r;
        float v = fmaxf(acc[r] + bias, 0.f);
        bufA[(node * 64 + n) ^ ((node & 7) << 3)] = f2bf(v);
      }
    }
    asm volatile("s_waitcnt lgkmcnt(0)" ::: "memory");
    // ---- fc4: S[16x32] @ fW4p + fb4 -> regs (statically indexed by g)
    {
      f32x4 acc = {0.f, 0.f, 0.f, 0.f};
      s16x8 a = *reinterpret_cast<const s16x8*>(
          &bufA[(m * 64 + kg * 8) ^ ((m & 7) << 3)]);
      s16x8 b = *reinterpret_cast<const s16x8*>(
          &wv[WT_F4 + ((m * 32 + kg * 8) ^ ((m & 3) << 3))]);
      acc = __builtin_amdgcn_mfma_f32_16x16x32_bf16(a, b, acc, 0, 0, 0);
      float bias = (m < 10) ? fb4[m] : 0.f;
#pragma unroll
      for (int r = 0; r < 4; ++r) fc4r[g * 4 + r] = acc[r] + bias;
    }
  }

  // flush fc4 results into this wave's (now dead) act buffer as f32 [64][12]
  asm volatile("s_waitcnt lgkmcnt(0)" ::: "memory");
  {
    float* fbuf = reinterpret_cast<float*>(bufA);
    if (m < 10) {
#pragma unroll
      for (int g = 0; g < 4; ++g)
#pragma unroll
        for (int r = 0; r < 4; ++r) {
          int nl = g * 16 + kg * 4 + r;
          fbuf[nl * 12 + m] = fc4r[g * 4 + r];
        }
    }
  }
  __syncthreads();

  // segmented graph-mean: 4 teams of 10 threads, one per 64-node quarter
  if (t < 40) {
    int q = t / 10, j = t % 10;
    const float* fbuf = reinterpret_cast<const float*>(acts + q * 3072);
    int qbase = q * 64;
    int qrem = min(64, NN - (nb + qbase));
    if (qrem > 0) {
      int g = sgid[qbase];
      float run = 0.f;
      for (int n = 0; n < qrem; ++n) {
        run += fbuf[n * 12 + j];
        bool last = (n == qrem - 1) || (sgid[qbase + n + 1] != g);
        if (last) {
          atomicAdd(&out[g * 10 + j], run * inv_counts[g]);
          run = 0.f;
          if (n < qrem - 1) g = sgid[qbase + n + 1];
        }
      }
    }
  }
}

extern "C" void kernel_launch(void* const* d_in, const int* in_sizes, int n_in,
                              void* d_out, int out_size, void* d_ws, size_t ws_size,
                              hipStream_t stream) {
  const int* src = (const int*)d_in[0];
  const int* dst = (const int*)d_in[1];
  const int* gid = (const int*)d_in[2];
  const float* n_feat = (const float*)d_in[3];
  const float* W1 = (const float*)d_in[4];
  const float* b1 = (const float*)d_in[5];
  const float* W2 = (const float*)d_in[6];
  const float* b2 = (const float*)d_in[7];
  const float* W3 = (const float*)d_in[8];
  const float* b3 = (const float*)d_in[9];
  const float* fW1 = (const float*)d_in[10];
  const float* fb1 = (const float*)d_in[11];
  const float* fW2 = (const float*)d_in[12];
  const float* fb2 = (const float*)d_in[13];
  const float* fW3 = (const float*)d_in[14];
  const float* fb3 = (const float*)d_in[15];
  const float* fW4 = (const float*)d_in[16];
  const float* fb4 = (const float*)d_in[17];
  float* out = (float*)d_out;

  float* ws = (float*)d_ws;
  float* norm_out = ws + OFF_NORM_OUT;
  float* norm_in = ws + OFF_NORM_IN;
  float* inv_cnt = ws + OFF_INVC;
  int* row_ptr = (int*)(ws + OFF_ROWPTR);
  int* csr = (int*)(ws + OFF_CSR);
  float* agg = ws + OFF_AGG;
  float* buf = ws + OFF_BUF;
  int* cnt_dst = (int*)(ws + OFF_CNTD);
  int* cnt_src = (int*)(ws + OFF_CNTS);
  int* bb_dst = (int*)(ws + OFF_BBD);
  int* bb_src = (int*)(ws + OFF_BBS);
  int* tot = (int*)(ws + OFF_TOT);
  unsigned short* wT = (unsigned short*)(ws + OFF_WT);
  uint32_t* pairs = (uint32_t*)agg;                 // NE u32 inside agg region
  uint16_t* srcbuf = (uint16_t*)((int*)agg + NE);   // NE u16, after pairs
  unsigned short* xs1b = (unsigned short*)agg;      // [NN][16] bf16 (after pairs dead)
  unsigned short* xs2b = (unsigned short*)buf;      // [NN][32] bf16 (over xs0, dead)
  unsigned short* aggb = (unsigned short*)agg;      // [NN][32] bf16 (over xs1b, dead)

  hipMemsetAsync(out, 0, (size_t)out_size * sizeof(float), stream);

  k_prepw<<<1, 256, 0, stream>>>(W3, fW1, fW2, fW3, fW4, wT);
  k_part_count<<<NPB, 256, 0, stream>>>(src, dst, cnt_dst, cnt_src);
  k_graphinfo<<<1, NG, 0, stream>>>(gid, inv_cnt);
  k_btot<<<2 * NB, 256, 0, stream>>>(cnt_dst, cnt_src, tot);
  k_bscan<<<1, 256, 0, stream>>>(tot, bb_dst, bb_src);
  k_crow<<<2 * NB, 256, 0, stream>>>(cnt_dst, cnt_src, bb_dst, bb_src);
  k_part_scatter<<<NPB, 256, 0, stream>>>(src, dst, cnt_dst, cnt_src, pairs, srcbuf);
  k_bucket_csr<<<NB, 256, 0, stream>>>(pairs, bb_dst, row_ptr, norm_in, csr);
  k_bucket_deg<<<NB, 256, 0, stream>>>(srcbuf, bb_src, n_feat, norm_out, buf);

  // layer 1: gather(d=8, fp32) + 8->16 + relu -> xs1 bf16 (agg region)
  k_agglayer<8, 16, false, true><<<(NN + 255) / 256, 256, 0, stream>>>(
      buf, csr, row_ptr, norm_in, norm_out, W1, b1, xs1b);
  // layer 2: gather(d=16, bf16) + 16->32 + relu -> xs2 bf16 (buf region)
  k_agglayer<16, 32, true, true><<<(NN + 255) / 256, 256, 0, stream>>>(
      xs1b, csr, row_ptr, norm_in, norm_out, W2, b2, xs2b);
  // layer 3: bf16 gather (d=32) -> aggb bf16, then MFMA tail
  k_agg32_bf<<<(NN * 4 + 255) / 256, 256, 0, stream>>>(xs2b, csr, row_ptr, norm_in, aggb);
  k_tail9<<<(NN + 255) / 256, 256, 0, stream>>>(aggb, gid, wT, b3, fb1, fb2, fb3, fb4,
                                                inv_cnt, out);
}

// Round 14
// 215.994 us; speedup vs baseline: 1.8592x; 1.0412x over previous
//
#include <hip/hip_runtime.h>
#include <stdint.h>

#define NN 100000
#define NE 1600000
#define NG 256

#define NB 196    // node buckets of 512 nodes
#define BSH 9     // bucket shift (512)
#define NPB 392   // partition blocks
#define EPB 4096  // edges per partition block

typedef float f32x4 __attribute__((ext_vector_type(4)));
typedef short s16x8 __attribute__((ext_vector_type(8)));

// bf16 weight buffer layout (elems), [N][K] transposed, XOR-swizzled
#define WT_W3 0        // [128][32]  4096  swz (n&3)<<3
#define WT_F1 4096     // [128][64]  8192  swz (n&7)<<3
#define WT_F2 12288    // [64][128]  8192  swz (n&7)<<3
#define WT_F3 20480    // [32][64]   2048  swz (n&7)<<3
#define WT_F4 22528    // [16][32]   512   swz (n&3)<<3, rows 10..15 zero
#define WT_TOT 23040

#define OFF_NORM_OUT 0
#define OFF_NORM_IN  (NN)
#define OFF_INVC     (2 * NN)
#define OFF_ROWPTR   (2 * NN + 512)
#define OFF_CSR      (3 * NN + 516)
#define OFF_AGG      (3 * NN + 516 + NE)
#define OFF_BUF      (OFF_AGG + 32 * NN)
#define OFF_CNTD     (OFF_BUF + 32 * NN)
#define OFF_CNTS     (OFF_CNTD + NB * NPB)
#define OFF_BBD      (OFF_CNTS + NB * NPB)
#define OFF_BBS      (OFF_BBD + 200)
#define OFF_TOT      (OFF_BBS + 200)
#define OFF_WT       (OFF_TOT + 400)   // 23040 ushorts = 11520 words

__device__ __forceinline__ unsigned short f2bf(float f) {
  uint32_t u = __float_as_uint(f);
  u += 0x7fff + ((u >> 16) & 1);  // round to nearest even
  return (unsigned short)(u >> 16);
}
__device__ __forceinline__ float bf2f(unsigned short h) {
  return __uint_as_float(((uint32_t)h) << 16);
}

// ---------------- graph setup ----------------------------------------------
__global__ void __launch_bounds__(256) k_part_count(const int* __restrict__ src,
                                                    const int* __restrict__ dst,
                                                    int* __restrict__ cnt_dst,
                                                    int* __restrict__ cnt_src) {
  __shared__ int hd[NB], hs[NB];
  int t = threadIdx.x;
  int blk = blockIdx.x;
  for (int i = t; i < NB; i += 256) { hd[i] = 0; hs[i] = 0; }
  __syncthreads();
  int e0 = blk * EPB, e1 = min(e0 + EPB, NE);
  for (int e = e0 + t; e < e1; e += 256) {
    atomicAdd(&hd[dst[e] >> BSH], 1);
    atomicAdd(&hs[src[e] >> BSH], 1);
  }
  __syncthreads();
  for (int i = t; i < NB; i += 256) {
    cnt_dst[i * NPB + blk] = hd[i];
    cnt_src[i * NPB + blk] = hs[i];
  }
}

__global__ void __launch_bounds__(256) k_btot(const int* __restrict__ cnt_dst,
                                              const int* __restrict__ cnt_src,
                                              int* __restrict__ tot) {
  __shared__ int red[256];
  int m = blockIdx.x;
  const int* cnt = (m < NB) ? cnt_dst : cnt_src;
  int row = (m < NB) ? m : m - NB;
  int t = threadIdx.x;
  int s = 0;
  for (int k = t; k < NPB; k += 256) s += cnt[row * NPB + k];
  red[t] = s;
  __syncthreads();
  for (int off = 128; off; off >>= 1) {
    if (t < off) red[t] += red[t + off];
    __syncthreads();
  }
  if (t == 0) tot[m] = red[0];
}

__global__ void __launch_bounds__(256) k_bscan(const int* __restrict__ tot,
                                               int* __restrict__ bb_dst,
                                               int* __restrict__ bb_src) {
  __shared__ int tmp[256];
  int t = threadIdx.x;
  for (int p = 0; p < 2; ++p) {
    int* bb = p ? bb_src : bb_dst;
    int v = (t < NB) ? tot[p * NB + t] : 0;
    tmp[t] = v;
    __syncthreads();
    int incl = v;
    for (int off = 1; off < 256; off <<= 1) {
      int o = (t >= off) ? tmp[t - off] : 0;
      __syncthreads();
      incl += o;
      tmp[t] = incl;
      __syncthreads();
    }
    if (t < NB) bb[t] = incl - v;
    if (t == NB - 1) bb[NB] = incl;
    __syncthreads();
  }
}

__global__ void __launch_bounds__(256) k_crow(int* __restrict__ cnt_dst,
                                              int* __restrict__ cnt_src,
                                              const int* __restrict__ bb_dst,
                                              const int* __restrict__ bb_src) {
  __shared__ int tmp[256];
  int m = blockIdx.x;
  bool is_src = m >= NB;
  int row = is_src ? m - NB : m;
  int* cnt = is_src ? cnt_src : cnt_dst;
  const int* bb = is_src ? bb_src : bb_dst;
  int t = threadIdx.x;
  int i0 = 2 * t, i1 = 2 * t + 1;
  int v0 = (i0 < NPB) ? cnt[row * NPB + i0] : 0;
  int v1 = (i1 < NPB) ? cnt[row * NPB + i1] : 0;
  int ps = v0 + v1;
  tmp[t] = ps;
  __syncthreads();
  int incl = ps;
  for (int off = 1; off < 256; off <<= 1) {
    int o = (t >= off) ? tmp[t - off] : 0;
    __syncthreads();
    incl += o;
    tmp[t] = incl;
    __syncthreads();
  }
  int ex = incl - ps + bb[row];
  if (i0 < NPB) cnt[row * NPB + i0] = ex;
  if (i1 < NPB) cnt[row * NPB + i1] = ex + v0;
}

__global__ void __launch_bounds__(256) k_part_scatter(const int* __restrict__ src,
                                                      const int* __restrict__ dst,
                                                      const int* __restrict__ cnt_dst,
                                                      const int* __restrict__ cnt_src,
                                                      uint32_t* __restrict__ pairs,
                                                      uint16_t* __restrict__ srcbuf) {
  __shared__ int cd[NB], cs[NB];
  int t = threadIdx.x;
  int blk = blockIdx.x;
  for (int i = t; i < NB; i += 256) {
    cd[i] = cnt_dst[i * NPB + blk];
    cs[i] = cnt_src[i * NPB + blk];
  }
  __syncthreads();
  int e0 = blk * EPB, e1 = min(e0 + EPB, NE);
  for (int e = e0 + t; e < e1; e += 256) {
    int s = src[e], d = dst[e];
    int pd = atomicAdd(&cd[d >> BSH], 1);
    pairs[pd] = ((uint32_t)s << 9) | (uint32_t)(d & 511);
    int ps = atomicAdd(&cs[s >> BSH], 1);
    srcbuf[ps] = (uint16_t)(s & 511);
  }
}

__global__ void __launch_bounds__(256) k_bucket_csr(const uint32_t* __restrict__ pairs,
                                                    const int* __restrict__ bb,
                                                    int* __restrict__ row_ptr,
                                                    float* __restrict__ norm_in,
                                                    int* __restrict__ csr) {
  __shared__ int hist[512], curs[512], pscan[256];
  int t = threadIdx.x;
  int b = blockIdx.x;
  int n0 = b << BSH;
  int ebase = bb[b], eend = bb[b + 1];
  hist[t] = 0;
  hist[t + 256] = 0;
  __syncthreads();
  for (int e = ebase + t; e < eend; e += 256)
    atomicAdd(&hist[pairs[e] & 511], 1);
  __syncthreads();
  int s0 = hist[2 * t], s1 = hist[2 * t + 1];
  int ps = s0 + s1;
  pscan[t] = ps;
  __syncthreads();
  int incl = ps;
  for (int off = 1; off < 256; off <<= 1) {
    int o = (t >= off) ? pscan[t - off] : 0;
    __syncthreads();
    incl += o;
    pscan[t] = incl;
    __syncthreads();
  }
  int ex = incl - ps;
  curs[2 * t] = ex;
  curs[2 * t + 1] = ex + s0;
  int n = n0 + 2 * t;
  if (n < NN) {
    row_ptr[n] = ebase + ex;
    norm_in[n] = s0 > 0 ? 1.0f / sqrtf((float)s0) : 0.0f;
  }
  if (n + 1 < NN) {
    row_ptr[n + 1] = ebase + ex + s0;
    norm_in[n + 1] = s1 > 0 ? 1.0f / sqrtf((float)s1) : 0.0f;
  }
  __syncthreads();
  for (int e = ebase + t; e < eend; e += 256) {
    uint32_t pr = pairs[e];
    int pos = atomicAdd(&curs[pr & 511], 1);
    csr[ebase + pos] = (int)(pr >> 9);
  }
  if (b == 0 && t == 0) row_ptr[NN] = NE;
}

// out-degree -> norm_out, fused xs0 = bf16(n_feat * norm_out) [NN][8]
__global__ void __launch_bounds__(256) k_bucket_deg(const uint16_t* __restrict__ srcbuf,
                                                    const int* __restrict__ bb,
                                                    const float* __restrict__ n_feat,
                                                    float* __restrict__ norm_out,
                                                    unsigned short* __restrict__ xsb) {
  __shared__ int hist[512];
  int t = threadIdx.x;
  int b = blockIdx.x;
  hist[t] = 0;
  hist[t + 256] = 0;
  __syncthreads();
  int e0 = bb[b], e1 = bb[b + 1];
  for (int e = e0 + t; e < e1; e += 256)
    atomicAdd(&hist[srcbuf[e]], 1);
  __syncthreads();
#pragma unroll
  for (int h = 0; h < 2; ++h) {
    int n = (b << BSH) + t + h * 256;
    if (n < NN) {
      int d = hist[t + h * 256];
      float no = d > 0 ? 1.0f / sqrtf((float)d) : 0.0f;
      norm_out[n] = no;
      float4 a = *reinterpret_cast<const float4*>(n_feat + (size_t)n * 8);
      float4 bb4 = *reinterpret_cast<const float4*>(n_feat + (size_t)n * 8 + 4);
      s16x8 o;
      o[0] = (short)f2bf(a.x * no);   o[1] = (short)f2bf(a.y * no);
      o[2] = (short)f2bf(a.z * no);   o[3] = (short)f2bf(a.w * no);
      o[4] = (short)f2bf(bb4.x * no); o[5] = (short)f2bf(bb4.y * no);
      o[6] = (short)f2bf(bb4.z * no); o[7] = (short)f2bf(bb4.w * no);
      *reinterpret_cast<s16x8*>(&xsb[(size_t)n * 8]) = o;
    }
  }
}

__global__ void __launch_bounds__(NG) k_graphinfo(const int* __restrict__ gid,
                                                  float* __restrict__ inv) {
  int g = threadIdx.x;
  int lo0 = 0, hi0 = NN;
  while (lo0 < hi0) { int m = (lo0 + hi0) >> 1; if (gid[m] < g) lo0 = m + 1; else hi0 = m; }
  int lo1 = lo0, hi1 = NN;
  while (lo1 < hi1) { int m = (lo1 + hi1) >> 1; if (gid[m] < g + 1) lo1 = m + 1; else hi1 = m; }
  int c = lo1 - lo0;
  inv[g] = 1.0f / fmaxf((float)c, 1.0f);
}

// fused gather + linear + relu + *norm_out; bf16 in, bf16 out
template <int DIN, int DOUT>
__global__ void __launch_bounds__(256) k_agglayer(
    const unsigned short* __restrict__ xs, const int* __restrict__ csr,
    const int* __restrict__ row_ptr, const float* __restrict__ norm_in,
    const float* __restrict__ norm_out, const float* __restrict__ W,
    const float* __restrict__ bvec, unsigned short* __restrict__ ys) {
  int i = blockIdx.x * 256 + threadIdx.x;
  if (i >= NN) return;
  float acc[DIN];
#pragma unroll
  for (int k = 0; k < DIN; ++k) acc[k] = 0.f;
  int e0 = row_ptr[i], e1 = row_ptr[i + 1];
  for (int e = e0; e < e1; ++e) {
    int s = csr[e];
#pragma unroll
    for (int c = 0; c < DIN / 8; ++c) {
      s16x8 v = *reinterpret_cast<const s16x8*>(&xs[(size_t)s * DIN + c * 8]);
#pragma unroll
      for (int j = 0; j < 8; ++j)
        acc[c * 8 + j] += bf2f((unsigned short)v[j]);
    }
  }
  float ni = norm_in[i];
#pragma unroll
  for (int k = 0; k < DIN; ++k) acc[k] *= ni;
  float no = norm_out[i];
  float y[DOUT];
#pragma unroll
  for (int j = 0; j < DOUT; ++j) {
    float s = bvec[j];
#pragma unroll
    for (int k = 0; k < DIN; ++k) s = fmaf(acc[k], W[k * DOUT + j], s);
    y[j] = fmaxf(s, 0.f) * no;
  }
#pragma unroll
  for (int c = 0; c < DOUT / 8; ++c) {
    s16x8 o;
#pragma unroll
    for (int j = 0; j < 8; ++j) o[j] = (short)f2bf(y[c * 8 + j]);
    *reinterpret_cast<s16x8*>(&ys[(size_t)i * DOUT + c * 8]) = o;
  }
}

// layer-3 gather: bf16 in, bf16 out (rows 64 B = 1 cache line per edge)
__global__ void k_agg32_bf(const unsigned short* __restrict__ xs,
                           const int* __restrict__ csr,
                           const int* __restrict__ row_ptr,
                           const float* __restrict__ norm_in,
                           unsigned short* __restrict__ aggb) {
  int t = blockIdx.x * blockDim.x + threadIdx.x;
  if (t >= NN * 4) return;
  int i = t >> 2;
  int c = t & 3;
  int e0 = row_ptr[i], e1 = row_ptr[i + 1];
  float acc[8];
#pragma unroll
  for (int j = 0; j < 8; ++j) acc[j] = 0.f;
  for (int e = e0; e < e1; ++e) {
    int s = csr[e];
    s16x8 v = *reinterpret_cast<const s16x8*>(&xs[(size_t)s * 32 + c * 8]);
#pragma unroll
    for (int j = 0; j < 8; ++j) acc[j] += bf2f((unsigned short)v[j]);
  }
  float ni = norm_in[i];
  s16x8 o;
#pragma unroll
  for (int j = 0; j < 8; ++j) o[j] = (short)f2bf(acc[j] * ni);
  *reinterpret_cast<s16x8*>(&aggb[(size_t)i * 32 + c * 8]) = o;
}

// ---------------------------------------------------------------------------
// Weight prep (+ zero the 2560-float output; replaces the graph memset node).
// ---------------------------------------------------------------------------
__global__ void __launch_bounds__(256) k_prepw(
    const float* __restrict__ W3, const float* __restrict__ fW1,
    const float* __restrict__ fW2, const float* __restrict__ fW3,
    const float* __restrict__ fW4, unsigned short* __restrict__ wT,
    float* __restrict__ out, int out_size) {
  int t = threadIdx.x;
  for (int i = t; i < out_size; i += 256) out[i] = 0.f;
  for (int i = t; i < 4096; i += 256) {          // W3T [128][32]
    int n = i >> 5, k = i & 31;
    wT[WT_W3 + ((n * 32 + k) ^ ((n & 3) << 3))] = f2bf(W3[k * 128 + n]);
  }
  for (int i = t; i < 8192; i += 256) {          // F1T [128][64]
    int n = i >> 6, k = i & 63;
    wT[WT_F1 + ((n * 64 + k) ^ ((n & 7) << 3))] = f2bf(fW1[k * 128 + n]);
  }
  for (int i = t; i < 8192; i += 256) {          // F2T [64][128]
    int n = i >> 7, k = i & 127;
    wT[WT_F2 + ((n * 128 + k) ^ ((n & 7) << 3))] = f2bf(fW2[k * 64 + n]);
  }
  for (int i = t; i < 2048; i += 256) {          // F3T [32][64]
    int n = i >> 6, k = i & 63;
    wT[WT_F3 + ((n * 64 + k) ^ ((n & 7) << 3))] = f2bf(fW3[k * 32 + n]);
  }
  for (int i = t; i < 512; i += 256) {           // F4T [16][32], pad rows >=10
    int n = i >> 5, k = i & 31;
    float v = (n < 10) ? fW4[k * 10 + n] : 0.f;
    wT[WT_F4 + ((n * 32 + k) ^ ((n & 3) << 3))] = f2bf(v);
  }
}

// ---------------------------------------------------------------------------
// Tail v9b (MFMA, 256 nodes/block), bf16 X input.
// ---------------------------------------------------------------------------
__global__ void __launch_bounds__(256) k_tail9(
    const unsigned short* __restrict__ aggb, const int* __restrict__ gid,
    const unsigned short* __restrict__ wT,
    const float* __restrict__ b3, const float* __restrict__ fb1,
    const float* __restrict__ fb2, const float* __restrict__ fb3,
    const float* __restrict__ fb4, const float* __restrict__ inv_counts,
    float* __restrict__ out) {
  __shared__ __align__(16) unsigned short wv[WT_TOT];      // 45KB
  __shared__ __align__(16) unsigned short acts[4 * 3072];  // 24KB
  __shared__ int sgid[256];                                // 1KB
  int t = threadIdx.x;
  int l = t & 63;
  int w = t >> 6;
  int nb = blockIdx.x * 256;

  for (int i = t; i < WT_TOT / 8; i += 256)
    *reinterpret_cast<s16x8*>(&wv[i * 8]) =
        *reinterpret_cast<const s16x8*>(&wT[i * 8]);
  if (nb + t < NN) sgid[t] = gid[nb + t]; else sgid[t] = 0x7fffffff;
  __syncthreads();

  unsigned short* bufA = acts + w * 3072;         // X / Q / S
  unsigned short* bufB = acts + w * 3072 + 2048;  // P / R
  int m = l & 15;
  int kg = l >> 4;  // 0..3
  float fc4r[16];

#pragma unroll
  for (int g = 0; g < 4; ++g) {
    int base = nb + w * 64 + g * 16;
    // ---- stage X wave-locally (bf16 copy): node16 = l>>2, k-octet = l&3
    {
      int n16 = l >> 2, kq = l & 3;
      int node = base + n16;
      s16x8 xpk = {0, 0, 0, 0, 0, 0, 0, 0};
      if (node < NN)
        xpk = *reinterpret_cast<const s16x8*>(&aggb[(size_t)node * 32 + kq * 8]);
      int e = (n16 * 64 + kq * 8) ^ ((n16 & 7) << 3);
      *reinterpret_cast<s16x8*>(&bufA[e]) = xpk;
    }
    asm volatile("s_waitcnt lgkmcnt(0)" ::: "memory");

    // ---- L3: X[16x32] @ W3 + b3, maxpool(2) -> P[16][64] in bufB
#pragma unroll
    for (int nt = 0; nt < 8; ++nt) {
      int n = nt * 16 + m;
      f32x4 acc = {0.f, 0.f, 0.f, 0.f};
      s16x8 a = *reinterpret_cast<const s16x8*>(
          &bufA[(m * 64 + kg * 8) ^ ((m & 7) << 3)]);
      s16x8 b = *reinterpret_cast<const s16x8*>(
          &wv[WT_W3 + ((n * 32 + kg * 8) ^ ((n & 3) << 3))]);
      acc = __builtin_amdgcn_mfma_f32_16x16x32_bf16(a, b, acc, 0, 0, 0);
      float bias = b3[n];
#pragma unroll
      for (int r = 0; r < 4; ++r) {
        float v = acc[r] + bias;
        float pv = fmaxf(v, __shfl_xor(v, 1));
        if (!(m & 1)) {
          int node = kg * 4 + r;
          int j = n >> 1;
          bufB[(node * 64 + j) ^ ((node & 7) << 3)] = f2bf(pv);
        }
      }
    }
    asm volatile("s_waitcnt lgkmcnt(0)" ::: "memory");
    // ---- fc1: P[16x64] @ fW1 + fb1, relu -> Q[16][128] in bufA
#pragma unroll
    for (int nt = 0; nt < 8; ++nt) {
      int n = nt * 16 + m;
      f32x4 acc = {0.f, 0.f, 0.f, 0.f};
#pragma unroll
      for (int kt = 0; kt < 2; ++kt) {
        s16x8 a = *reinterpret_cast<const s16x8*>(
            &bufB[(m * 64 + kt * 32 + kg * 8) ^ ((m & 7) << 3)]);
        s16x8 b = *reinterpret_cast<const s16x8*>(
            &wv[WT_F1 + ((n * 64 + kt * 32 + kg * 8) ^ ((n & 7) << 3))]);
        acc = __builtin_amdgcn_mfma_f32_16x16x32_bf16(a, b, acc, 0, 0, 0);
      }
      float bias = fb1[n];
#pragma unroll
      for (int r = 0; r < 4; ++r) {
        int node = kg * 4 + r;
        float v = fmaxf(acc[r] + bias, 0.f);
        bufA[(node * 128 + n) ^ ((node & 7) << 3)] = f2bf(v);
      }
    }
    asm volatile("s_waitcnt lgkmcnt(0)" ::: "memory");
    // ---- fc2: Q[16x128] @ fW2 + fb2, relu -> R[16][64] in bufB
#pragma unroll
    for (int nt = 0; nt < 4; ++nt) {
      int n = nt * 16 + m;
      f32x4 acc = {0.f, 0.f, 0.f, 0.f};
#pragma unroll
      for (int kt = 0; kt < 4; ++kt) {
        s16x8 a = *reinterpret_cast<const s16x8*>(
            &bufA[(m * 128 + kt * 32 + kg * 8) ^ ((m & 7) << 3)]);
        s16x8 b = *reinterpret_cast<const s16x8*>(
            &wv[WT_F2 + ((n * 128 + kt * 32 + kg * 8) ^ ((n & 7) << 3))]);
        acc = __builtin_amdgcn_mfma_f32_16x16x32_bf16(a, b, acc, 0, 0, 0);
      }
      float bias = fb2[n];
#pragma unroll
      for (int r = 0; r < 4; ++r) {
        int node = kg * 4 + r;
        float v = fmaxf(acc[r] + bias, 0.f);
        bufB[(node * 64 + n) ^ ((node & 7) << 3)] = f2bf(v);
      }
    }
    asm volatile("s_waitcnt lgkmcnt(0)" ::: "memory");
    // ---- fc3: R[16x64] @ fW3 + fb3, relu -> S[16][32] in bufA (stride 64)
#pragma unroll
    for (int nt = 0; nt < 2; ++nt) {
      int n = nt * 16 + m;
      f32x4 acc = {0.f, 0.f, 0.f, 0.f};
#pragma unroll
      for (int kt = 0; kt < 2; ++kt) {
        s16x8 a = *reinterpret_cast<const s16x8*>(
            &bufB[(m * 64 + kt * 32 + kg * 8) ^ ((m & 7) << 3)]);
        s16x8 b = *reinterpret_cast<const s16x8*>(
            &wv[WT_F3 + ((n * 64 + kt * 32 + kg * 8) ^ ((n & 7) << 3))]);
        acc = __builtin_amdgcn_mfma_f32_16x16x32_bf16(a, b, acc, 0, 0, 0);
      }
      float bias = fb3[n];
#pragma unroll
      for (int r = 0; r < 4; ++r) {
        int node = kg * 4 + r;
        float v = fmaxf(acc[r] + bias, 0.f);
        bufA[(node * 64 + n) ^ ((node & 7) << 3)] = f2bf(v);
      }
    }
    asm volatile("s_waitcnt lgkmcnt(0)" ::: "memory");
    // ---- fc4: S[16x32] @ fW4p + fb4 -> regs (statically indexed by g)
    {
      f32x4 acc = {0.f, 0.f, 0.f, 0.f};
      s16x8 a = *reinterpret_cast<const s16x8*>(
          &bufA[(m * 64 + kg * 8) ^ ((m & 7) << 3)]);
      s16x8 b = *reinterpret_cast<const s16x8*>(
          &wv[WT_F4 + ((m * 32 + kg * 8) ^ ((m & 3) << 3))]);
      acc = __builtin_amdgcn_mfma_f32_16x16x32_bf16(a, b, acc, 0, 0, 0);
      float bias = (m < 10) ? fb4[m] : 0.f;
#pragma unroll
      for (int r = 0; r < 4; ++r) fc4r[g * 4 + r] = acc[r] + bias;
    }
  }

  // flush fc4 results into this wave's (now dead) act buffer as f32 [64][12]
  asm volatile("s_waitcnt lgkmcnt(0)" ::: "memory");
  {
    float* fbuf = reinterpret_cast<float*>(bufA);
    if (m < 10) {
#pragma unroll
      for (int g = 0; g < 4; ++g)
#pragma unroll
        for (int r = 0; r < 4; ++r) {
          int nl = g * 16 + kg * 4 + r;
          fbuf[nl * 12 + m] = fc4r[g * 4 + r];
        }
    }
  }
  __syncthreads();

  // segmented graph-mean: 4 teams of 10 threads, one per 64-node quarter
  if (t < 40) {
    int q = t / 10, j = t % 10;
    const float* fbuf = reinterpret_cast<const float*>(acts + q * 3072);
    int qbase = q * 64;
    int qrem = min(64, NN - (nb + qbase));
    if (qrem > 0) {
      int g = sgid[qbase];
      float run = 0.f;
      for (int n = 0; n < qrem; ++n) {
        run += fbuf[n * 12 + j];
        bool last = (n == qrem - 1) || (sgid[qbase + n + 1] != g);
        if (last) {
          atomicAdd(&out[g * 10 + j], run * inv_counts[g]);
          run = 0.f;
          if (n < qrem - 1) g = sgid[qbase + n + 1];
        }
      }
    }
  }
}

extern "C" void kernel_launch(void* const* d_in, const int* in_sizes, int n_in,
                              void* d_out, int out_size, void* d_ws, size_t ws_size,
                              hipStream_t stream) {
  const int* src = (const int*)d_in[0];
  const int* dst = (const int*)d_in[1];
  const int* gid = (const int*)d_in[2];
  const float* n_feat = (const float*)d_in[3];
  const float* W1 = (const float*)d_in[4];
  const float* b1 = (const float*)d_in[5];
  const float* W2 = (const float*)d_in[6];
  const float* b2 = (const float*)d_in[7];
  const float* W3 = (const float*)d_in[8];
  const float* b3 = (const float*)d_in[9];
  const float* fW1 = (const float*)d_in[10];
  const float* fb1 = (const float*)d_in[11];
  const float* fW2 = (const float*)d_in[12];
  const float* fb2 = (const float*)d_in[13];
  const float* fW3 = (const float*)d_in[14];
  const float* fb3 = (const float*)d_in[15];
  const float* fW4 = (const float*)d_in[16];
  const float* fb4 = (const float*)d_in[17];
  float* out = (float*)d_out;

  float* ws = (float*)d_ws;
  float* norm_out = ws + OFF_NORM_OUT;
  float* norm_in = ws + OFF_NORM_IN;
  float* inv_cnt = ws + OFF_INVC;
  int* row_ptr = (int*)(ws + OFF_ROWPTR);
  int* csr = (int*)(ws + OFF_CSR);
  float* agg = ws + OFF_AGG;
  float* buf = ws + OFF_BUF;
  int* cnt_dst = (int*)(ws + OFF_CNTD);
  int* cnt_src = (int*)(ws + OFF_CNTS);
  int* bb_dst = (int*)(ws + OFF_BBD);
  int* bb_src = (int*)(ws + OFF_BBS);
  int* tot = (int*)(ws + OFF_TOT);
  unsigned short* wT = (unsigned short*)(ws + OFF_WT);
  uint32_t* pairs = (uint32_t*)agg;                 // NE u32 inside agg region
  uint16_t* srcbuf = (uint16_t*)((int*)agg + NE);   // NE u16, after pairs
  unsigned short* xs0b = (unsigned short*)buf;      // [NN][8]  bf16
  unsigned short* xs1b = (unsigned short*)agg;      // [NN][16] bf16 (pairs dead)
  unsigned short* xs2b = (unsigned short*)buf;      // [NN][32] bf16 (xs0 dead)
  unsigned short* aggb = (unsigned short*)agg;      // [NN][32] bf16 (xs1 dead)

  k_prepw<<<1, 256, 0, stream>>>(W3, fW1, fW2, fW3, fW4, wT, out, out_size);
  k_part_count<<<NPB, 256, 0, stream>>>(src, dst, cnt_dst, cnt_src);
  k_graphinfo<<<1, NG, 0, stream>>>(gid, inv_cnt);
  k_btot<<<2 * NB, 256, 0, stream>>>(cnt_dst, cnt_src, tot);
  k_bscan<<<1, 256, 0, stream>>>(tot, bb_dst, bb_src);
  k_crow<<<2 * NB, 256, 0, stream>>>(cnt_dst, cnt_src, bb_dst, bb_src);
  k_part_scatter<<<NPB, 256, 0, stream>>>(src, dst, cnt_dst, cnt_src, pairs, srcbuf);
  k_bucket_csr<<<NB, 256, 0, stream>>>(pairs, bb_dst, row_ptr, norm_in, csr);
  k_bucket_deg<<<NB, 256, 0, stream>>>(srcbuf, bb_src, n_feat, norm_out, xs0b);

  // layer 1: gather(d=8, bf16) + 8->16 + relu -> xs1 bf16 (agg region)
  k_agglayer<8, 16><<<(NN + 255) / 256, 256, 0, stream>>>(
      xs0b, csr, row_ptr, norm_in, norm_out, W1, b1, xs1b);
  // layer 2: gather(d=16, bf16) + 16->32 + relu -> xs2 bf16 (buf region)
  k_agglayer<16, 32><<<(NN + 255) / 256, 256, 0, stream>>>(
      xs1b, csr, row_ptr, norm_in, norm_out, W2, b2, xs2b);
  // layer 3: bf16 gather (d=32) -> aggb bf16, then MFMA tail
  k_agg32_bf<<<(NN * 4 + 255) / 256, 256, 0, stream>>>(xs2b, csr, row_ptr, norm_in, aggb);
  k_tail9<<<(NN + 255) / 256, 256, 0, stream>>>(aggb, gid, wT, b3, fb1, fb2, fb3, fb4,
                                                inv_cnt, out);
}

// Round 15
// 202.148 us; speedup vs baseline: 1.9865x; 1.0685x over previous
//
#include <hip/hip_runtime.h>
#include <stdint.h>

#define NN 100000
#define NE 1600000
#define NG 256

#define NB 196    // node buckets of 512 nodes
#define BSH 9     // bucket shift (512)
#define NPB 392   // partition blocks
#define EPB 4096  // edges per partition block

typedef float f32x4 __attribute__((ext_vector_type(4)));
typedef short s16x8 __attribute__((ext_vector_type(8)));

// bf16 weight buffer layout (elems), [N][K] transposed, XOR-swizzled
#define WT_W3 0        // [128][32]  4096  swz (n&3)<<3
#define WT_F1 4096     // [128][64]  8192  swz (n&7)<<3
#define WT_F2 12288    // [64][128]  8192  swz (n&7)<<3
#define WT_F3 20480    // [32][64]   2048  swz (n&7)<<3
#define WT_F4 22528    // [16][32]   512   swz (n&3)<<3, rows 10..15 zero
#define WT_TOT 23040

#define OFF_NORM_OUT 0
#define OFF_NORM_IN  (NN)
#define OFF_INVC     (2 * NN)
#define OFF_ROWPTR   (2 * NN + 512)
#define OFF_CSR      (3 * NN + 516)
#define OFF_AGG      (3 * NN + 516 + NE)
#define OFF_BUF      (OFF_AGG + 32 * NN)
#define OFF_CNTD     (OFF_BUF + 32 * NN)
#define OFF_CNTS     (OFF_CNTD + NB * NPB)
#define OFF_BBD      (OFF_CNTS + NB * NPB)
#define OFF_BBS      (OFF_BBD + 200)
#define OFF_TOT      (OFF_BBS + 200)
#define OFF_WT       (OFF_TOT + 400)   // 23040 ushorts = 11520 words

__device__ __forceinline__ unsigned short f2bf(float f) {
  uint32_t u = __float_as_uint(f);
  u += 0x7fff + ((u >> 16) & 1);  // round to nearest even
  return (unsigned short)(u >> 16);
}
__device__ __forceinline__ float bf2f(unsigned short h) {
  return __uint_as_float(((uint32_t)h) << 16);
}

// ---------------------------------------------------------------------------
// prep: zero out, transpose/convert/swizzle weights, graph sizes (1 block)
// ---------------------------------------------------------------------------
__global__ void __launch_bounds__(256) k_prepw(
    const float* __restrict__ W3, const float* __restrict__ fW1,
    const float* __restrict__ fW2, const float* __restrict__ fW3,
    const float* __restrict__ fW4, unsigned short* __restrict__ wT,
    float* __restrict__ out, int out_size,
    const int* __restrict__ gid, float* __restrict__ inv) {
  int t = threadIdx.x;
  for (int i = t; i < out_size; i += 256) out[i] = 0.f;
  for (int i = t; i < 4096; i += 256) {          // W3T [128][32]
    int n = i >> 5, k = i & 31;
    wT[WT_W3 + ((n * 32 + k) ^ ((n & 3) << 3))] = f2bf(W3[k * 128 + n]);
  }
  for (int i = t; i < 8192; i += 256) {          // F1T [128][64]
    int n = i >> 6, k = i & 63;
    wT[WT_F1 + ((n * 64 + k) ^ ((n & 7) << 3))] = f2bf(fW1[k * 128 + n]);
  }
  for (int i = t; i < 8192; i += 256) {          // F2T [64][128]
    int n = i >> 7, k = i & 127;
    wT[WT_F2 + ((n * 128 + k) ^ ((n & 7) << 3))] = f2bf(fW2[k * 64 + n]);
  }
  for (int i = t; i < 2048; i += 256) {          // F3T [32][64]
    int n = i >> 6, k = i & 63;
    wT[WT_F3 + ((n * 64 + k) ^ ((n & 7) << 3))] = f2bf(fW3[k * 32 + n]);
  }
  for (int i = t; i < 512; i += 256) {           // F4T [16][32], pad rows >=10
    int n = i >> 5, k = i & 31;
    float v = (n < 10) ? fW4[k * 10 + n] : 0.f;
    wT[WT_F4 + ((n * 32 + k) ^ ((n & 3) << 3))] = f2bf(v);
  }
  // graph sizes via binary search on sorted gid (thread t = graph t)
  {
    int g = t;
    int lo0 = 0, hi0 = NN;
    while (lo0 < hi0) { int m = (lo0 + hi0) >> 1; if (gid[m] < g) lo0 = m + 1; else hi0 = m; }
    int lo1 = lo0, hi1 = NN;
    while (lo1 < hi1) { int m = (lo1 + hi1) >> 1; if (gid[m] < g + 1) lo1 = m + 1; else hi1 = m; }
    int c = lo1 - lo0;
    inv[g] = 1.0f / fmaxf((float)c, 1.0f);
  }
}

// ---------------- graph setup ----------------------------------------------
__global__ void __launch_bounds__(256) k_part_count(const int* __restrict__ src,
                                                    const int* __restrict__ dst,
                                                    int* __restrict__ cnt_dst,
                                                    int* __restrict__ cnt_src) {
  __shared__ int hd[NB], hs[NB];
  int t = threadIdx.x;
  int blk = blockIdx.x;
  for (int i = t; i < NB; i += 256) { hd[i] = 0; hs[i] = 0; }
  __syncthreads();
  int e0 = blk * EPB, e1 = min(e0 + EPB, NE);
  for (int e = e0 + t; e < e1; e += 256) {
    atomicAdd(&hd[dst[e] >> BSH], 1);
    atomicAdd(&hs[src[e] >> BSH], 1);
  }
  __syncthreads();
  for (int i = t; i < NB; i += 256) {
    cnt_dst[i * NPB + blk] = hd[i];
    cnt_src[i * NPB + blk] = hs[i];
  }
}

__global__ void __launch_bounds__(256) k_btot(const int* __restrict__ cnt_dst,
                                              const int* __restrict__ cnt_src,
                                              int* __restrict__ tot) {
  __shared__ int red[256];
  int m = blockIdx.x;
  const int* cnt = (m < NB) ? cnt_dst : cnt_src;
  int row = (m < NB) ? m : m - NB;
  int t = threadIdx.x;
  int s = 0;
  for (int k = t; k < NPB; k += 256) s += cnt[row * NPB + k];
  red[t] = s;
  __syncthreads();
  for (int off = 128; off; off >>= 1) {
    if (t < off) red[t] += red[t + off];
    __syncthreads();
  }
  if (t == 0) tot[m] = red[0];
}

// chunk prefix per row + bucket bases (absorbs the old k_bscan)
__global__ void __launch_bounds__(256) k_crow(int* __restrict__ cnt_dst,
                                              int* __restrict__ cnt_src,
                                              const int* __restrict__ tot,
                                              int* __restrict__ bb_dst,
                                              int* __restrict__ bb_src) {
  __shared__ int tmp[256];
  __shared__ int sbase;
  int m = blockIdx.x;
  bool is_src = m >= NB;
  int row = is_src ? m - NB : m;
  int* cnt = is_src ? cnt_src : cnt_dst;
  int* bb = is_src ? bb_src : bb_dst;
  const int* trow = tot + (is_src ? NB : 0);
  int t = threadIdx.x;

  // scan bucket totals -> this row's bucket base (and bb for one block/side)
  int v = (t < NB) ? trow[t] : 0;
  tmp[t] = v;
  __syncthreads();
  int incl = v;
  for (int off = 1; off < 256; off <<= 1) {
    int o = (t >= off) ? tmp[t - off] : 0;
    __syncthreads();
    incl += o;
    tmp[t] = incl;
    __syncthreads();
  }
  if (t == row) sbase = incl - v;
  if (row == 0) {  // first block of each side writes the bb array
    if (t < NB) bb[t] = incl - v;
    if (t == NB - 1) bb[NB] = incl;
  }
  __syncthreads();
  int base = sbase;

  // per-chunk prefix within the row
  int i0 = 2 * t, i1 = 2 * t + 1;
  int v0 = (i0 < NPB) ? cnt[row * NPB + i0] : 0;
  int v1 = (i1 < NPB) ? cnt[row * NPB + i1] : 0;
  int ps = v0 + v1;
  tmp[t] = ps;
  __syncthreads();
  int incl2 = ps;
  for (int off = 1; off < 256; off <<= 1) {
    int o = (t >= off) ? tmp[t - off] : 0;
    __syncthreads();
    incl2 += o;
    tmp[t] = incl2;
    __syncthreads();
  }
  int ex = incl2 - ps + base;
  if (i0 < NPB) cnt[row * NPB + i0] = ex;
  if (i1 < NPB) cnt[row * NPB + i1] = ex + v0;
}

__global__ void __launch_bounds__(256) k_part_scatter(const int* __restrict__ src,
                                                      const int* __restrict__ dst,
                                                      const int* __restrict__ cnt_dst,
                                                      const int* __restrict__ cnt_src,
                                                      uint32_t* __restrict__ pairs,
                                                      uint16_t* __restrict__ srcbuf) {
  __shared__ int cd[NB], cs[NB];
  int t = threadIdx.x;
  int blk = blockIdx.x;
  for (int i = t; i < NB; i += 256) {
    cd[i] = cnt_dst[i * NPB + blk];
    cs[i] = cnt_src[i * NPB + blk];
  }
  __syncthreads();
  int e0 = blk * EPB, e1 = min(e0 + EPB, NE);
  for (int e = e0 + t; e < e1; e += 256) {
    int s = src[e], d = dst[e];
    int pd = atomicAdd(&cd[d >> BSH], 1);
    pairs[pd] = ((uint32_t)s << 9) | (uint32_t)(d & 511);
    int ps = atomicAdd(&cs[s >> BSH], 1);
    srcbuf[ps] = (uint16_t)(s & 511);
  }
}

// merged per-bucket finalize: blocks [0,NB) build CSR side, [NB,2NB) deg side
__global__ void __launch_bounds__(256) k_bucket(
    const uint32_t* __restrict__ pairs, const int* __restrict__ bb_dst,
    const uint16_t* __restrict__ srcbuf, const int* __restrict__ bb_src,
    const float* __restrict__ n_feat,
    int* __restrict__ row_ptr, float* __restrict__ norm_in, int* __restrict__ csr,
    float* __restrict__ norm_out, unsigned short* __restrict__ xsb) {
  __shared__ int hist[512], curs[512], pscan[256];
  int t = threadIdx.x;
  int m = blockIdx.x;
  if (m < NB) {
    // ---- CSR side ----
    int b = m;
    int n0 = b << BSH;
    int ebase = bb_dst[b], eend = bb_dst[b + 1];
    hist[t] = 0;
    hist[t + 256] = 0;
    __syncthreads();
    for (int e = ebase + t; e < eend; e += 256)
      atomicAdd(&hist[pairs[e] & 511], 1);
    __syncthreads();
    int s0 = hist[2 * t], s1 = hist[2 * t + 1];
    int ps = s0 + s1;
    pscan[t] = ps;
    __syncthreads();
    int incl = ps;
    for (int off = 1; off < 256; off <<= 1) {
      int o = (t >= off) ? pscan[t - off] : 0;
      __syncthreads();
      incl += o;
      pscan[t] = incl;
      __syncthreads();
    }
    int ex = incl - ps;
    curs[2 * t] = ex;
    curs[2 * t + 1] = ex + s0;
    int n = n0 + 2 * t;
    if (n < NN) {
      row_ptr[n] = ebase + ex;
      norm_in[n] = s0 > 0 ? 1.0f / sqrtf((float)s0) : 0.0f;
    }
    if (n + 1 < NN) {
      row_ptr[n + 1] = ebase + ex + s0;
      norm_in[n + 1] = s1 > 0 ? 1.0f / sqrtf((float)s1) : 0.0f;
    }
    __syncthreads();
    for (int e = ebase + t; e < eend; e += 256) {
      uint32_t pr = pairs[e];
      int pos = atomicAdd(&curs[pr & 511], 1);
      csr[ebase + pos] = (int)(pr >> 9);
    }
    if (b == 0 && t == 0) row_ptr[NN] = NE;
  } else {
    // ---- deg side: out-degree -> norm_out, xs0 = bf16(n_feat * norm_out) ----
    int b = m - NB;
    hist[t] = 0;
    hist[t + 256] = 0;
    __syncthreads();
    int e0 = bb_src[b], e1 = bb_src[b + 1];
    for (int e = e0 + t; e < e1; e += 256)
      atomicAdd(&hist[srcbuf[e]], 1);
    __syncthreads();
#pragma unroll
    for (int h = 0; h < 2; ++h) {
      int n = (b << BSH) + t + h * 256;
      if (n < NN) {
        int d = hist[t + h * 256];
        float no = d > 0 ? 1.0f / sqrtf((float)d) : 0.0f;
        norm_out[n] = no;
        float4 a = *reinterpret_cast<const float4*>(n_feat + (size_t)n * 8);
        float4 bb4 = *reinterpret_cast<const float4*>(n_feat + (size_t)n * 8 + 4);
        s16x8 o;
        o[0] = (short)f2bf(a.x * no);   o[1] = (short)f2bf(a.y * no);
        o[2] = (short)f2bf(a.z * no);   o[3] = (short)f2bf(a.w * no);
        o[4] = (short)f2bf(bb4.x * no); o[5] = (short)f2bf(bb4.y * no);
        o[6] = (short)f2bf(bb4.z * no); o[7] = (short)f2bf(bb4.w * no);
        *reinterpret_cast<s16x8*>(&xsb[(size_t)n * 8]) = o;
      }
    }
  }
}

// fused gather + linear + relu + *norm_out; bf16 in, bf16 out
template <int DIN, int DOUT>
__global__ void __launch_bounds__(256) k_agglayer(
    const unsigned short* __restrict__ xs, const int* __restrict__ csr,
    const int* __restrict__ row_ptr, const float* __restrict__ norm_in,
    const float* __restrict__ norm_out, const float* __restrict__ W,
    const float* __restrict__ bvec, unsigned short* __restrict__ ys) {
  int i = blockIdx.x * 256 + threadIdx.x;
  if (i >= NN) return;
  float acc[DIN];
#pragma unroll
  for (int k = 0; k < DIN; ++k) acc[k] = 0.f;
  int e0 = row_ptr[i], e1 = row_ptr[i + 1];
  for (int e = e0; e < e1; ++e) {
    int s = csr[e];
#pragma unroll
    for (int c = 0; c < DIN / 8; ++c) {
      s16x8 v = *reinterpret_cast<const s16x8*>(&xs[(size_t)s * DIN + c * 8]);
#pragma unroll
      for (int j = 0; j < 8; ++j)
        acc[c * 8 + j] += bf2f((unsigned short)v[j]);
    }
  }
  float ni = norm_in[i];
#pragma unroll
  for (int k = 0; k < DIN; ++k) acc[k] *= ni;
  float no = norm_out[i];
  float y[DOUT];
#pragma unroll
  for (int j = 0; j < DOUT; ++j) {
    float s = bvec[j];
#pragma unroll
    for (int k = 0; k < DIN; ++k) s = fmaf(acc[k], W[k * DOUT + j], s);
    y[j] = fmaxf(s, 0.f) * no;
  }
#pragma unroll
  for (int c = 0; c < DOUT / 8; ++c) {
    s16x8 o;
#pragma unroll
    for (int j = 0; j < 8; ++j) o[j] = (short)f2bf(y[c * 8 + j]);
    *reinterpret_cast<s16x8*>(&ys[(size_t)i * DOUT + c * 8]) = o;
  }
}

// layer-3 gather: bf16 in, bf16 out (rows 64 B = 1 cache line per edge)
__global__ void k_agg32_bf(const unsigned short* __restrict__ xs,
                           const int* __restrict__ csr,
                           const int* __restrict__ row_ptr,
                           const float* __restrict__ norm_in,
                           unsigned short* __restrict__ aggb) {
  int t = blockIdx.x * blockDim.x + threadIdx.x;
  if (t >= NN * 4) return;
  int i = t >> 2;
  int c = t & 3;
  int e0 = row_ptr[i], e1 = row_ptr[i + 1];
  float acc[8];
#pragma unroll
  for (int j = 0; j < 8; ++j) acc[j] = 0.f;
  for (int e = e0; e < e1; ++e) {
    int s = csr[e];
    s16x8 v = *reinterpret_cast<const s16x8*>(&xs[(size_t)s * 32 + c * 8]);
#pragma unroll
    for (int j = 0; j < 8; ++j) acc[j] += bf2f((unsigned short)v[j]);
  }
  float ni = norm_in[i];
  s16x8 o;
#pragma unroll
  for (int j = 0; j < 8; ++j) o[j] = (short)f2bf(acc[j] * ni);
  *reinterpret_cast<s16x8*>(&aggb[(size_t)i * 32 + c * 8]) = o;
}

// ---------------------------------------------------------------------------
// Tail v9b (MFMA, 256 nodes/block), bf16 X input.
// ---------------------------------------------------------------------------
__global__ void __launch_bounds__(256) k_tail9(
    const unsigned short* __restrict__ aggb, const int* __restrict__ gid,
    const unsigned short* __restrict__ wT,
    const float* __restrict__ b3, const float* __restrict__ fb1,
    const float* __restrict__ fb2, const float* __restrict__ fb3,
    const float* __restrict__ fb4, const float* __restrict__ inv_counts,
    float* __restrict__ out) {
  __shared__ __align__(16) unsigned short wv[WT_TOT];      // 45KB
  __shared__ __align__(16) unsigned short acts[4 * 3072];  // 24KB
  __shared__ int sgid[256];                                // 1KB
  int t = threadIdx.x;
  int l = t & 63;
  int w = t >> 6;
  int nb = blockIdx.x * 256;

  for (int i = t; i < WT_TOT / 8; i += 256)
    *reinterpret_cast<s16x8*>(&wv[i * 8]) =
        *reinterpret_cast<const s16x8*>(&wT[i * 8]);
  if (nb + t < NN) sgid[t] = gid[nb + t]; else sgid[t] = 0x7fffffff;
  __syncthreads();

  unsigned short* bufA = acts + w * 3072;         // X / Q / S
  unsigned short* bufB = acts + w * 3072 + 2048;  // P / R
  int m = l & 15;
  int kg = l >> 4;  // 0..3
  float fc4r[16];

#pragma unroll
  for (int g = 0; g < 4; ++g) {
    int base = nb + w * 64 + g * 16;
    // ---- stage X wave-locally (bf16 copy): node16 = l>>2, k-octet = l&3
    {
      int n16 = l >> 2, kq = l & 3;
      int node = base + n16;
      s16x8 xpk = {0, 0, 0, 0, 0, 0, 0, 0};
      if (node < NN)
        xpk = *reinterpret_cast<const s16x8*>(&aggb[(size_t)node * 32 + kq * 8]);
      int e = (n16 * 64 + kq * 8) ^ ((n16 & 7) << 3);
      *reinterpret_cast<s16x8*>(&bufA[e]) = xpk;
    }
    asm volatile("s_waitcnt lgkmcnt(0)" ::: "memory");

    // ---- L3: X[16x32] @ W3 + b3, maxpool(2) -> P[16][64] in bufB
#pragma unroll
    for (int nt = 0; nt < 8; ++nt) {
      int n = nt * 16 + m;
      f32x4 acc = {0.f, 0.f, 0.f, 0.f};
      s16x8 a = *reinterpret_cast<const s16x8*>(
          &bufA[(m * 64 + kg * 8) ^ ((m & 7) << 3)]);
      s16x8 b = *reinterpret_cast<const s16x8*>(
          &wv[WT_W3 + ((n * 32 + kg * 8) ^ ((n & 3) << 3))]);
      acc = __builtin_amdgcn_mfma_f32_16x16x32_bf16(a, b, acc, 0, 0, 0);
      float bias = b3[n];
#pragma unroll
      for (int r = 0; r < 4; ++r) {
        float v = acc[r] + bias;
        float pv = fmaxf(v, __shfl_xor(v, 1));
        if (!(m & 1)) {
          int node = kg * 4 + r;
          int j = n >> 1;
          bufB[(node * 64 + j) ^ ((node & 7) << 3)] = f2bf(pv);
        }
      }
    }
    asm volatile("s_waitcnt lgkmcnt(0)" ::: "memory");
    // ---- fc1: P[16x64] @ fW1 + fb1, relu -> Q[16][128] in bufA
#pragma unroll
    for (int nt = 0; nt < 8; ++nt) {
      int n = nt * 16 + m;
      f32x4 acc = {0.f, 0.f, 0.f, 0.f};
#pragma unroll
      for (int kt = 0; kt < 2; ++kt) {
        s16x8 a = *reinterpret_cast<const s16x8*>(
            &bufB[(m * 64 + kt * 32 + kg * 8) ^ ((m & 7) << 3)]);
        s16x8 b = *reinterpret_cast<const s16x8*>(
            &wv[WT_F1 + ((n * 64 + kt * 32 + kg * 8) ^ ((n & 7) << 3))]);
        acc = __builtin_amdgcn_mfma_f32_16x16x32_bf16(a, b, acc, 0, 0, 0);
      }
      float bias = fb1[n];
#pragma unroll
      for (int r = 0; r < 4; ++r) {
        int node = kg * 4 + r;
        float v = fmaxf(acc[r] + bias, 0.f);
        bufA[(node * 128 + n) ^ ((node & 7) << 3)] = f2bf(v);
      }
    }
    asm volatile("s_waitcnt lgkmcnt(0)" ::: "memory");
    // ---- fc2: Q[16x128] @ fW2 + fb2, relu -> R[16][64] in bufB
#pragma unroll
    for (int nt = 0; nt < 4; ++nt) {
      int n = nt * 16 + m;
      f32x4 acc = {0.f, 0.f, 0.f, 0.f};
#pragma unroll
      for (int kt = 0; kt < 4; ++kt) {
        s16x8 a = *reinterpret_cast<const s16x8*>(
            &bufA[(m * 128 + kt * 32 + kg * 8) ^ ((m & 7) << 3)]);
        s16x8 b = *reinterpret_cast<const s16x8*>(
            &wv[WT_F2 + ((n * 128 + kt * 32 + kg * 8) ^ ((n & 7) << 3))]);
        acc = __builtin_amdgcn_mfma_f32_16x16x32_bf16(a, b, acc, 0, 0, 0);
      }
      float bias = fb2[n];
#pragma unroll
      for (int r = 0; r < 4; ++r) {
        int node = kg * 4 + r;
        float v = fmaxf(acc[r] + bias, 0.f);
        bufB[(node * 64 + n) ^ ((node & 7) << 3)] = f2bf(v);
      }
    }
    asm volatile("s_waitcnt lgkmcnt(0)" ::: "memory");
    // ---- fc3: R[16x64] @ fW3 + fb3, relu -> S[16][32] in bufA (stride 64)
#pragma unroll
    for (int nt = 0; nt < 2; ++nt) {
      int n = nt * 16 + m;
      f32x4 acc = {0.f, 0.f, 0.f, 0.f};
#pragma unroll
      for (int kt = 0; kt < 2; ++kt) {
        s16x8 a = *reinterpret_cast<const s16x8*>(
            &bufB[(m * 64 + kt * 32 + kg * 8) ^ ((m & 7) << 3)]);
        s16x8 b = *reinterpret_cast<const s16x8*>(
            &wv[WT_F3 + ((n * 64 + kt * 32 + kg * 8) ^ ((n & 7) << 3))]);
        acc = __builtin_amdgcn_mfma_f32_16x16x32_bf16(a, b, acc, 0, 0, 0);
      }
      float bias = fb3[n];
#pragma unroll
      for (int r = 0; r < 4; ++r) {
        int node = kg * 4 + r;
        float v = fmaxf(acc[r] + bias, 0.f);
        bufA[(node * 64 + n) ^ ((node & 7) << 3)] = f2bf(v);
      }
    }
    asm volatile("s_waitcnt lgkmcnt(0)" ::: "memory");
    // ---- fc4: S[16x32] @ fW4p + fb4 -> regs (statically indexed by g)
    {
      f32x4 acc = {0.f, 0.f, 0.f, 0.f};
      s16x8 a = *reinterpret_cast<const s16x8*>(
          &bufA[(m * 64 + kg * 8) ^ ((m & 7) << 3)]);
      s16x8 b = *reinterpret_cast<const s16x8*>(
          &wv[WT_F4 + ((m * 32 + kg * 8) ^ ((m & 3) << 3))]);
      acc = __builtin_amdgcn_mfma_f32_16x16x32_bf16(a, b, acc, 0, 0, 0);
      float bias = (m < 10) ? fb4[m] : 0.f;
#pragma unroll
      for (int r = 0; r < 4; ++r) fc4r[g * 4 + r] = acc[r] + bias;
    }
  }

  // flush fc4 results into this wave's (now dead) act buffer as f32 [64][12]
  asm volatile("s_waitcnt lgkmcnt(0)" ::: "memory");
  {
    float* fbuf = reinterpret_cast<float*>(bufA);
    if (m < 10) {
#pragma unroll
      for (int g = 0; g < 4; ++g)
#pragma unroll
        for (int r = 0; r < 4; ++r) {
          int nl = g * 16 + kg * 4 + r;
          fbuf[nl * 12 + m] = fc4r[g * 4 + r];
        }
    }
  }
  __syncthreads();

  // segmented graph-mean: 4 teams of 10 threads, one per 64-node quarter
  if (t < 40) {
    int q = t / 10, j = t % 10;
    const float* fbuf = reinterpret_cast<const float*>(acts + q * 3072);
    int qbase = q * 64;
    int qrem = min(64, NN - (nb + qbase));
    if (qrem > 0) {
      int g = sgid[qbase];
      float run = 0.f;
      for (int n = 0; n < qrem; ++n) {
        run += fbuf[n * 12 + j];
        bool last = (n == qrem - 1) || (sgid[qbase + n + 1] != g);
        if (last) {
          atomicAdd(&out[g * 10 + j], run * inv_counts[g]);
          run = 0.f;
          if (n < qrem - 1) g = sgid[qbase + n + 1];
        }
      }
    }
  }
}

extern "C" void kernel_launch(void* const* d_in, const int* in_sizes, int n_in,
                              void* d_out, int out_size, void* d_ws, size_t ws_size,
                              hipStream_t stream) {
  const int* src = (const int*)d_in[0];
  const int* dst = (const int*)d_in[1];
  const int* gid = (const int*)d_in[2];
  const float* n_feat = (const float*)d_in[3];
  const float* W1 = (const float*)d_in[4];
  const float* b1 = (const float*)d_in[5];
  const float* W2 = (const float*)d_in[6];
  const float* b2 = (const float*)d_in[7];
  const float* W3 = (const float*)d_in[8];
  const float* b3 = (const float*)d_in[9];
  const float* fW1 = (const float*)d_in[10];
  const float* fb1 = (const float*)d_in[11];
  const float* fW2 = (const float*)d_in[12];
  const float* fb2 = (const float*)d_in[13];
  const float* fW3 = (const float*)d_in[14];
  const float* fb3 = (const float*)d_in[15];
  const float* fW4 = (const float*)d_in[16];
  const float* fb4 = (const float*)d_in[17];
  float* out = (float*)d_out;

  float* ws = (float*)d_ws;
  float* norm_out = ws + OFF_NORM_OUT;
  float* norm_in = ws + OFF_NORM_IN;
  float* inv_cnt = ws + OFF_INVC;
  int* row_ptr = (int*)(ws + OFF_ROWPTR);
  int* csr = (int*)(ws + OFF_CSR);
  float* agg = ws + OFF_AGG;
  float* buf = ws + OFF_BUF;
  int* cnt_dst = (int*)(ws + OFF_CNTD);
  int* cnt_src = (int*)(ws + OFF_CNTS);
  int* bb_dst = (int*)(ws + OFF_BBD);
  int* bb_src = (int*)(ws + OFF_BBS);
  int* tot = (int*)(ws + OFF_TOT);
  unsigned short* wT = (unsigned short*)(ws + OFF_WT);
  uint32_t* pairs = (uint32_t*)agg;                 // NE u32 inside agg region
  uint16_t* srcbuf = (uint16_t*)((int*)agg + NE);   // NE u16, after pairs
  unsigned short* xs0b = (unsigned short*)buf;      // [NN][8]  bf16
  unsigned short* xs1b = (unsigned short*)agg;      // [NN][16] bf16 (pairs dead)
  unsigned short* xs2b = (unsigned short*)buf;      // [NN][32] bf16 (xs0 dead)
  unsigned short* aggb = (unsigned short*)agg;      // [NN][32] bf16 (xs1 dead)

  k_prepw<<<1, 256, 0, stream>>>(W3, fW1, fW2, fW3, fW4, wT, out, out_size, gid, inv_cnt);
  k_part_count<<<NPB, 256, 0, stream>>>(src, dst, cnt_dst, cnt_src);
  k_btot<<<2 * NB, 256, 0, stream>>>(cnt_dst, cnt_src, tot);
  k_crow<<<2 * NB, 256, 0, stream>>>(cnt_dst, cnt_src, tot, bb_dst, bb_src);
  k_part_scatter<<<NPB, 256, 0, stream>>>(src, dst, cnt_dst, cnt_src, pairs, srcbuf);
  k_bucket<<<2 * NB, 256, 0, stream>>>(pairs, bb_dst, srcbuf, bb_src, n_feat,
                                       row_ptr, norm_in, csr, norm_out, xs0b);

  // layer 1: gather(d=8, bf16) + 8->16 + relu -> xs1 bf16 (agg region)
  k_agglayer<8, 16><<<(NN + 255) / 256, 256, 0, stream>>>(
      xs0b, csr, row_ptr, norm_in, norm_out, W1, b1, xs1b);
  // layer 2: gather(d=16, bf16) + 16->32 + relu -> xs2 bf16 (buf region)
  k_agglayer<16, 32><<<(NN + 255) / 256, 256, 0, stream>>>(
      xs1b, csr, row_ptr, norm_in, norm_out, W2, b2, xs2b);
  // layer 3: bf16 gather (d=32) -> aggb bf16, then MFMA tail
  k_agg32_bf<<<(NN * 4 + 255) / 256, 256, 0, stream>>>(xs2b, csr, row_ptr, norm_in, aggb);
  k_tail9<<<(NN + 255) / 256, 256, 0, stream>>>(aggb, gid, wT, b3, fb1, fb2, fb3, fb4,
                                                inv_cnt, out);
}